// Round 3
// baseline (1346.591 us; speedup 1.0000x reference)
//
#include <hip/hip_runtime.h>
#include <hip/hip_bf16.h>

typedef __attribute__((ext_vector_type(8))) short short8_t;
typedef __attribute__((ext_vector_type(4))) float f32x4;

__device__ __forceinline__ float bf2f(unsigned short u) {
    return __uint_as_float(((unsigned)u) << 16);
}
__device__ __forceinline__ unsigned short f2bf(float f) {
    __hip_bfloat16 h = __float2bfloat16(f);
    return *reinterpret_cast<unsigned short*>(&h);
}

// window-order row r (r = wb*49 + n) -> natural token index
__device__ __forceinline__ int win_row_to_token(int r) {
    int wb = r / 49, n = r - wb * 49;
    int wq = wb & 7, hb = (wb >> 3) & 7, d = (wb >> 6) & 7, b = wb >> 9;
    int hh = n / 7, ww2 = n - hh * 7;
    return ((b * 8 + d) * 56 + hb * 7 + hh) * 56 + wq * 7 + ww2;
}

// ---------------- prep: scales, qkv bias, CPB-MLP -> rpb_t (transposed, padded 52x52) ----------------
__global__ __launch_bounds__(256) void prep_kernel(
    const float* __restrict__ logit_scale,
    const float* __restrict__ w1, const float* __restrict__ b1,
    const float* __restrict__ w2,
    const float* __restrict__ qb, const float* __restrict__ vb,
    const float* __restrict__ tabin, const int* __restrict__ rpi,
    float* __restrict__ scales, float* __restrict__ rpbt,
    float* __restrict__ qkvb)
{
    int t = threadIdx.x;
    if (t < 8) {
        float v = logit_scale[t];
        scales[t] = expf(fminf(v, 4.6051702f)); // ln(100)
    }
    for (int i = t; i < 768; i += 256) {
        float o;
        if (i < 256) o = qb[i];
        else if (i < 512) o = 0.f;
        else o = vb[i - 512];
        qkvb[i] = o;
    }
    // zero padded rpb_t: 8 heads x 52*52
    for (int i = t; i < 8 * 2704; i += 256) rpbt[i] = 0.f;
    __shared__ float table[169][8];
    for (int i = t; i < 169; i += 256) {
        float c0 = tabin[i * 3], c1 = tabin[i * 3 + 1], c2 = tabin[i * 3 + 2];
        float acc[8] = {0.f, 0.f, 0.f, 0.f, 0.f, 0.f, 0.f, 0.f};
        for (int j = 0; j < 512; ++j) {
            float hv = c0 * w1[j * 3] + c1 * w1[j * 3 + 1] + c2 * w1[j * 3 + 2] + b1[j];
            hv = fmaxf(hv, 0.f);
            #pragma unroll
            for (int h = 0; h < 8; ++h) acc[h] += hv * w2[h * 512 + j];
        }
        #pragma unroll
        for (int h = 0; h < 8; ++h) table[i][h] = acc[h];
    }
    __syncthreads();
    for (int e = t; e < 2401; e += 256) {
        int i = e / 49, j = e - i * 49;   // i = query row, j = key row
        int idx = rpi[e];
        #pragma unroll
        for (int h = 0; h < 8; ++h) {
            float xv = table[idx][h];
            rpbt[h * 2704 + j * 52 + i] = 16.f / (1.f + expf(-xv));
        }
    }
}

// ---------------- GEMM: C[M,N] = A[M,K] * W[N,K]^T + bias ----------------
template<int ACT, int SCATTER, int AF32>
__global__ __launch_bounds__(256) void gemm_kernel(
    const void* __restrict__ Av, const float* __restrict__ W,
    const float* __restrict__ bias, unsigned short* __restrict__ C,
    int M, int N, int K)
{
    constexpr int LDS_STRIDE = 72; // 64 + 8 pad elems; 144B rows
    __shared__ unsigned short As[128 * LDS_STRIDE];
    __shared__ unsigned short Bs[128 * LDS_STRIDE];
    const int tid = threadIdx.x;
    const int lane = tid & 63, wid = tid >> 6;
    const int wr = wid >> 1, wc = wid & 1;
    const int bm = blockIdx.x, bn = blockIdx.y;
    const size_t arow0 = (size_t)bm * 128;
    const size_t brow0 = (size_t)bn * 128;
    const int r16 = lane & 15, kq = (lane >> 4) * 8;
    f32x4 acc[4][4] = {};

    for (int kt = 0; kt < K; kt += 64) {
        if (AF32) {
            const float* A = (const float*)Av;
            #pragma unroll
            for (int i = 0; i < 8; ++i) {
                int s = tid + (i << 8);
                int row = s >> 4, c4 = (s & 15) << 2;
                float4 v = *reinterpret_cast<const float4*>(&A[(arow0 + row) * K + kt + c4]);
                short4 o;
                o.x = (short)f2bf(v.x); o.y = (short)f2bf(v.y);
                o.z = (short)f2bf(v.z); o.w = (short)f2bf(v.w);
                *reinterpret_cast<short4*>(&As[row * LDS_STRIDE + c4]) = o;
            }
        } else {
            const unsigned short* A = (const unsigned short*)Av;
            #pragma unroll
            for (int i = 0; i < 4; ++i) {
                int s = tid + (i << 8);
                int row = s >> 3, c8 = (s & 7) << 3;
                *reinterpret_cast<int4*>(&As[row * LDS_STRIDE + c8]) =
                    *reinterpret_cast<const int4*>(&A[(arow0 + row) * K + kt + c8]);
            }
        }
        #pragma unroll
        for (int i = 0; i < 8; ++i) {
            int s = tid + (i << 8);
            int row = s >> 4, c4 = (s & 15) << 2;
            float4 v = *reinterpret_cast<const float4*>(&W[(brow0 + row) * K + kt + c4]);
            short4 o;
            o.x = (short)f2bf(v.x); o.y = (short)f2bf(v.y);
            o.z = (short)f2bf(v.z); o.w = (short)f2bf(v.w);
            *reinterpret_cast<short4*>(&Bs[row * LDS_STRIDE + c4]) = o;
        }
        __syncthreads();
        #pragma unroll
        for (int kk = 0; kk < 2; ++kk) {
            short8_t af[4], bfr[4];
            #pragma unroll
            for (int m = 0; m < 4; ++m)
                af[m] = *reinterpret_cast<const short8_t*>(
                    &As[(wr * 64 + m * 16 + r16) * LDS_STRIDE + kk * 32 + kq]);
            #pragma unroll
            for (int n = 0; n < 4; ++n)
                bfr[n] = *reinterpret_cast<const short8_t*>(
                    &Bs[(wc * 64 + n * 16 + r16) * LDS_STRIDE + kk * 32 + kq]);
            #pragma unroll
            for (int m = 0; m < 4; ++m)
                #pragma unroll
                for (int n = 0; n < 4; ++n)
                    acc[m][n] = __builtin_amdgcn_mfma_f32_16x16x32_bf16(af[m], bfr[n], acc[m][n], 0, 0, 0);
        }
        __syncthreads();
    }

    const int rbase = (lane >> 4) * 4;
    #pragma unroll
    for (int n = 0; n < 4; ++n) {
        int gcol = bn * 128 + wc * 64 + n * 16 + r16;
        float bv = bias[gcol];
        #pragma unroll
        for (int m = 0; m < 4; ++m) {
            #pragma unroll
            for (int r = 0; r < 4; ++r) {
                int grow = bm * 128 + wr * 64 + m * 16 + rbase + r;
                float v = acc[m][n][r] + bv;
                if (ACT == 1) v = 0.5f * v * (1.f + erff(v * 0.70710678118f));
                size_t orow = SCATTER ? (size_t)win_row_to_token(grow) : (size_t)grow;
                C[orow * (size_t)N + gcol] = f2bf(v);
            }
        }
    }
}

// ---------------- attention: one block per (window, head), register-tiled VALU ----------------
// LDS layouts: q_sw/k_sw: [52 rows][32 f32], 16B-granule XOR swizzle g = dg ^ ((row>>2)&7).
// vv natural [49][32]. St transposed [j:52][i:52] f32 (stride 52, float4-aligned).
__global__ __launch_bounds__(256) void attn_kernel(
    const unsigned short* __restrict__ qkv, const float* __restrict__ scales,
    const float* __restrict__ rpbt, unsigned short* __restrict__ out)
{
    int blk = blockIdx.x;
    int h = blk & 7, wb = blk >> 3;
    int t = threadIdx.x;
    __shared__ float q_sw[52 * 32];
    __shared__ float k_sw[52 * 32];
    __shared__ float vv[49 * 32];
    __shared__ float St[52 * 52];
    __shared__ int toks[49];
    if (t < 49) toks[t] = win_row_to_token(wb * 49 + t);
    if (t >= 64) {           // zero-fill pad rows 49..51 of q_sw/k_sw
        int z = t - 64;
        if (z < 96) q_sw[49 * 32 + z] = 0.f;
        else if (z < 192) k_sw[49 * 32 + (z - 96)] = 0.f;
    }
    __syncthreads();

    const float sc = scales[h];
    // ---- staging with fused l2-norm (shuffle reduce over the 8 lanes of each row) ----
    for (int c = t; c < 1176; c += 256) {
        int which = c / 392;               // 0=q, 1=k, 2=v
        int rem = c - which * 392;
        int row = rem >> 3, dg = rem & 7;
        size_t base = (size_t)toks[row] * 768 + (size_t)(which * 256 + h * 32 + dg * 4);
        short4 s4 = *reinterpret_cast<const short4*>(&qkv[base]);
        float f0 = bf2f((unsigned short)s4.x), f1 = bf2f((unsigned short)s4.y);
        float f2 = bf2f((unsigned short)s4.z), f3 = bf2f((unsigned short)s4.w);
        if (which == 2) {
            float4 o; o.x = f0; o.y = f1; o.z = f2; o.w = f3;
            *reinterpret_cast<float4*>(&vv[row * 32 + dg * 4]) = o;
        } else {
            float ss = f0 * f0 + f1 * f1 + f2 * f2 + f3 * f3;
            ss += __shfl_xor(ss, 1); ss += __shfl_xor(ss, 2); ss += __shfl_xor(ss, 4);
            float inv = 1.f / fmaxf(sqrtf(ss), 1e-12f);
            if (which == 0) inv *= sc;     // fold logit scale into q
            float4 o; o.x = f0 * inv; o.y = f1 * inv; o.z = f2 * inv; o.w = f3 * inv;
            float* dst = which ? k_sw : q_sw;
            int g = dg ^ ((row >> 2) & 7);
            *reinterpret_cast<float4*>(&dst[row * 32 + g * 4]) = o;
        }
    }
    __syncthreads();

    // ---- QK^T: 13x13 grid of 4x4 register tiles ----
    if (t < 169) {
        int it = t % 13, jt = t / 13;
        int i0 = it * 4, j0 = jt * 4;
        int gq = it & 7, gk = jt & 7;
        float acc[4][4];
        #pragma unroll
        for (int r = 0; r < 4; ++r)
            #pragma unroll
            for (int c = 0; c < 4; ++c) acc[r][c] = 0.f;
        #pragma unroll
        for (int dq = 0; dq < 8; ++dq) {
            float4 qr[4], kr[4];
            #pragma unroll
            for (int r = 0; r < 4; ++r)
                qr[r] = *reinterpret_cast<const float4*>(&q_sw[(i0 + r) * 32 + ((dq ^ gq) << 2)]);
            #pragma unroll
            for (int c = 0; c < 4; ++c)
                kr[c] = *reinterpret_cast<const float4*>(&k_sw[(j0 + c) * 32 + ((dq ^ gk) << 2)]);
            #pragma unroll
            for (int r = 0; r < 4; ++r)
                #pragma unroll
                for (int c = 0; c < 4; ++c)
                    acc[r][c] += qr[r].x * kr[c].x + qr[r].y * kr[c].y
                               + qr[r].z * kr[c].z + qr[r].w * kr[c].w;
        }
        const float* rb = rpbt + h * 2704;
        #pragma unroll
        for (int c = 0; c < 4; ++c) {
            int j = j0 + c;
            float4 rv = *reinterpret_cast<const float4*>(&rb[j * 52 + i0]);
            float4 o;
            o.x = acc[0][c] + rv.x; o.y = acc[1][c] + rv.y;
            o.z = acc[2][c] + rv.z; o.w = acc[3][c] + rv.w;
            *reinterpret_cast<float4*>(&St[j * 52 + i0]) = o;
        }
    }
    __syncthreads();

    // ---- softmax over j for each query i (conflict-free: lanes = i, consecutive) ----
    if (t < 49) {
        float m = -1e30f;
        for (int j = 0; j < 49; ++j) m = fmaxf(m, St[j * 52 + t]);
        float sum = 0.f;
        for (int j = 0; j < 49; ++j) {
            float p = __expf(St[j * 52 + t] - m);
            St[j * 52 + t] = p; sum += p;
        }
        float r = 1.f / sum;
        for (int j = 0; j < 49; ++j) St[j * 52 + t] *= r;
    }
    __syncthreads();

    // ---- PV: thread = (i-tile of 4, d-quad); v reads broadcast across i-tiles ----
    if (t < 104) {
        int it = t % 13, dq = t / 13;
        int i0 = it * 4;
        f32x4 a0 = {0.f, 0.f, 0.f, 0.f}, a1 = a0, a2 = a0, a3 = a0;
        for (int j = 0; j < 49; ++j) {
            f32x4 v4 = *reinterpret_cast<const f32x4*>(&vv[j * 32 + dq * 4]);
            f32x4 p4 = *reinterpret_cast<const f32x4*>(&St[j * 52 + i0]);
            a0 += p4[0] * v4; a1 += p4[1] * v4; a2 += p4[2] * v4; a3 += p4[3] * v4;
        }
        #pragma unroll
        for (int r = 0; r < 4; ++r) {
            int i = i0 + r;
            if (i < 49) {
                f32x4 a = (r == 0) ? a0 : (r == 1) ? a1 : (r == 2) ? a2 : a3;
                short4 o;
                o.x = (short)f2bf(a[0]); o.y = (short)f2bf(a[1]);
                o.z = (short)f2bf(a[2]); o.w = (short)f2bf(a[3]);
                *reinterpret_cast<short4*>(&out[(size_t)(wb * 49 + i) * 256 + h * 32 + dq * 4]) = o;
            }
        }
    }
}

// ---------------- fused residual + LayerNorm (one wave per token) ----------------
template<int BASE_F32, int OUT_F32>
__global__ __launch_bounds__(256) void ln_add_kernel(
    const void* __restrict__ basev, const unsigned short* __restrict__ vin,
    const float* __restrict__ gg, const float* __restrict__ bb,
    void* __restrict__ outv)
{
    int token = blockIdx.x * 4 + (threadIdx.x >> 6);
    int lane = threadIdx.x & 63;
    size_t off = (size_t)token * 256 + lane * 4;
    short4 raw = *reinterpret_cast<const short4*>(&vin[off]);
    float f0 = bf2f((unsigned short)raw.x), f1 = bf2f((unsigned short)raw.y);
    float f2 = bf2f((unsigned short)raw.z), f3 = bf2f((unsigned short)raw.w);
    float s  = f0 + f1 + f2 + f3;
    float s2 = f0 * f0 + f1 * f1 + f2 * f2 + f3 * f3;
    #pragma unroll
    for (int m = 32; m >= 1; m >>= 1) { s += __shfl_xor(s, m, 64); s2 += __shfl_xor(s2, m, 64); }
    float mu = s * 0.00390625f;
    float var = s2 * 0.00390625f - mu * mu;
    float inv = rsqrtf(var + 1e-5f);

    float b0, b1v, b2, b3;
    if (BASE_F32) {
        float4 braw = *reinterpret_cast<const float4*>(&((const float*)basev)[off]);
        b0 = braw.x; b1v = braw.y; b2 = braw.z; b3 = braw.w;
    } else {
        short4 braw = *reinterpret_cast<const short4*>(&((const unsigned short*)basev)[off]);
        b0 = bf2f((unsigned short)braw.x); b1v = bf2f((unsigned short)braw.y);
        b2 = bf2f((unsigned short)braw.z); b3 = bf2f((unsigned short)braw.w);
    }
    float4 graw = *reinterpret_cast<const float4*>(&gg[lane * 4]);
    float4 brw2 = *reinterpret_cast<const float4*>(&bb[lane * 4]);
    float o0 = b0 + (f0 - mu) * inv * graw.x + brw2.x;
    float o1 = b1v + (f1 - mu) * inv * graw.y + brw2.y;
    float o2 = b2 + (f2 - mu) * inv * graw.z + brw2.z;
    float o3 = b3 + (f3 - mu) * inv * graw.w + brw2.w;
    if (OUT_F32) {
        float4 o; o.x = o0; o.y = o1; o.z = o2; o.w = o3;
        *reinterpret_cast<float4*>(&((float*)outv)[off]) = o;
    } else {
        short4 o;
        o.x = (short)f2bf(o0); o.y = (short)f2bf(o1);
        o.z = (short)f2bf(o2); o.w = (short)f2bf(o3);
        *reinterpret_cast<short4*>(&((unsigned short*)outv)[off]) = o;
    }
}

extern "C" void kernel_launch(void* const* d_in, const int* in_sizes, int n_in,
                              void* d_out, int out_size, void* d_ws, size_t ws_size,
                              hipStream_t stream) {
    const float* x      = (const float*)d_in[0];
    const float* qkv_w  = (const float*)d_in[1];
    const float* q_bias = (const float*)d_in[2];
    const float* v_bias = (const float*)d_in[3];
    const float* lscale = (const float*)d_in[4];
    const float* cpb_w1 = (const float*)d_in[5];
    const float* cpb_b1 = (const float*)d_in[6];
    const float* cpb_w2 = (const float*)d_in[7];
    const float* proj_w = (const float*)d_in[8];
    const float* proj_b = (const float*)d_in[9];
    const float* n1g    = (const float*)d_in[10];
    const float* n1b    = (const float*)d_in[11];
    const float* fc1_w  = (const float*)d_in[12];
    const float* fc1_b  = (const float*)d_in[13];
    const float* fc2_w  = (const float*)d_in[14];
    const float* fc2_b  = (const float*)d_in[15];
    const float* n2g    = (const float*)d_in[16];
    const float* n2b    = (const float*)d_in[17];
    const float* rct    = (const float*)d_in[18];
    const int*   rpi    = (const int*)d_in[19];

    char* ws = (char*)d_ws;
    // region 0 [0, 205520896): qkv bf16 (154.1MB), later h bf16 (205.5MB).
    // Small buffers live in region 0's tail slack [160000000, ~160.1MB) —
    // dead by the time fc1 overwrites region 0 with h.
    unsigned short* qkv    = (unsigned short*)(ws);
    unsigned short* hbuf   = (unsigned short*)(ws);
    float*          scales = (float*)(ws + 160000000);
    float*          qkvb   = (float*)(ws + 160000128);
    float*          rpbt   = (float*)(ws + 160004096); // 8*52*52*4 = 86528 B
    // region 1 [205520896, 256901120): attn_o bf16 (window order), later x1 bf16
    unsigned short* attn_o = (unsigned short*)(ws + 205520896);
    unsigned short* x1     = (unsigned short*)(ws + 205520896);
    // region 2 [256901120, 308281344): projy bf16, later y bf16
    unsigned short* projy  = (unsigned short*)(ws + 256901120);

    const int M = 100352; // tokens

    prep_kernel<<<1, 256, 0, stream>>>(lscale, cpb_w1, cpb_b1, cpb_w2, q_bias, v_bias,
                                       rct, rpi, scales, rpbt, qkvb);
    // qkv = x @ qkv_w^T + qkv_bias   (natural token order)
    gemm_kernel<0, 0, 1><<<dim3(784, 6), 256, 0, stream>>>(x, qkv_w, qkvb, qkv, M, 768, 256);
    // attention per (window, head) -> window-ordered (Bw*49, 256)
    attn_kernel<<<16384, 256, 0, stream>>>(qkv, scales, rpbt, attn_o);
    // proj with row scatter back to natural order
    gemm_kernel<0, 1, 0><<<dim3(784, 2), 256, 0, stream>>>(attn_o, proj_w, proj_b, projy, M, 256, 256);
    // x1 = x + LN(proj_out)
    ln_add_kernel<1, 0><<<25088, 256, 0, stream>>>(x, projy, n1g, n1b, x1);
    // h = gelu(x1 @ fc1_w^T + fc1_b)
    gemm_kernel<1, 0, 0><<<dim3(784, 8), 256, 0, stream>>>(x1, fc1_w, fc1_b, hbuf, M, 1024, 256);
    // y = h @ fc2_w^T + fc2_b
    gemm_kernel<0, 0, 0><<<dim3(784, 2), 256, 0, stream>>>(hbuf, fc2_w, fc2_b, projy, M, 256, 1024);
    // out = x1 + LN(y)
    ln_add_kernel<0, 1><<<25088, 256, 0, stream>>>(x1, projy, n2g, n2b, d_out);
}

// Round 4
// 811.599 us; speedup vs baseline: 1.6592x; 1.6592x over previous
//
#include <hip/hip_runtime.h>
#include <hip/hip_bf16.h>

typedef __attribute__((ext_vector_type(8))) short short8_t;
typedef __attribute__((ext_vector_type(4))) float f32x4;

__device__ __forceinline__ float bf2f(unsigned short u) {
    return __uint_as_float(((unsigned)u) << 16);
}
__device__ __forceinline__ unsigned short f2bf(float f) {
    __hip_bfloat16 h = __float2bfloat16(f);
    return *reinterpret_cast<unsigned short*>(&h);
}

// window-order row r (r = wb*49 + n) -> natural token index
__device__ __forceinline__ int win_row_to_token(int r) {
    int wb = r / 49, n = r - wb * 49;
    int wq = wb & 7, hb = (wb >> 3) & 7, d = (wb >> 6) & 7, b = wb >> 9;
    int hh = n / 7, ww2 = n - hh * 7;
    return ((b * 8 + d) * 56 + hb * 7 + hh) * 56 + wq * 7 + ww2;
}

// ---------------- prep: scales, qkv bias, CPB-MLP -> rpbn [8][64][64] natural padded ----------------
__global__ __launch_bounds__(256) void prep_kernel(
    const float* __restrict__ logit_scale,
    const float* __restrict__ w1, const float* __restrict__ b1,
    const float* __restrict__ w2,
    const float* __restrict__ qb, const float* __restrict__ vb,
    const float* __restrict__ tabin, const int* __restrict__ rpi,
    float* __restrict__ scales, float* __restrict__ rpbn,
    float* __restrict__ qkvb)
{
    int t = threadIdx.x;
    if (t < 8) {
        float v = logit_scale[t];
        scales[t] = expf(fminf(v, 4.6051702f)); // ln(100)
    }
    for (int i = t; i < 768; i += 256) {
        float o;
        if (i < 256) o = qb[i];
        else if (i < 512) o = 0.f;
        else o = vb[i - 512];
        qkvb[i] = o;
    }
    for (int i = t; i < 8 * 4096; i += 256) rpbn[i] = 0.f;
    __shared__ float table[169][8];
    for (int i = t; i < 169; i += 256) {
        float c0 = tabin[i * 3], c1 = tabin[i * 3 + 1], c2 = tabin[i * 3 + 2];
        float acc[8] = {0.f, 0.f, 0.f, 0.f, 0.f, 0.f, 0.f, 0.f};
        for (int j = 0; j < 512; ++j) {
            float hv = c0 * w1[j * 3] + c1 * w1[j * 3 + 1] + c2 * w1[j * 3 + 2] + b1[j];
            hv = fmaxf(hv, 0.f);
            #pragma unroll
            for (int h = 0; h < 8; ++h) acc[h] += hv * w2[h * 512 + j];
        }
        #pragma unroll
        for (int h = 0; h < 8; ++h) table[i][h] = acc[h];
    }
    __syncthreads();
    for (int e = t; e < 2401; e += 256) {
        int i = e / 49, j = e - i * 49;   // i = query row, j = key col
        int idx = rpi[e];
        #pragma unroll
        for (int h = 0; h < 8; ++h) {
            float xv = table[idx][h];
            rpbn[h * 4096 + i * 64 + j] = 16.f / (1.f + expf(-xv));
        }
    }
}

// ---------------- GEMM: C[M,N] = A[M,K] * W[N,K]^T + bias ----------------
// Grid: blockIdx.x = N-tile (fast, so blocks sharing an A-tile dispatch together),
//       blockIdx.y = M-tile.
template<int ACT, int SCATTER, int AF32>
__global__ __launch_bounds__(256) void gemm_kernel(
    const void* __restrict__ Av, const float* __restrict__ W,
    const float* __restrict__ bias, unsigned short* __restrict__ C,
    int M, int N, int K)
{
    constexpr int LDS_STRIDE = 72; // 64 + 8 pad elems; 144B rows
    __shared__ unsigned short As[128 * LDS_STRIDE];
    __shared__ unsigned short Bs[128 * LDS_STRIDE];
    const int tid = threadIdx.x;
    const int lane = tid & 63, wid = tid >> 6;
    const int wr = wid >> 1, wc = wid & 1;
    const int bm = blockIdx.y, bn = blockIdx.x;
    const size_t arow0 = (size_t)bm * 128;
    const size_t brow0 = (size_t)bn * 128;
    const int r16 = lane & 15, kq = (lane >> 4) * 8;
    f32x4 acc[4][4] = {};

    for (int kt = 0; kt < K; kt += 64) {
        if (AF32) {
            const float* A = (const float*)Av;
            #pragma unroll
            for (int i = 0; i < 8; ++i) {
                int s = tid + (i << 8);
                int row = s >> 4, c4 = (s & 15) << 2;
                float4 v = *reinterpret_cast<const float4*>(&A[(arow0 + row) * K + kt + c4]);
                short4 o;
                o.x = (short)f2bf(v.x); o.y = (short)f2bf(v.y);
                o.z = (short)f2bf(v.z); o.w = (short)f2bf(v.w);
                *reinterpret_cast<short4*>(&As[row * LDS_STRIDE + c4]) = o;
            }
        } else {
            const unsigned short* A = (const unsigned short*)Av;
            #pragma unroll
            for (int i = 0; i < 4; ++i) {
                int s = tid + (i << 8);
                int row = s >> 3, c8 = (s & 7) << 3;
                *reinterpret_cast<int4*>(&As[row * LDS_STRIDE + c8]) =
                    *reinterpret_cast<const int4*>(&A[(arow0 + row) * K + kt + c8]);
            }
        }
        #pragma unroll
        for (int i = 0; i < 8; ++i) {
            int s = tid + (i << 8);
            int row = s >> 4, c4 = (s & 15) << 2;
            float4 v = *reinterpret_cast<const float4*>(&W[(brow0 + row) * K + kt + c4]);
            short4 o;
            o.x = (short)f2bf(v.x); o.y = (short)f2bf(v.y);
            o.z = (short)f2bf(v.z); o.w = (short)f2bf(v.w);
            *reinterpret_cast<short4*>(&Bs[row * LDS_STRIDE + c4]) = o;
        }
        __syncthreads();
        #pragma unroll
        for (int kk = 0; kk < 2; ++kk) {
            short8_t af[4], bfr[4];
            #pragma unroll
            for (int m = 0; m < 4; ++m)
                af[m] = *reinterpret_cast<const short8_t*>(
                    &As[(wr * 64 + m * 16 + r16) * LDS_STRIDE + kk * 32 + kq]);
            #pragma unroll
            for (int n = 0; n < 4; ++n)
                bfr[n] = *reinterpret_cast<const short8_t*>(
                    &Bs[(wc * 64 + n * 16 + r16) * LDS_STRIDE + kk * 32 + kq]);
            #pragma unroll
            for (int m = 0; m < 4; ++m)
                #pragma unroll
                for (int n = 0; n < 4; ++n)
                    acc[m][n] = __builtin_amdgcn_mfma_f32_16x16x32_bf16(af[m], bfr[n], acc[m][n], 0, 0, 0);
        }
        __syncthreads();
    }

    const int rbase = (lane >> 4) * 4;
    #pragma unroll
    for (int n = 0; n < 4; ++n) {
        int gcol = bn * 128 + wc * 64 + n * 16 + r16;
        float bv = bias[gcol];
        #pragma unroll
        for (int m = 0; m < 4; ++m) {
            #pragma unroll
            for (int r = 0; r < 4; ++r) {
                int grow = bm * 128 + wr * 64 + m * 16 + rbase + r;
                float v = acc[m][n][r] + bv;
                if (ACT == 1) v = 0.5f * v * (1.f + erff(v * 0.70710678118f));
                size_t orow = SCATTER ? (size_t)win_row_to_token(grow) : (size_t)grow;
                C[orow * (size_t)N + gcol] = f2bf(v);
            }
        }
    }
}

// ---------------- attention: one WAVE per (window, head), MFMA ----------------
// LDS (ushort, stride-72 rows like the GEMM): Q rows [0,49), K rows at KO,
// Vt (32 x j) at VO. P (64x64 bf16) aliases the dead Q/K region after QK.
// Padding discipline: QK fragment reads beyond row 48 read in-bounds garbage;
// S columns j>=49 are masked to -inf before exp; vt j-pad is zeroed so P=0
// never multiplies NaN; output rows i>=49 are never stored.
__global__ __launch_bounds__(64) void attn_kernel(
    const unsigned short* __restrict__ qkv, const float* __restrict__ scales,
    const float* __restrict__ rpbn, unsigned short* __restrict__ out)
{
    constexpr int QO = 0;
    constexpr int KO = 49 * 72;     // 3528
    constexpr int VO = 98 * 72;     // 7056
    constexpr int PO = 0;           // aliases Q+K after QK phase
    __shared__ unsigned short lds[98 * 72 + 32 * 72]; // 9360 ushort = 18.3 KB

    const int blk = blockIdx.x;
    const int h = blk & 7, wb = blk >> 3;
    const int lane = threadIdx.x;
    const int r16 = lane & 15, g4 = lane >> 4;

    const int wq = wb & 7, hb = (wb >> 3) & 7, dd = (wb >> 6) & 7, bb2 = wb >> 9;
    const int tok_base = ((bb2 * 8 + dd) * 56 + hb * 7) * 56 + wq * 7;
    const float sc = scales[h];

    // zero vt j-pad (granules 6,7 => j 48..63; j=48 rewritten below)
    {
        short8_t z = {};
        int d = lane >> 1, gi = 6 + (lane & 1);
        *reinterpret_cast<short8_t*>(&lds[VO + d * 72 + gi * 8]) = z;
    }
    // stage Q (scaled) and K with fused l2norm; granule = 8 bf16 = 16B, 4/row
    #pragma unroll
    for (int sel = 0; sel < 2; ++sel) {
        for (int c = lane; c < 196; c += 64) {
            int row = c >> 2, gi = c & 3;
            int tok = tok_base + (row / 7) * 56 + (row % 7);
            const unsigned short* gp = qkv + (size_t)tok * 768 + sel * 256 + h * 32 + gi * 8;
            short8_t raw = *reinterpret_cast<const short8_t*>(gp);
            float f[8]; float ss = 0.f;
            #pragma unroll
            for (int e = 0; e < 8; ++e) { f[e] = bf2f((unsigned short)raw[e]); ss += f[e] * f[e]; }
            ss += __shfl_xor(ss, 1); ss += __shfl_xor(ss, 2);  // quad = one row
            float inv = 1.f / fmaxf(sqrtf(ss), 1e-12f);
            if (sel == 0) inv *= sc;                            // fold logit scale into q
            short8_t o;
            #pragma unroll
            for (int e = 0; e < 8; ++e) o[e] = (short)f2bf(f[e] * inv);
            *reinterpret_cast<short8_t*>(&lds[(sel ? KO : QO) + row * 72 + gi * 8]) = o;
        }
    }
    // stage V transposed: vt[d][j]
    for (int c = lane; c < 1568; c += 64) {
        int j = c >> 5, d = c & 31;
        int tok = tok_base + (j / 7) * 56 + (j % 7);
        lds[VO + d * 72 + j] = qkv[(size_t)tok * 768 + 512 + h * 32 + d];
    }
    __syncthreads();

    // ---- QK^T: 4x4 tiles of 16x16, single K=32 MFMA each ----
    short8_t qf[4], kf[4];
    #pragma unroll
    for (int mi = 0; mi < 4; ++mi)
        qf[mi] = *reinterpret_cast<const short8_t*>(&lds[QO + (mi * 16 + r16) * 72 + g4 * 8]);
    #pragma unroll
    for (int ji = 0; ji < 4; ++ji)
        kf[ji] = *reinterpret_cast<const short8_t*>(&lds[KO + (ji * 16 + r16) * 72 + g4 * 8]);
    f32x4 acc[4][4] = {};
    #pragma unroll
    for (int mi = 0; mi < 4; ++mi)
        #pragma unroll
        for (int ji = 0; ji < 4; ++ji)
            acc[mi][ji] = __builtin_amdgcn_mfma_f32_16x16x32_bf16(qf[mi], kf[ji], acc[mi][ji], 0, 0, 0);
    __syncthreads();

    // ---- softmax over j (cross-lane within 16-groups + 4 ji regs), P -> LDS bf16 ----
    const float* rb = rpbn + h * 4096;
    #pragma unroll
    for (int mi = 0; mi < 4; ++mi) {
        #pragma unroll
        for (int r = 0; r < 4; ++r) {
            int i = mi * 16 + g4 * 4 + r;
            float s[4]; float m = -1e30f;
            #pragma unroll
            for (int ji = 0; ji < 4; ++ji) {
                int j = ji * 16 + r16;
                float v = acc[mi][ji][r] + rb[i * 64 + j];
                s[ji] = (j < 49) ? v : -1e30f;
                m = fmaxf(m, s[ji]);
            }
            m = fmaxf(m, __shfl_xor(m, 1)); m = fmaxf(m, __shfl_xor(m, 2));
            m = fmaxf(m, __shfl_xor(m, 4)); m = fmaxf(m, __shfl_xor(m, 8));
            float p[4]; float sum = 0.f;
            #pragma unroll
            for (int ji = 0; ji < 4; ++ji) {
                p[ji] = (s[ji] > -1e29f) ? __expf(s[ji] - m) : 0.f;
                sum += p[ji];
            }
            sum += __shfl_xor(sum, 1); sum += __shfl_xor(sum, 2);
            sum += __shfl_xor(sum, 4); sum += __shfl_xor(sum, 8);
            float rinv = 1.f / sum;
            #pragma unroll
            for (int ji = 0; ji < 4; ++ji) {
                int j = ji * 16 + r16;
                lds[PO + i * 72 + j] = f2bf(p[ji] * rinv);
            }
        }
    }
    __syncthreads();

    // ---- PV: out[i,d] = sum_j P[i,j] * Vt[d,j]; 4x2 tiles x 2 k-steps ----
    f32x4 acc2[4][2] = {};
    #pragma unroll
    for (int ks = 0; ks < 2; ++ks) {
        short8_t pf[4], vf[2];
        int ko = ks * 32 + g4 * 8;
        #pragma unroll
        for (int mi = 0; mi < 4; ++mi)
            pf[mi] = *reinterpret_cast<const short8_t*>(&lds[PO + (mi * 16 + r16) * 72 + ko]);
        #pragma unroll
        for (int ni = 0; ni < 2; ++ni)
            vf[ni] = *reinterpret_cast<const short8_t*>(&lds[VO + (ni * 16 + r16) * 72 + ko]);
        #pragma unroll
        for (int mi = 0; mi < 4; ++mi)
            #pragma unroll
            for (int ni = 0; ni < 2; ++ni)
                acc2[mi][ni] = __builtin_amdgcn_mfma_f32_16x16x32_bf16(pf[mi], vf[ni], acc2[mi][ni], 0, 0, 0);
    }

    #pragma unroll
    for (int mi = 0; mi < 4; ++mi)
        #pragma unroll
        for (int r = 0; r < 4; ++r) {
            int i = mi * 16 + g4 * 4 + r;
            if (i < 49) {
                size_t ob = (size_t)(wb * 49 + i) * 256 + h * 32;
                out[ob + r16]      = f2bf(acc2[mi][0][r]);
                out[ob + 16 + r16] = f2bf(acc2[mi][1][r]);
            }
        }
}

// ---------------- fused residual + LayerNorm (one wave per token) ----------------
template<int BASE_F32, int OUT_F32>
__global__ __launch_bounds__(256) void ln_add_kernel(
    const void* __restrict__ basev, const unsigned short* __restrict__ vin,
    const float* __restrict__ gg, const float* __restrict__ bb,
    void* __restrict__ outv)
{
    int token = blockIdx.x * 4 + (threadIdx.x >> 6);
    int lane = threadIdx.x & 63;
    size_t off = (size_t)token * 256 + lane * 4;
    short4 raw = *reinterpret_cast<const short4*>(&vin[off]);
    float f0 = bf2f((unsigned short)raw.x), f1 = bf2f((unsigned short)raw.y);
    float f2 = bf2f((unsigned short)raw.z), f3 = bf2f((unsigned short)raw.w);
    float s  = f0 + f1 + f2 + f3;
    float s2 = f0 * f0 + f1 * f1 + f2 * f2 + f3 * f3;
    #pragma unroll
    for (int m = 32; m >= 1; m >>= 1) { s += __shfl_xor(s, m, 64); s2 += __shfl_xor(s2, m, 64); }
    float mu = s * 0.00390625f;
    float var = s2 * 0.00390625f - mu * mu;
    float inv = rsqrtf(var + 1e-5f);

    float b0, b1v, b2, b3;
    if (BASE_F32) {
        float4 braw = *reinterpret_cast<const float4*>(&((const float*)basev)[off]);
        b0 = braw.x; b1v = braw.y; b2 = braw.z; b3 = braw.w;
    } else {
        short4 braw = *reinterpret_cast<const short4*>(&((const unsigned short*)basev)[off]);
        b0 = bf2f((unsigned short)braw.x); b1v = bf2f((unsigned short)braw.y);
        b2 = bf2f((unsigned short)braw.z); b3 = bf2f((unsigned short)braw.w);
    }
    float4 graw = *reinterpret_cast<const float4*>(&gg[lane * 4]);
    float4 brw2 = *reinterpret_cast<const float4*>(&bb[lane * 4]);
    float o0 = b0 + (f0 - mu) * inv * graw.x + brw2.x;
    float o1 = b1v + (f1 - mu) * inv * graw.y + brw2.y;
    float o2 = b2 + (f2 - mu) * inv * graw.z + brw2.z;
    float o3 = b3 + (f3 - mu) * inv * graw.w + brw2.w;
    if (OUT_F32) {
        float4 o; o.x = o0; o.y = o1; o.z = o2; o.w = o3;
        *reinterpret_cast<float4*>(&((float*)outv)[off]) = o;
    } else {
        short4 o;
        o.x = (short)f2bf(o0); o.y = (short)f2bf(o1);
        o.z = (short)f2bf(o2); o.w = (short)f2bf(o3);
        *reinterpret_cast<short4*>(&((unsigned short*)outv)[off]) = o;
    }
}

extern "C" void kernel_launch(void* const* d_in, const int* in_sizes, int n_in,
                              void* d_out, int out_size, void* d_ws, size_t ws_size,
                              hipStream_t stream) {
    const float* x      = (const float*)d_in[0];
    const float* qkv_w  = (const float*)d_in[1];
    const float* q_bias = (const float*)d_in[2];
    const float* v_bias = (const float*)d_in[3];
    const float* lscale = (const float*)d_in[4];
    const float* cpb_w1 = (const float*)d_in[5];
    const float* cpb_b1 = (const float*)d_in[6];
    const float* cpb_w2 = (const float*)d_in[7];
    const float* proj_w = (const float*)d_in[8];
    const float* proj_b = (const float*)d_in[9];
    const float* n1g    = (const float*)d_in[10];
    const float* n1b    = (const float*)d_in[11];
    const float* fc1_w  = (const float*)d_in[12];
    const float* fc1_b  = (const float*)d_in[13];
    const float* fc2_w  = (const float*)d_in[14];
    const float* fc2_b  = (const float*)d_in[15];
    const float* n2g    = (const float*)d_in[16];
    const float* n2b    = (const float*)d_in[17];
    const float* rct    = (const float*)d_in[18];
    const int*   rpi    = (const int*)d_in[19];

    char* ws = (char*)d_ws;
    // region 0 [0, 205520896): qkv bf16 (154.1MB), later h bf16 (205.5MB).
    // Small buffers in region-0 tail slack (dead before fc1 overwrites with h).
    unsigned short* qkv    = (unsigned short*)(ws);
    unsigned short* hbuf   = (unsigned short*)(ws);
    float*          scales = (float*)(ws + 160000000);
    float*          qkvb   = (float*)(ws + 160000128);
    float*          rpbn   = (float*)(ws + 160004096); // 8*64*64*4 = 131072 B
    // region 1 [205520896, 256901120): attn_o bf16 (window order), later x1 bf16
    unsigned short* attn_o = (unsigned short*)(ws + 205520896);
    unsigned short* x1     = (unsigned short*)(ws + 205520896);
    // region 2 [256901120, 308281344): projy bf16, later y bf16
    unsigned short* projy  = (unsigned short*)(ws + 256901120);

    const int M = 100352; // tokens

    prep_kernel<<<1, 256, 0, stream>>>(lscale, cpb_w1, cpb_b1, cpb_w2, q_bias, v_bias,
                                       rct, rpi, scales, rpbn, qkvb);
    // qkv = x @ qkv_w^T + qkv_bias   (natural token order); N-tile fast for A-reuse
    gemm_kernel<0, 0, 1><<<dim3(6, 784), 256, 0, stream>>>(x, qkv_w, qkvb, qkv, M, 768, 256);
    // attention: one wave per (window, head) -> window-ordered (Bw*49, 256)
    attn_kernel<<<16384, 64, 0, stream>>>(qkv, scales, rpbn, attn_o);
    // proj with row scatter back to natural order
    gemm_kernel<0, 1, 0><<<dim3(2, 784), 256, 0, stream>>>(attn_o, proj_w, proj_b, projy, M, 256, 256);
    // x1 = x + LN(proj_out)
    ln_add_kernel<1, 0><<<25088, 256, 0, stream>>>(x, projy, n1g, n1b, x1);
    // h = gelu(x1 @ fc1_w^T + fc1_b)
    gemm_kernel<1, 0, 0><<<dim3(8, 784), 256, 0, stream>>>(x1, fc1_w, fc1_b, hbuf, M, 1024, 256);
    // y = h @ fc2_w^T + fc2_b
    gemm_kernel<0, 0, 0><<<dim3(2, 784), 256, 0, stream>>>(hbuf, fc2_w, fc2_b, projy, M, 256, 1024);
    // out = x1 + LN(y)
    ln_add_kernel<0, 1><<<25088, 256, 0, stream>>>(x1, projy, n2g, n2b, d_out);
}

// Round 5
// 723.399 us; speedup vs baseline: 1.8615x; 1.1219x over previous
//
#include <hip/hip_runtime.h>
#include <hip/hip_bf16.h>

typedef __attribute__((ext_vector_type(8))) short short8_t;
typedef __attribute__((ext_vector_type(4))) float f32x4;

__device__ __forceinline__ float bf2f(unsigned short u) {
    return __uint_as_float(((unsigned)u) << 16);
}
__device__ __forceinline__ unsigned short f2bf(float f) {
    __hip_bfloat16 h = __float2bfloat16(f);
    return *reinterpret_cast<unsigned short*>(&h);
}

// async global->LDS, 16B per lane; LDS dest = wave-uniform base + lane*16
__device__ __forceinline__ void async16(const unsigned short* g, unsigned short* l) {
    __builtin_amdgcn_global_load_lds(
        (const __attribute__((address_space(1))) unsigned int*)g,
        (__attribute__((address_space(3))) unsigned int*)l,
        16, 0, 0);
}

// window-order row r (r = wb*49 + n) -> natural token index
__device__ __forceinline__ int win_row_to_token(int r) {
    int wb = r / 49, n = r - wb * 49;
    int wq = wb & 7, hb = (wb >> 3) & 7, d = (wb >> 6) & 7, b = wb >> 9;
    int hh = n / 7, ww2 = n - hh * 7;
    return ((b * 8 + d) * 56 + hb * 7 + hh) * 56 + wq * 7 + ww2;
}

// ---------------- f32 -> bf16 bulk convert (vectorized, grid-stride) ----------------
__global__ __launch_bounds__(256) void conv_kernel(
    const float* __restrict__ src, unsigned short* __restrict__ dst, int n4)
{
    int stride = gridDim.x * 256;
    for (int i = blockIdx.x * 256 + threadIdx.x; i < n4; i += stride) {
        float4 v = *reinterpret_cast<const float4*>(&src[(size_t)i * 4]);
        short4 o;
        o.x = (short)f2bf(v.x); o.y = (short)f2bf(v.y);
        o.z = (short)f2bf(v.z); o.w = (short)f2bf(v.w);
        *reinterpret_cast<short4*>(&dst[(size_t)i * 4]) = o;
    }
}

// ---------------- prep: scales, qkv bias, CPB-MLP -> rpbn [8][64][64] ----------------
__global__ __launch_bounds__(256) void prep_kernel(
    const float* __restrict__ logit_scale,
    const float* __restrict__ w1, const float* __restrict__ b1,
    const float* __restrict__ w2,
    const float* __restrict__ qb, const float* __restrict__ vb,
    const float* __restrict__ tabin, const int* __restrict__ rpi,
    float* __restrict__ scales, float* __restrict__ rpbn,
    float* __restrict__ qkvb)
{
    int t = threadIdx.x;
    if (t < 8) {
        float v = logit_scale[t];
        scales[t] = expf(fminf(v, 4.6051702f)); // ln(100)
    }
    for (int i = t; i < 768; i += 256) {
        float o;
        if (i < 256) o = qb[i];
        else if (i < 512) o = 0.f;
        else o = vb[i - 512];
        qkvb[i] = o;
    }
    for (int i = t; i < 8 * 4096; i += 256) rpbn[i] = 0.f;
    __shared__ float table[169][8];
    for (int i = t; i < 169; i += 256) {
        float c0 = tabin[i * 3], c1 = tabin[i * 3 + 1], c2 = tabin[i * 3 + 2];
        float acc[8] = {0.f, 0.f, 0.f, 0.f, 0.f, 0.f, 0.f, 0.f};
        for (int j = 0; j < 512; ++j) {
            float hv = c0 * w1[j * 3] + c1 * w1[j * 3 + 1] + c2 * w1[j * 3 + 2] + b1[j];
            hv = fmaxf(hv, 0.f);
            #pragma unroll
            for (int h = 0; h < 8; ++h) acc[h] += hv * w2[h * 512 + j];
        }
        #pragma unroll
        for (int h = 0; h < 8; ++h) table[i][h] = acc[h];
    }
    __syncthreads();
    for (int e = t; e < 2401; e += 256) {
        int i = e / 49, j = e - i * 49;
        int idx = rpi[e];
        #pragma unroll
        for (int h = 0; h < 8; ++h) {
            float xv = table[idx][h];
            rpbn[h * 4096 + i * 64 + j] = 16.f / (1.f + expf(-xv));
        }
    }
}

// ---------------- GEMM: C[M,N] = A[M,K] * W[N,K]^T + bias (all bf16 in) ----------------
// Staging: global_load_lds dwordx4, linear LDS [128][64], source-granule XOR swizzle
// g_src = (lane&7)^(lane>>3); fragment ds_read applies granule ^= (row&7).
template<int ACT, int SCATTER>
__global__ __launch_bounds__(256) void gemm_kernel(
    const unsigned short* __restrict__ A, const unsigned short* __restrict__ W,
    const float* __restrict__ bias, unsigned short* __restrict__ C,
    int M, int N, int K)
{
    __shared__ unsigned short As[128 * 64];
    __shared__ unsigned short Bs[128 * 64];
    const int tid = threadIdx.x;
    const int lane = tid & 63, wv = tid >> 6;
    const int wr = wv >> 1, wc = wv & 1;
    const int bm = blockIdx.y, bn = blockIdx.x;
    const size_t arow0 = (size_t)bm * 128;
    const size_t brow0 = (size_t)bn * 128;
    const int r16 = lane & 15, g4 = lane >> 4;
    const int lrow = lane >> 3;                  // 0..7 row within 8-row issue
    const int lgran = (lane & 7) ^ lrow;         // swizzled source granule
    f32x4 acc[4][4] = {};

    for (int kt = 0; kt < K; kt += 64) {
        #pragma unroll
        for (int i = 0; i < 4; ++i) {
            int row = wv * 32 + i * 8;           // base row of this 8-row issue
            async16(&A[(arow0 + row + lrow) * (size_t)K + kt + lgran * 8],
                    &As[row * 64]);
            async16(&W[(brow0 + row + lrow) * (size_t)K + kt + lgran * 8],
                    &Bs[row * 64]);
        }
        __syncthreads();
        #pragma unroll
        for (int kk = 0; kk < 2; ++kk) {
            short8_t af[4], bfr[4];
            #pragma unroll
            for (int m = 0; m < 4; ++m) {
                int row = wr * 64 + m * 16 + r16;
                int g = (kk * 4 + g4) ^ (row & 7);
                af[m] = *reinterpret_cast<const short8_t*>(&As[row * 64 + g * 8]);
            }
            #pragma unroll
            for (int n = 0; n < 4; ++n) {
                int row = wc * 64 + n * 16 + r16;
                int g = (kk * 4 + g4) ^ (row & 7);
                bfr[n] = *reinterpret_cast<const short8_t*>(&Bs[row * 64 + g * 8]);
            }
            #pragma unroll
            for (int m = 0; m < 4; ++m)
                #pragma unroll
                for (int n = 0; n < 4; ++n)
                    acc[m][n] = __builtin_amdgcn_mfma_f32_16x16x32_bf16(af[m], bfr[n], acc[m][n], 0, 0, 0);
        }
        __syncthreads();
    }

    const int rbase = g4 * 4;
    #pragma unroll
    for (int n = 0; n < 4; ++n) {
        int gcol = bn * 128 + wc * 64 + n * 16 + r16;
        float bv = bias[gcol];
        #pragma unroll
        for (int m = 0; m < 4; ++m) {
            #pragma unroll
            for (int r = 0; r < 4; ++r) {
                int grow = bm * 128 + wr * 64 + m * 16 + rbase + r;
                float v = acc[m][n][r] + bv;
                if (ACT == 1) v = 0.5f * v * (1.f + erff(v * 0.70710678118f));
                size_t orow = SCATTER ? (size_t)win_row_to_token(grow) : (size_t)grow;
                C[orow * (size_t)N + gcol] = f2bf(v);
            }
        }
    }
}

// ---------------- attention: one WAVE per (window, head), MFMA ----------------
__global__ __launch_bounds__(64) void attn_kernel(
    const unsigned short* __restrict__ qkv, const float* __restrict__ scales,
    const float* __restrict__ rpbn, unsigned short* __restrict__ out)
{
    constexpr int QO = 0;
    constexpr int KO = 49 * 72;
    constexpr int VO = 98 * 72;
    constexpr int PO = 0;
    __shared__ unsigned short lds[98 * 72 + 32 * 72];

    const int blk = blockIdx.x;
    const int h = blk & 7, wb = blk >> 3;
    const int lane = threadIdx.x;
    const int r16 = lane & 15, g4 = lane >> 4;

    const int wq = wb & 7, hb = (wb >> 3) & 7, dd = (wb >> 6) & 7, bb2 = wb >> 9;
    const int tok_base = ((bb2 * 8 + dd) * 56 + hb * 7) * 56 + wq * 7;
    const float sc = scales[h];

    {
        short8_t z = {};
        int d = lane >> 1, gi = 6 + (lane & 1);
        *reinterpret_cast<short8_t*>(&lds[VO + d * 72 + gi * 8]) = z;
    }
    #pragma unroll
    for (int sel = 0; sel < 2; ++sel) {
        for (int c = lane; c < 196; c += 64) {
            int row = c >> 2, gi = c & 3;
            int tok = tok_base + (row / 7) * 56 + (row % 7);
            const unsigned short* gp = qkv + (size_t)tok * 768 + sel * 256 + h * 32 + gi * 8;
            short8_t raw = *reinterpret_cast<const short8_t*>(gp);
            float f[8]; float ss = 0.f;
            #pragma unroll
            for (int e = 0; e < 8; ++e) { f[e] = bf2f((unsigned short)raw[e]); ss += f[e] * f[e]; }
            ss += __shfl_xor(ss, 1); ss += __shfl_xor(ss, 2);
            float inv = 1.f / fmaxf(sqrtf(ss), 1e-12f);
            if (sel == 0) inv *= sc;
            short8_t o;
            #pragma unroll
            for (int e = 0; e < 8; ++e) o[e] = (short)f2bf(f[e] * inv);
            *reinterpret_cast<short8_t*>(&lds[(sel ? KO : QO) + row * 72 + gi * 8]) = o;
        }
    }
    for (int c = lane; c < 1568; c += 64) {
        int j = c >> 5, d = c & 31;
        int tok = tok_base + (j / 7) * 56 + (j % 7);
        lds[VO + d * 72 + j] = qkv[(size_t)tok * 768 + 512 + h * 32 + d];
    }
    __syncthreads();

    short8_t qf[4], kf[4];
    #pragma unroll
    for (int mi = 0; mi < 4; ++mi)
        qf[mi] = *reinterpret_cast<const short8_t*>(&lds[QO + (mi * 16 + r16) * 72 + g4 * 8]);
    #pragma unroll
    for (int ji = 0; ji < 4; ++ji)
        kf[ji] = *reinterpret_cast<const short8_t*>(&lds[KO + (ji * 16 + r16) * 72 + g4 * 8]);
    f32x4 acc[4][4] = {};
    #pragma unroll
    for (int mi = 0; mi < 4; ++mi)
        #pragma unroll
        for (int ji = 0; ji < 4; ++ji)
            acc[mi][ji] = __builtin_amdgcn_mfma_f32_16x16x32_bf16(qf[mi], kf[ji], acc[mi][ji], 0, 0, 0);
    __syncthreads();

    const float* rb = rpbn + h * 4096;
    #pragma unroll
    for (int mi = 0; mi < 4; ++mi) {
        #pragma unroll
        for (int r = 0; r < 4; ++r) {
            int i = mi * 16 + g4 * 4 + r;
            float s[4]; float m = -1e30f;
            #pragma unroll
            for (int ji = 0; ji < 4; ++ji) {
                int j = ji * 16 + r16;
                float v = acc[mi][ji][r] + rb[i * 64 + j];
                s[ji] = (j < 49) ? v : -1e30f;
                m = fmaxf(m, s[ji]);
            }
            m = fmaxf(m, __shfl_xor(m, 1)); m = fmaxf(m, __shfl_xor(m, 2));
            m = fmaxf(m, __shfl_xor(m, 4)); m = fmaxf(m, __shfl_xor(m, 8));
            float p[4]; float sum = 0.f;
            #pragma unroll
            for (int ji = 0; ji < 4; ++ji) {
                p[ji] = (s[ji] > -1e29f) ? __expf(s[ji] - m) : 0.f;
                sum += p[ji];
            }
            sum += __shfl_xor(sum, 1); sum += __shfl_xor(sum, 2);
            sum += __shfl_xor(sum, 4); sum += __shfl_xor(sum, 8);
            float rinv = 1.f / sum;
            #pragma unroll
            for (int ji = 0; ji < 4; ++ji) {
                int j = ji * 16 + r16;
                lds[PO + i * 72 + j] = f2bf(p[ji] * rinv);
            }
        }
    }
    __syncthreads();

    f32x4 acc2[4][2] = {};
    #pragma unroll
    for (int ks = 0; ks < 2; ++ks) {
        short8_t pf[4], vf[2];
        int ko = ks * 32 + g4 * 8;
        #pragma unroll
        for (int mi = 0; mi < 4; ++mi)
            pf[mi] = *reinterpret_cast<const short8_t*>(&lds[PO + (mi * 16 + r16) * 72 + ko]);
        #pragma unroll
        for (int ni = 0; ni < 2; ++ni)
            vf[ni] = *reinterpret_cast<const short8_t*>(&lds[VO + (ni * 16 + r16) * 72 + ko]);
        #pragma unroll
        for (int mi = 0; mi < 4; ++mi)
            #pragma unroll
            for (int ni = 0; ni < 2; ++ni)
                acc2[mi][ni] = __builtin_amdgcn_mfma_f32_16x16x32_bf16(pf[mi], vf[ni], acc2[mi][ni], 0, 0, 0);
    }

    #pragma unroll
    for (int mi = 0; mi < 4; ++mi)
        #pragma unroll
        for (int r = 0; r < 4; ++r) {
            int i = mi * 16 + g4 * 4 + r;
            if (i < 49) {
                size_t ob = (size_t)(wb * 49 + i) * 256 + h * 32;
                out[ob + r16]      = f2bf(acc2[mi][0][r]);
                out[ob + 16 + r16] = f2bf(acc2[mi][1][r]);
            }
        }
}

// ---------------- fused residual + LayerNorm (one wave per token) ----------------
template<int BASE_F32, int OUT_F32>
__global__ __launch_bounds__(256) void ln_add_kernel(
    const void* __restrict__ basev, const unsigned short* __restrict__ vin,
    const float* __restrict__ gg, const float* __restrict__ bb,
    void* __restrict__ outv)
{
    int token = blockIdx.x * 4 + (threadIdx.x >> 6);
    int lane = threadIdx.x & 63;
    size_t off = (size_t)token * 256 + lane * 4;
    short4 raw = *reinterpret_cast<const short4*>(&vin[off]);
    float f0 = bf2f((unsigned short)raw.x), f1 = bf2f((unsigned short)raw.y);
    float f2 = bf2f((unsigned short)raw.z), f3 = bf2f((unsigned short)raw.w);
    float s  = f0 + f1 + f2 + f3;
    float s2 = f0 * f0 + f1 * f1 + f2 * f2 + f3 * f3;
    #pragma unroll
    for (int m = 32; m >= 1; m >>= 1) { s += __shfl_xor(s, m, 64); s2 += __shfl_xor(s2, m, 64); }
    float mu = s * 0.00390625f;
    float var = s2 * 0.00390625f - mu * mu;
    float inv = rsqrtf(var + 1e-5f);

    float b0, b1v, b2, b3;
    if (BASE_F32) {
        float4 braw = *reinterpret_cast<const float4*>(&((const float*)basev)[off]);
        b0 = braw.x; b1v = braw.y; b2 = braw.z; b3 = braw.w;
    } else {
        short4 braw = *reinterpret_cast<const short4*>(&((const unsigned short*)basev)[off]);
        b0 = bf2f((unsigned short)braw.x); b1v = bf2f((unsigned short)braw.y);
        b2 = bf2f((unsigned short)braw.z); b3 = bf2f((unsigned short)braw.w);
    }
    float4 graw = *reinterpret_cast<const float4*>(&gg[lane * 4]);
    float4 brw2 = *reinterpret_cast<const float4*>(&bb[lane * 4]);
    float o0 = b0 + (f0 - mu) * inv * graw.x + brw2.x;
    float o1 = b1v + (f1 - mu) * inv * graw.y + brw2.y;
    float o2 = b2 + (f2 - mu) * inv * graw.z + brw2.z;
    float o3 = b3 + (f3 - mu) * inv * graw.w + brw2.w;
    if (OUT_F32) {
        float4 o; o.x = o0; o.y = o1; o.z = o2; o.w = o3;
        *reinterpret_cast<float4*>(&((float*)outv)[off]) = o;
    } else {
        short4 o;
        o.x = (short)f2bf(o0); o.y = (short)f2bf(o1);
        o.z = (short)f2bf(o2); o.w = (short)f2bf(o3);
        *reinterpret_cast<short4*>(&((unsigned short*)outv)[off]) = o;
    }
}

extern "C" void kernel_launch(void* const* d_in, const int* in_sizes, int n_in,
                              void* d_out, int out_size, void* d_ws, size_t ws_size,
                              hipStream_t stream) {
    const float* x      = (const float*)d_in[0];
    const float* qkv_w  = (const float*)d_in[1];
    const float* q_bias = (const float*)d_in[2];
    const float* v_bias = (const float*)d_in[3];
    const float* lscale = (const float*)d_in[4];
    const float* cpb_w1 = (const float*)d_in[5];
    const float* cpb_b1 = (const float*)d_in[6];
    const float* cpb_w2 = (const float*)d_in[7];
    const float* proj_w = (const float*)d_in[8];
    const float* proj_b = (const float*)d_in[9];
    const float* n1g    = (const float*)d_in[10];
    const float* n1b    = (const float*)d_in[11];
    const float* fc1_w  = (const float*)d_in[12];
    const float* fc1_b  = (const float*)d_in[13];
    const float* fc2_w  = (const float*)d_in[14];
    const float* fc2_b  = (const float*)d_in[15];
    const float* n2g    = (const float*)d_in[16];
    const float* n2b    = (const float*)d_in[17];
    const float* rct    = (const float*)d_in[18];
    const int*   rpi    = (const int*)d_in[19];

    char* ws = (char*)d_ws;
    // [0, 154,140,672): qkv bf16 (steps qkv..attn); hbuf bf16 [0, 205,520,896) (fc1..fc2)
    unsigned short* qkv    = (unsigned short*)(ws);
    unsigned short* hbuf   = (unsigned short*)(ws);
    // [154,140,672, 205,520,896): attn_o (attn..proj); overlapped later by hbuf
    unsigned short* attn_o = (unsigned short*)(ws + 154140672);
    // [205,520,896, 256,901,120): xb bf16 (conv..qkv GEMM), then x1 (ln1..ln2)
    unsigned short* xb     = (unsigned short*)(ws + 205520896);
    unsigned short* x1     = (unsigned short*)(ws + 205520896);
    // [256,901,120, 308,281,344): projy (proj..ln1), then y (fc2..ln2)
    unsigned short* projy  = (unsigned short*)(ws + 256901120);
    // bf16 weights + small buffers
    unsigned short* wqkv   = (unsigned short*)(ws + 308281344); //   393,216 B
    unsigned short* wproj  = (unsigned short*)(ws + 308674560); //   131,072 B
    unsigned short* wfc1   = (unsigned short*)(ws + 308805632); //   524,288 B
    unsigned short* wfc2   = (unsigned short*)(ws + 309329920); //   524,288 B
    float*          rpbn   = (float*)(ws + 309854208);          //   524,288 B
    float*          scales = (float*)(ws + 310378496);
    float*          qkvb   = (float*)(ws + 310378528);

    const int M = 100352;

    conv_kernel<<<2048, 256, 0, stream>>>(x, xb, 25690112 / 4);
    conv_kernel<<<192, 256, 0, stream>>>(qkv_w, wqkv, 196608 / 4);
    conv_kernel<<<64, 256, 0, stream>>>(proj_w, wproj, 65536 / 4);
    conv_kernel<<<256, 256, 0, stream>>>(fc1_w, wfc1, 262144 / 4);
    conv_kernel<<<256, 256, 0, stream>>>(fc2_w, wfc2, 262144 / 4);
    prep_kernel<<<1, 256, 0, stream>>>(lscale, cpb_w1, cpb_b1, cpb_w2, q_bias, v_bias,
                                       rct, rpi, scales, rpbn, qkvb);
    // qkv = xb @ wqkv^T + qkv_bias
    gemm_kernel<0, 0><<<dim3(6, 784), 256, 0, stream>>>(xb, wqkv, qkvb, qkv, M, 768, 256);
    // attention -> window-ordered (Bw*49, 256)
    attn_kernel<<<16384, 64, 0, stream>>>(qkv, scales, rpbn, attn_o);
    // proj with scatter to natural order
    gemm_kernel<0, 1><<<dim3(2, 784), 256, 0, stream>>>(attn_o, wproj, proj_b, projy, M, 256, 256);
    // x1 = x + LN(projy)
    ln_add_kernel<1, 0><<<25088, 256, 0, stream>>>(x, projy, n1g, n1b, x1);
    // h = gelu(x1 @ wfc1^T + fc1_b)
    gemm_kernel<1, 0><<<dim3(8, 784), 256, 0, stream>>>(x1, wfc1, fc1_b, hbuf, M, 1024, 256);
    // y = h @ wfc2^T + fc2_b
    gemm_kernel<0, 0><<<dim3(2, 784), 256, 0, stream>>>(hbuf, wfc2, fc2_b, projy, M, 256, 1024);
    // out = x1 + LN(y)
    ln_add_kernel<0, 1><<<25088, 256, 0, stream>>>(x1, projy, n2g, n2b, d_out);
}

// Round 6
// 696.958 us; speedup vs baseline: 1.9321x; 1.0379x over previous
//
#include <hip/hip_runtime.h>
#include <hip/hip_bf16.h>

typedef __attribute__((ext_vector_type(8))) short short8_t;
typedef __attribute__((ext_vector_type(4))) float f32x4;

__device__ __forceinline__ float bf2f(unsigned short u) {
    return __uint_as_float(((unsigned)u) << 16);
}
__device__ __forceinline__ unsigned short f2bf(float f) {
    __hip_bfloat16 h = __float2bfloat16(f);
    return *reinterpret_cast<unsigned short*>(&h);
}

// async global->LDS, 16B per lane; LDS dest = wave-uniform base + lane*16
__device__ __forceinline__ void async16(const unsigned short* g, unsigned short* l) {
    __builtin_amdgcn_global_load_lds(
        (const __attribute__((address_space(1))) unsigned int*)g,
        (__attribute__((address_space(3))) unsigned int*)l,
        16, 0, 0);
}

// window-order row r (r = wb*49 + n) -> natural token index
__device__ __forceinline__ int win_row_to_token(int r) {
    int wb = r / 49, n = r - wb * 49;
    int wq = wb & 7, hb = (wb >> 3) & 7, d = (wb >> 6) & 7, b = wb >> 9;
    int hh = n / 7, ww2 = n - hh * 7;
    return ((b * 8 + d) * 56 + hb * 7 + hh) * 56 + wq * 7 + ww2;
}

// ---------------- f32 -> bf16 bulk convert ----------------
__global__ __launch_bounds__(256) void conv_kernel(
    const float* __restrict__ src, unsigned short* __restrict__ dst, int n4)
{
    int stride = gridDim.x * 256;
    for (int i = blockIdx.x * 256 + threadIdx.x; i < n4; i += stride) {
        float4 v = *reinterpret_cast<const float4*>(&src[(size_t)i * 4]);
        short4 o;
        o.x = (short)f2bf(v.x); o.y = (short)f2bf(v.y);
        o.z = (short)f2bf(v.z); o.w = (short)f2bf(v.w);
        *reinterpret_cast<short4*>(&dst[(size_t)i * 4]) = o;
    }
}

// ---------------- prep: scales, qkv bias, CPB-MLP -> rpbn [8][64][64] ----------------
__global__ __launch_bounds__(256) void prep_kernel(
    const float* __restrict__ logit_scale,
    const float* __restrict__ w1, const float* __restrict__ b1,
    const float* __restrict__ w2,
    const float* __restrict__ qb, const float* __restrict__ vb,
    const float* __restrict__ tabin, const int* __restrict__ rpi,
    float* __restrict__ scales, float* __restrict__ rpbn,
    float* __restrict__ qkvb)
{
    int t = threadIdx.x;
    if (t < 8) {
        float v = logit_scale[t];
        scales[t] = expf(fminf(v, 4.6051702f)); // ln(100)
    }
    for (int i = t; i < 768; i += 256) {
        float o;
        if (i < 256) o = qb[i];
        else if (i < 512) o = 0.f;
        else o = vb[i - 512];
        qkvb[i] = o;
    }
    for (int i = t; i < 8 * 4096; i += 256) rpbn[i] = 0.f;
    __shared__ float table[169][8];
    for (int i = t; i < 169; i += 256) {
        float c0 = tabin[i * 3], c1 = tabin[i * 3 + 1], c2 = tabin[i * 3 + 2];
        float acc[8] = {0.f, 0.f, 0.f, 0.f, 0.f, 0.f, 0.f, 0.f};
        for (int j = 0; j < 512; ++j) {
            float hv = c0 * w1[j * 3] + c1 * w1[j * 3 + 1] + c2 * w1[j * 3 + 2] + b1[j];
            hv = fmaxf(hv, 0.f);
            #pragma unroll
            for (int h = 0; h < 8; ++h) acc[h] += hv * w2[h * 512 + j];
        }
        #pragma unroll
        for (int h = 0; h < 8; ++h) table[i][h] = acc[h];
    }
    __syncthreads();
    for (int e = t; e < 2401; e += 256) {
        int i = e / 49, j = e - i * 49;
        int idx = rpi[e];
        #pragma unroll
        for (int h = 0; h < 8; ++h) {
            float xv = table[idx][h];
            rpbn[h * 4096 + i * 64 + j] = 16.f / (1.f + expf(-xv));
        }
    }
}

// ---------------- GEMM: C[M,N] = A[M,K] * W[N,K]^T + bias (bf16 in/out) ----------------
// 128x128 tile, BK=64, 4 waves. Double-buffered global_load_lds staging (2-phase
// pipeline), XCD-aware block swizzle (1-D grid), LDS-transpose epilogue for
// coalesced 16B/lane stores.
template<int ACT, int SCATTER>
__global__ __launch_bounds__(256) void gemm_kernel(
    const unsigned short* __restrict__ A, const unsigned short* __restrict__ W,
    const float* __restrict__ bias, unsigned short* __restrict__ C,
    int M, int N, int K, int ntn)
{
    __shared__ unsigned short smem[32768]; // As[2]:16KB x2? layout: As(buf)=buf*8192, Bs(buf)=16384+buf*8192 (ushort idx)
    const int tid = threadIdx.x;
    const int lane = tid & 63, wv = tid >> 6;
    const int wr = wv >> 1, wc = wv & 1;
    // XCD swizzle: contiguous virt range per XCD; consecutive virt share A-tile
    const int nwg = gridDim.x;
    const int virt = (blockIdx.x & 7) * (nwg >> 3) + (blockIdx.x >> 3);
    const int bn = virt % ntn, bm = virt / ntn;
    const size_t arow0 = (size_t)bm * 128;
    const size_t brow0 = (size_t)bn * 128;
    const int r16 = lane & 15, g4 = lane >> 4;
    const int lrow = lane >> 3;              // 0..7 row within 8-row issue
    const int lgran = (lane & 7) ^ lrow;     // swizzled source granule
    f32x4 acc[4][4] = {};

    auto STAGE = [&](int buf, int kt) {
        unsigned short* As = smem + buf * 8192;
        unsigned short* Bs = smem + 16384 + buf * 8192;
        #pragma unroll
        for (int i = 0; i < 4; ++i) {
            int row = wv * 32 + i * 8;
            async16(&A[(arow0 + row + lrow) * (size_t)K + kt + lgran * 8], &As[row * 64]);
            async16(&W[(brow0 + row + lrow) * (size_t)K + kt + lgran * 8], &Bs[row * 64]);
        }
    };
    auto COMPUTE = [&](int buf) {
        unsigned short* As = smem + buf * 8192;
        unsigned short* Bs = smem + 16384 + buf * 8192;
        #pragma unroll
        for (int kk = 0; kk < 2; ++kk) {
            short8_t af[4], bfr[4];
            #pragma unroll
            for (int m = 0; m < 4; ++m) {
                int row = wr * 64 + m * 16 + r16;
                int g = (kk * 4 + g4) ^ (row & 7);
                af[m] = *reinterpret_cast<const short8_t*>(&As[row * 64 + g * 8]);
            }
            #pragma unroll
            for (int n = 0; n < 4; ++n) {
                int row = wc * 64 + n * 16 + r16;
                int g = (kk * 4 + g4) ^ (row & 7);
                bfr[n] = *reinterpret_cast<const short8_t*>(&Bs[row * 64 + g * 8]);
            }
            #pragma unroll
            for (int m = 0; m < 4; ++m)
                #pragma unroll
                for (int n = 0; n < 4; ++n)
                    acc[m][n] = __builtin_amdgcn_mfma_f32_16x16x32_bf16(af[m], bfr[n], acc[m][n], 0, 0, 0);
        }
    };

    STAGE(0, 0);
    __syncthreads();                 // drains vmcnt(0): buf0 ready
    int cur = 0;
    for (int kt = 64; kt < K; kt += 64) {
        STAGE(cur ^ 1, kt);          // loads in flight during compute
        COMPUTE(cur);
        __syncthreads();             // drain: next buffer ready
        cur ^= 1;
    }
    COMPUTE(cur);
    __syncthreads();                 // all LDS reads done before Cs overwrite

    // ---- epilogue: acc -> per-wave LDS tile (stride 76) -> coalesced stores ----
    unsigned short* Cs = smem + wv * 4864;   // 64 x 76 ushorts
    const int rbase = g4 * 4;
    #pragma unroll
    for (int n = 0; n < 4; ++n) {
        float bv = bias[bn * 128 + wc * 64 + n * 16 + r16];
        #pragma unroll
        for (int m = 0; m < 4; ++m)
            #pragma unroll
            for (int r = 0; r < 4; ++r) {
                float v = acc[m][n][r] + bv;
                if (ACT == 1) v = 0.5f * v * (1.f + erff(v * 0.70710678118f));
                Cs[(m * 16 + rbase + r) * 76 + n * 16 + r16] = f2bf(v);
            }
    }
    __syncthreads();
    const int srow = lane >> 3, scol = (lane & 7) * 8;
    const int gcol0 = bn * 128 + wc * 64;
    #pragma unroll
    for (int rr = 0; rr < 8; ++rr) {
        int lr = rr * 8 + srow;
        int grow = bm * 128 + wr * 64 + lr;
        size_t orow = SCATTER ? (size_t)win_row_to_token(grow) : (size_t)grow;
        short8_t vv = *reinterpret_cast<const short8_t*>(&Cs[lr * 76 + scol]);
        *reinterpret_cast<short8_t*>(&C[orow * (size_t)N + gcol0 + scol]) = vv;
    }
}

// ---------------- attention: one WAVE per (window, head), MFMA ----------------
__global__ __launch_bounds__(64) void attn_kernel(
    const unsigned short* __restrict__ qkv, const float* __restrict__ scales,
    const float* __restrict__ rpbn, unsigned short* __restrict__ out)
{
    constexpr int QO = 0;
    constexpr int KO = 49 * 72;
    constexpr int VO = 98 * 72;
    constexpr int PO = 0;
    __shared__ unsigned short lds[98 * 72 + 32 * 72];

    const int blk = blockIdx.x;
    const int h = blk & 7, wb = blk >> 3;
    const int lane = threadIdx.x;
    const int r16 = lane & 15, g4 = lane >> 4;

    const int wq = wb & 7, hb = (wb >> 3) & 7, dd = (wb >> 6) & 7, bb2 = wb >> 9;
    const int tok_base = ((bb2 * 8 + dd) * 56 + hb * 7) * 56 + wq * 7;
    const float sc = scales[h];

    {
        short8_t z = {};
        int d = lane >> 1, gi = 6 + (lane & 1);
        *reinterpret_cast<short8_t*>(&lds[VO + d * 72 + gi * 8]) = z;
    }
    #pragma unroll
    for (int sel = 0; sel < 2; ++sel) {
        for (int c = lane; c < 196; c += 64) {
            int row = c >> 2, gi = c & 3;
            int tok = tok_base + (row / 7) * 56 + (row % 7);
            const unsigned short* gp = qkv + (size_t)tok * 768 + sel * 256 + h * 32 + gi * 8;
            short8_t raw = *reinterpret_cast<const short8_t*>(gp);
            float f[8]; float ss = 0.f;
            #pragma unroll
            for (int e = 0; e < 8; ++e) { f[e] = bf2f((unsigned short)raw[e]); ss += f[e] * f[e]; }
            ss += __shfl_xor(ss, 1); ss += __shfl_xor(ss, 2);
            float inv = 1.f / fmaxf(sqrtf(ss), 1e-12f);
            if (sel == 0) inv *= sc;
            short8_t o;
            #pragma unroll
            for (int e = 0; e < 8; ++e) o[e] = (short)f2bf(f[e] * inv);
            *reinterpret_cast<short8_t*>(&lds[(sel ? KO : QO) + row * 72 + gi * 8]) = o;
        }
    }
    for (int c = lane; c < 1568; c += 64) {
        int j = c >> 5, d = c & 31;
        int tok = tok_base + (j / 7) * 56 + (j % 7);
        lds[VO + d * 72 + j] = qkv[(size_t)tok * 768 + 512 + h * 32 + d];
    }
    __syncthreads();

    short8_t qf[4], kf[4];
    #pragma unroll
    for (int mi = 0; mi < 4; ++mi)
        qf[mi] = *reinterpret_cast<const short8_t*>(&lds[QO + (mi * 16 + r16) * 72 + g4 * 8]);
    #pragma unroll
    for (int ji = 0; ji < 4; ++ji)
        kf[ji] = *reinterpret_cast<const short8_t*>(&lds[KO + (ji * 16 + r16) * 72 + g4 * 8]);
    f32x4 acc[4][4] = {};
    #pragma unroll
    for (int mi = 0; mi < 4; ++mi)
        #pragma unroll
        for (int ji = 0; ji < 4; ++ji)
            acc[mi][ji] = __builtin_amdgcn_mfma_f32_16x16x32_bf16(qf[mi], kf[ji], acc[mi][ji], 0, 0, 0);
    __syncthreads();

    const float* rb = rpbn + h * 4096;
    #pragma unroll
    for (int mi = 0; mi < 4; ++mi) {
        #pragma unroll
        for (int r = 0; r < 4; ++r) {
            int i = mi * 16 + g4 * 4 + r;
            float s[4]; float m = -1e30f;
            #pragma unroll
            for (int ji = 0; ji < 4; ++ji) {
                int j = ji * 16 + r16;
                float v = acc[mi][ji][r] + rb[i * 64 + j];
                s[ji] = (j < 49) ? v : -1e30f;
                m = fmaxf(m, s[ji]);
            }
            m = fmaxf(m, __shfl_xor(m, 1)); m = fmaxf(m, __shfl_xor(m, 2));
            m = fmaxf(m, __shfl_xor(m, 4)); m = fmaxf(m, __shfl_xor(m, 8));
            float p[4]; float sum = 0.f;
            #pragma unroll
            for (int ji = 0; ji < 4; ++ji) {
                p[ji] = (s[ji] > -1e29f) ? __expf(s[ji] - m) : 0.f;
                sum += p[ji];
            }
            sum += __shfl_xor(sum, 1); sum += __shfl_xor(sum, 2);
            sum += __shfl_xor(sum, 4); sum += __shfl_xor(sum, 8);
            float rinv = 1.f / sum;
            #pragma unroll
            for (int ji = 0; ji < 4; ++ji) {
                int j = ji * 16 + r16;
                lds[PO + i * 72 + j] = f2bf(p[ji] * rinv);
            }
        }
    }
    __syncthreads();

    f32x4 acc2[4][2] = {};
    #pragma unroll
    for (int ks = 0; ks < 2; ++ks) {
        short8_t pf[4], vf[2];
        int ko = ks * 32 + g4 * 8;
        #pragma unroll
        for (int mi = 0; mi < 4; ++mi)
            pf[mi] = *reinterpret_cast<const short8_t*>(&lds[PO + (mi * 16 + r16) * 72 + ko]);
        #pragma unroll
        for (int ni = 0; ni < 2; ++ni)
            vf[ni] = *reinterpret_cast<const short8_t*>(&lds[VO + (ni * 16 + r16) * 72 + ko]);
        #pragma unroll
        for (int mi = 0; mi < 4; ++mi)
            #pragma unroll
            for (int ni = 0; ni < 2; ++ni)
                acc2[mi][ni] = __builtin_amdgcn_mfma_f32_16x16x32_bf16(pf[mi], vf[ni], acc2[mi][ni], 0, 0, 0);
    }

    #pragma unroll
    for (int mi = 0; mi < 4; ++mi)
        #pragma unroll
        for (int r = 0; r < 4; ++r) {
            int i = mi * 16 + g4 * 4 + r;
            if (i < 49) {
                size_t ob = (size_t)(wb * 49 + i) * 256 + h * 32;
                out[ob + r16]      = f2bf(acc2[mi][0][r]);
                out[ob + 16 + r16] = f2bf(acc2[mi][1][r]);
            }
        }
}

// ---------------- fused residual + LayerNorm (one wave per token) ----------------
template<int BASE_F32, int OUT_F32>
__global__ __launch_bounds__(256) void ln_add_kernel(
    const void* __restrict__ basev, const unsigned short* __restrict__ vin,
    const float* __restrict__ gg, const float* __restrict__ bb,
    void* __restrict__ outv)
{
    int token = blockIdx.x * 4 + (threadIdx.x >> 6);
    int lane = threadIdx.x & 63;
    size_t off = (size_t)token * 256 + lane * 4;
    short4 raw = *reinterpret_cast<const short4*>(&vin[off]);
    float f0 = bf2f((unsigned short)raw.x), f1 = bf2f((unsigned short)raw.y);
    float f2 = bf2f((unsigned short)raw.z), f3 = bf2f((unsigned short)raw.w);
    float s  = f0 + f1 + f2 + f3;
    float s2 = f0 * f0 + f1 * f1 + f2 * f2 + f3 * f3;
    #pragma unroll
    for (int m = 32; m >= 1; m >>= 1) { s += __shfl_xor(s, m, 64); s2 += __shfl_xor(s2, m, 64); }
    float mu = s * 0.00390625f;
    float var = s2 * 0.00390625f - mu * mu;
    float inv = rsqrtf(var + 1e-5f);

    float b0, b1v, b2, b3;
    if (BASE_F32) {
        float4 braw = *reinterpret_cast<const float4*>(&((const float*)basev)[off]);
        b0 = braw.x; b1v = braw.y; b2 = braw.z; b3 = braw.w;
    } else {
        short4 braw = *reinterpret_cast<const short4*>(&((const unsigned short*)basev)[off]);
        b0 = bf2f((unsigned short)braw.x); b1v = bf2f((unsigned short)braw.y);
        b2 = bf2f((unsigned short)braw.z); b3 = bf2f((unsigned short)braw.w);
    }
    float4 graw = *reinterpret_cast<const float4*>(&gg[lane * 4]);
    float4 brw2 = *reinterpret_cast<const float4*>(&bb[lane * 4]);
    float o0 = b0 + (f0 - mu) * inv * graw.x + brw2.x;
    float o1 = b1v + (f1 - mu) * inv * graw.y + brw2.y;
    float o2 = b2 + (f2 - mu) * inv * graw.z + brw2.z;
    float o3 = b3 + (f3 - mu) * inv * graw.w + brw2.w;
    if (OUT_F32) {
        float4 o; o.x = o0; o.y = o1; o.z = o2; o.w = o3;
        *reinterpret_cast<float4*>(&((float*)outv)[off]) = o;
    } else {
        short4 o;
        o.x = (short)f2bf(o0); o.y = (short)f2bf(o1);
        o.z = (short)f2bf(o2); o.w = (short)f2bf(o3);
        *reinterpret_cast<short4*>(&((unsigned short*)outv)[off]) = o;
    }
}

extern "C" void kernel_launch(void* const* d_in, const int* in_sizes, int n_in,
                              void* d_out, int out_size, void* d_ws, size_t ws_size,
                              hipStream_t stream) {
    const float* x      = (const float*)d_in[0];
    const float* qkv_w  = (const float*)d_in[1];
    const float* q_bias = (const float*)d_in[2];
    const float* v_bias = (const float*)d_in[3];
    const float* lscale = (const float*)d_in[4];
    const float* cpb_w1 = (const float*)d_in[5];
    const float* cpb_b1 = (const float*)d_in[6];
    const float* cpb_w2 = (const float*)d_in[7];
    const float* proj_w = (const float*)d_in[8];
    const float* proj_b = (const float*)d_in[9];
    const float* n1g    = (const float*)d_in[10];
    const float* n1b    = (const float*)d_in[11];
    const float* fc1_w  = (const float*)d_in[12];
    const float* fc1_b  = (const float*)d_in[13];
    const float* fc2_w  = (const float*)d_in[14];
    const float* fc2_b  = (const float*)d_in[15];
    const float* n2g    = (const float*)d_in[16];
    const float* n2b    = (const float*)d_in[17];
    const float* rct    = (const float*)d_in[18];
    const int*   rpi    = (const int*)d_in[19];

    char* ws = (char*)d_ws;
    // [0, 154,140,672): qkv bf16 (qkv..attn); hbuf bf16 [0, 205,520,896) (fc1..fc2)
    unsigned short* qkv    = (unsigned short*)(ws);
    unsigned short* hbuf   = (unsigned short*)(ws);
    // [154,140,672, 205,520,896): attn_o (attn..proj)
    unsigned short* attn_o = (unsigned short*)(ws + 154140672);
    // [205,520,896, 256,901,120): xb bf16 (conv..ln1), then x1 in-place (ln1..ln2)
    unsigned short* xb     = (unsigned short*)(ws + 205520896);
    unsigned short* x1     = (unsigned short*)(ws + 205520896);
    // [256,901,120, 308,281,344): projy (proj..ln1), then y (fc2..ln2)
    unsigned short* projy  = (unsigned short*)(ws + 256901120);
    // bf16 weights + small buffers
    unsigned short* wqkv   = (unsigned short*)(ws + 308281344);
    unsigned short* wproj  = (unsigned short*)(ws + 308674560);
    unsigned short* wfc1   = (unsigned short*)(ws + 308805632);
    unsigned short* wfc2   = (unsigned short*)(ws + 309329920);
    float*          rpbn   = (float*)(ws + 309854208);
    float*          scales = (float*)(ws + 310378496);
    float*          qkvb   = (float*)(ws + 310378528);

    const int M = 100352;

    conv_kernel<<<2048, 256, 0, stream>>>(x, xb, 25690112 / 4);
    conv_kernel<<<192, 256, 0, stream>>>(qkv_w, wqkv, 196608 / 4);
    conv_kernel<<<64, 256, 0, stream>>>(proj_w, wproj, 65536 / 4);
    conv_kernel<<<256, 256, 0, stream>>>(fc1_w, wfc1, 262144 / 4);
    conv_kernel<<<256, 256, 0, stream>>>(fc2_w, wfc2, 262144 / 4);
    prep_kernel<<<1, 256, 0, stream>>>(lscale, cpb_w1, cpb_b1, cpb_w2, q_bias, v_bias,
                                       rct, rpi, scales, rpbn, qkvb);
    // qkv = xb @ wqkv^T + qkv_bias   (784 M-tiles x 6 N-tiles)
    gemm_kernel<0, 0><<<4704, 256, 0, stream>>>(xb, wqkv, qkvb, qkv, M, 768, 256, 6);
    // attention -> window-ordered (Bw*49, 256)
    attn_kernel<<<16384, 64, 0, stream>>>(qkv, scales, rpbn, attn_o);
    // proj with scatter to natural order (784 x 2)
    gemm_kernel<0, 1><<<1568, 256, 0, stream>>>(attn_o, wproj, proj_b, projy, M, 256, 256, 2);
    // x1 = xb + LN(projy)   (in-place over xb region)
    ln_add_kernel<0, 0><<<25088, 256, 0, stream>>>(xb, projy, n1g, n1b, x1);
    // h = gelu(x1 @ wfc1^T + fc1_b)   (784 x 8)
    gemm_kernel<1, 0><<<6272, 256, 0, stream>>>(x1, wfc1, fc1_b, hbuf, M, 1024, 256, 8);
    // y = h @ wfc2^T + fc2_b   (784 x 2)
    gemm_kernel<0, 0><<<1568, 256, 0, stream>>>(hbuf, wfc2, fc2_b, projy, M, 256, 1024, 2);
    // out = x1 + LN(y)
    ln_add_kernel<0, 1><<<25088, 256, 0, stream>>>(x1, projy, n2g, n2b, d_out);
}

// Round 7
// 644.709 us; speedup vs baseline: 2.0887x; 1.0810x over previous
//
#include <hip/hip_runtime.h>
#include <hip/hip_bf16.h>

typedef __attribute__((ext_vector_type(8))) short short8_t;
typedef __attribute__((ext_vector_type(4))) float f32x4;

__device__ __forceinline__ float bf2f(unsigned short u) {
    return __uint_as_float(((unsigned)u) << 16);
}
__device__ __forceinline__ unsigned short f2bf(float f) {
    __hip_bfloat16 h = __float2bfloat16(f);
    return *reinterpret_cast<unsigned short*>(&h);
}

// exact-GELU via Abramowitz-Stegun 7.1.26 erf (|err| <= 1.5e-7), branch-free.
__device__ __forceinline__ float fast_gelu(float v) {
    float ax = fabsf(v) * 0.70710678118f;
    float t  = __builtin_amdgcn_rcpf(1.f + 0.3275911f * ax);
    float poly = t * (0.254829592f + t * (-0.284496736f + t * (1.421413741f
               + t * (-1.453152027f + t * 1.061405429f))));
    float e  = __expf(-ax * ax);
    float er = 1.f - poly * e;                 // erf(ax), ax >= 0
    float s  = (v >= 0.f) ? er : -er;
    return 0.5f * v * (1.f + s);
}

// async global->LDS, 16B per lane; LDS dest = wave-uniform base + lane*16
__device__ __forceinline__ void async16(const unsigned short* g, unsigned short* l) {
    __builtin_amdgcn_global_load_lds(
        (const __attribute__((address_space(1))) unsigned int*)g,
        (__attribute__((address_space(3))) unsigned int*)l,
        16, 0, 0);
}

// window-order row r (r = wb*49 + n) -> natural token index
__device__ __forceinline__ int win_row_to_token(int r) {
    int wb = r / 49, n = r - wb * 49;
    int wq = wb & 7, hb = (wb >> 3) & 7, d = (wb >> 6) & 7, b = wb >> 9;
    int hh = n / 7, ww2 = n - hh * 7;
    return ((b * 8 + d) * 56 + hb * 7 + hh) * 56 + wq * 7 + ww2;
}

// ---------------- f32 -> bf16 bulk convert ----------------
__global__ __launch_bounds__(256) void conv_kernel(
    const float* __restrict__ src, unsigned short* __restrict__ dst, int n4)
{
    int stride = gridDim.x * 256;
    for (int i = blockIdx.x * 256 + threadIdx.x; i < n4; i += stride) {
        float4 v = *reinterpret_cast<const float4*>(&src[(size_t)i * 4]);
        short4 o;
        o.x = (short)f2bf(v.x); o.y = (short)f2bf(v.y);
        o.z = (short)f2bf(v.z); o.w = (short)f2bf(v.w);
        *reinterpret_cast<short4*>(&dst[(size_t)i * 4]) = o;
    }
}

// ---------------- prep: scales, qkv bias, CPB-MLP -> rpbn [8][64][64] ----------------
__global__ __launch_bounds__(256) void prep_kernel(
    const float* __restrict__ logit_scale,
    const float* __restrict__ w1, const float* __restrict__ b1,
    const float* __restrict__ w2,
    const float* __restrict__ qb, const float* __restrict__ vb,
    const float* __restrict__ tabin, const int* __restrict__ rpi,
    float* __restrict__ scales, float* __restrict__ rpbn,
    float* __restrict__ qkvb)
{
    int t = threadIdx.x;
    if (t < 8) {
        float v = logit_scale[t];
        scales[t] = expf(fminf(v, 4.6051702f)); // ln(100)
    }
    for (int i = t; i < 768; i += 256) {
        float o;
        if (i < 256) o = qb[i];
        else if (i < 512) o = 0.f;
        else o = vb[i - 512];
        qkvb[i] = o;
    }
    for (int i = t; i < 8 * 4096; i += 256) rpbn[i] = 0.f;
    __shared__ float table[169][8];
    for (int i = t; i < 169; i += 256) {
        float c0 = tabin[i * 3], c1 = tabin[i * 3 + 1], c2 = tabin[i * 3 + 2];
        float acc[8] = {0.f, 0.f, 0.f, 0.f, 0.f, 0.f, 0.f, 0.f};
        for (int j = 0; j < 512; ++j) {
            float hv = c0 * w1[j * 3] + c1 * w1[j * 3 + 1] + c2 * w1[j * 3 + 2] + b1[j];
            hv = fmaxf(hv, 0.f);
            #pragma unroll
            for (int h = 0; h < 8; ++h) acc[h] += hv * w2[h * 512 + j];
        }
        #pragma unroll
        for (int h = 0; h < 8; ++h) table[i][h] = acc[h];
    }
    __syncthreads();
    for (int e = t; e < 2401; e += 256) {
        int i = e / 49, j = e - i * 49;
        int idx = rpi[e];
        #pragma unroll
        for (int h = 0; h < 8; ++h) {
            float xv = table[idx][h];
            rpbn[h * 4096 + i * 64 + j] = 16.f / (1.f + expf(-xv));
        }
    }
}

// ---------------- GEMM: C[M,N] = A[M,K] * W[N,K]^T + bias (bf16 in/out) ----------------
// 128x128 tile, BK=64, 4 waves. Double-buffered global_load_lds staging (2-phase
// pipeline), XCD-aware block swizzle, LDS-transpose epilogue for coalesced stores.
template<int ACT, int SCATTER>
__global__ __launch_bounds__(256) void gemm_kernel(
    const unsigned short* __restrict__ A, const unsigned short* __restrict__ W,
    const float* __restrict__ bias, unsigned short* __restrict__ C,
    int M, int N, int K, int ntn)
{
    __shared__ unsigned short smem[32768]; // As(buf)=buf*8192, Bs(buf)=16384+buf*8192
    const int tid = threadIdx.x;
    const int lane = tid & 63, wv = tid >> 6;
    const int wr = wv >> 1, wc = wv & 1;
    const int nwg = gridDim.x;
    const int virt = (blockIdx.x & 7) * (nwg >> 3) + (blockIdx.x >> 3);
    const int bn = virt % ntn, bm = virt / ntn;
    const size_t arow0 = (size_t)bm * 128;
    const size_t brow0 = (size_t)bn * 128;
    const int r16 = lane & 15, g4 = lane >> 4;
    const int lrow = lane >> 3;
    const int lgran = (lane & 7) ^ lrow;
    f32x4 acc[4][4] = {};

    auto STAGE = [&](int buf, int kt) {
        unsigned short* As = smem + buf * 8192;
        unsigned short* Bs = smem + 16384 + buf * 8192;
        #pragma unroll
        for (int i = 0; i < 4; ++i) {
            int row = wv * 32 + i * 8;
            async16(&A[(arow0 + row + lrow) * (size_t)K + kt + lgran * 8], &As[row * 64]);
            async16(&W[(brow0 + row + lrow) * (size_t)K + kt + lgran * 8], &Bs[row * 64]);
        }
    };
    auto COMPUTE = [&](int buf) {
        unsigned short* As = smem + buf * 8192;
        unsigned short* Bs = smem + 16384 + buf * 8192;
        #pragma unroll
        for (int kk = 0; kk < 2; ++kk) {
            short8_t af[4], bfr[4];
            #pragma unroll
            for (int m = 0; m < 4; ++m) {
                int row = wr * 64 + m * 16 + r16;
                int g = (kk * 4 + g4) ^ (row & 7);
                af[m] = *reinterpret_cast<const short8_t*>(&As[row * 64 + g * 8]);
            }
            #pragma unroll
            for (int n = 0; n < 4; ++n) {
                int row = wc * 64 + n * 16 + r16;
                int g = (kk * 4 + g4) ^ (row & 7);
                bfr[n] = *reinterpret_cast<const short8_t*>(&Bs[row * 64 + g * 8]);
            }
            #pragma unroll
            for (int m = 0; m < 4; ++m)
                #pragma unroll
                for (int n = 0; n < 4; ++n)
                    acc[m][n] = __builtin_amdgcn_mfma_f32_16x16x32_bf16(af[m], bfr[n], acc[m][n], 0, 0, 0);
        }
    };

    STAGE(0, 0);
    __syncthreads();
    int cur = 0;
    for (int kt = 64; kt < K; kt += 64) {
        STAGE(cur ^ 1, kt);
        COMPUTE(cur);
        __syncthreads();
        cur ^= 1;
    }
    COMPUTE(cur);
    __syncthreads();

    // ---- epilogue: acc -> per-wave LDS tile (stride 76) -> coalesced stores ----
    unsigned short* Cs = smem + wv * 4864;   // 64 x 76 ushorts
    const int rbase = g4 * 4;
    #pragma unroll
    for (int n = 0; n < 4; ++n) {
        float bv = bias[bn * 128 + wc * 64 + n * 16 + r16];
        #pragma unroll
        for (int m = 0; m < 4; ++m)
            #pragma unroll
            for (int r = 0; r < 4; ++r) {
                float v = acc[m][n][r] + bv;
                if (ACT == 1) v = fast_gelu(v);
                Cs[(m * 16 + rbase + r) * 76 + n * 16 + r16] = f2bf(v);
            }
    }
    __syncthreads();
    const int srow = lane >> 3, scol = (lane & 7) * 8;
    const int gcol0 = bn * 128 + wc * 64;
    #pragma unroll
    for (int rr = 0; rr < 8; ++rr) {
        int lr = rr * 8 + srow;
        int grow = bm * 128 + wr * 64 + lr;
        size_t orow = SCATTER ? (size_t)win_row_to_token(grow) : (size_t)grow;
        short8_t vv = *reinterpret_cast<const short8_t*>(&Cs[lr * 76 + scol]);
        *reinterpret_cast<short8_t*>(&C[orow * (size_t)N + gcol0 + scol]) = vv;
    }
}

// ---------------- attention: one WAVE per (window, head), MFMA ----------------
__global__ __launch_bounds__(64) void attn_kernel(
    const unsigned short* __restrict__ qkv, const float* __restrict__ scales,
    const float* __restrict__ rpbn, unsigned short* __restrict__ out)
{
    constexpr int QO = 0;
    constexpr int KO = 49 * 72;
    constexpr int VO = 98 * 72;
    constexpr int PO = 0;
    __shared__ unsigned short lds[98 * 72 + 32 * 72];

    const int blk = blockIdx.x;
    const int h = blk & 7, wb = blk >> 3;
    const int lane = threadIdx.x;
    const int r16 = lane & 15, g4 = lane >> 4;

    const int wq = wb & 7, hb = (wb >> 3) & 7, dd = (wb >> 6) & 7, bb2 = wb >> 9;
    const int tok_base = ((bb2 * 8 + dd) * 56 + hb * 7) * 56 + wq * 7;
    const float sc = scales[h];

    {
        short8_t z = {};
        int d = lane >> 1, gi = 6 + (lane & 1);
        *reinterpret_cast<short8_t*>(&lds[VO + d * 72 + gi * 8]) = z;
    }
    #pragma unroll
    for (int sel = 0; sel < 2; ++sel) {
        for (int c = lane; c < 196; c += 64) {
            int row = c >> 2, gi = c & 3;
            int tok = tok_base + (row / 7) * 56 + (row % 7);
            const unsigned short* gp = qkv + (size_t)tok * 768 + sel * 256 + h * 32 + gi * 8;
            short8_t raw = *reinterpret_cast<const short8_t*>(gp);
            float f[8]; float ss = 0.f;
            #pragma unroll
            for (int e = 0; e < 8; ++e) { f[e] = bf2f((unsigned short)raw[e]); ss += f[e] * f[e]; }
            ss += __shfl_xor(ss, 1); ss += __shfl_xor(ss, 2);
            float inv = 1.f / fmaxf(sqrtf(ss), 1e-12f);
            if (sel == 0) inv *= sc;
            short8_t o;
            #pragma unroll
            for (int e = 0; e < 8; ++e) o[e] = (short)f2bf(f[e] * inv);
            *reinterpret_cast<short8_t*>(&lds[(sel ? KO : QO) + row * 72 + gi * 8]) = o;
        }
    }
    for (int c = lane; c < 1568; c += 64) {
        int j = c >> 5, d = c & 31;
        int tok = tok_base + (j / 7) * 56 + (j % 7);
        lds[VO + d * 72 + j] = qkv[(size_t)tok * 768 + 512 + h * 32 + d];
    }
    __syncthreads();

    short8_t qf[4], kf[4];
    #pragma unroll
    for (int mi = 0; mi < 4; ++mi)
        qf[mi] = *reinterpret_cast<const short8_t*>(&lds[QO + (mi * 16 + r16) * 72 + g4 * 8]);
    #pragma unroll
    for (int ji = 0; ji < 4; ++ji)
        kf[ji] = *reinterpret_cast<const short8_t*>(&lds[KO + (ji * 16 + r16) * 72 + g4 * 8]);
    f32x4 acc[4][4] = {};
    #pragma unroll
    for (int mi = 0; mi < 4; ++mi)
        #pragma unroll
        for (int ji = 0; ji < 4; ++ji)
            acc[mi][ji] = __builtin_amdgcn_mfma_f32_16x16x32_bf16(qf[mi], kf[ji], acc[mi][ji], 0, 0, 0);
    __syncthreads();

    const float* rb = rpbn + h * 4096;
    #pragma unroll
    for (int mi = 0; mi < 4; ++mi) {
        #pragma unroll
        for (int r = 0; r < 4; ++r) {
            int i = mi * 16 + g4 * 4 + r;
            float s[4]; float m = -1e30f;
            #pragma unroll
            for (int ji = 0; ji < 4; ++ji) {
                int j = ji * 16 + r16;
                float v = acc[mi][ji][r] + rb[i * 64 + j];
                s[ji] = (j < 49) ? v : -1e30f;
                m = fmaxf(m, s[ji]);
            }
            m = fmaxf(m, __shfl_xor(m, 1)); m = fmaxf(m, __shfl_xor(m, 2));
            m = fmaxf(m, __shfl_xor(m, 4)); m = fmaxf(m, __shfl_xor(m, 8));
            float p[4]; float sum = 0.f;
            #pragma unroll
            for (int ji = 0; ji < 4; ++ji) {
                p[ji] = (s[ji] > -1e29f) ? __expf(s[ji] - m) : 0.f;
                sum += p[ji];
            }
            sum += __shfl_xor(sum, 1); sum += __shfl_xor(sum, 2);
            sum += __shfl_xor(sum, 4); sum += __shfl_xor(sum, 8);
            float rinv = 1.f / sum;
            #pragma unroll
            for (int ji = 0; ji < 4; ++ji) {
                int j = ji * 16 + r16;
                lds[PO + i * 72 + j] = f2bf(p[ji] * rinv);
            }
        }
    }
    __syncthreads();

    f32x4 acc2[4][2] = {};
    #pragma unroll
    for (int ks = 0; ks < 2; ++ks) {
        short8_t pf[4], vf[2];
        int ko = ks * 32 + g4 * 8;
        #pragma unroll
        for (int mi = 0; mi < 4; ++mi)
            pf[mi] = *reinterpret_cast<const short8_t*>(&lds[PO + (mi * 16 + r16) * 72 + ko]);
        #pragma unroll
        for (int ni = 0; ni < 2; ++ni)
            vf[ni] = *reinterpret_cast<const short8_t*>(&lds[VO + (ni * 16 + r16) * 72 + ko]);
        #pragma unroll
        for (int mi = 0; mi < 4; ++mi)
            #pragma unroll
            for (int ni = 0; ni < 2; ++ni)
                acc2[mi][ni] = __builtin_amdgcn_mfma_f32_16x16x32_bf16(pf[mi], vf[ni], acc2[mi][ni], 0, 0, 0);
    }

    #pragma unroll
    for (int mi = 0; mi < 4; ++mi)
        #pragma unroll
        for (int r = 0; r < 4; ++r) {
            int i = mi * 16 + g4 * 4 + r;
            if (i < 49) {
                size_t ob = (size_t)(wb * 49 + i) * 256 + h * 32;
                out[ob + r16]      = f2bf(acc2[mi][0][r]);
                out[ob + 16 + r16] = f2bf(acc2[mi][1][r]);
            }
        }
}

// ---------------- fused residual + LayerNorm (one wave per token) ----------------
template<int BASE_F32, int OUT_F32>
__global__ __launch_bounds__(256) void ln_add_kernel(
    const void* __restrict__ basev, const unsigned short* __restrict__ vin,
    const float* __restrict__ gg, const float* __restrict__ bb,
    void* __restrict__ outv)
{
    int token = blockIdx.x * 4 + (threadIdx.x >> 6);
    int lane = threadIdx.x & 63;
    size_t off = (size_t)token * 256 + lane * 4;
    short4 raw = *reinterpret_cast<const short4*>(&vin[off]);
    float f0 = bf2f((unsigned short)raw.x), f1 = bf2f((unsigned short)raw.y);
    float f2 = bf2f((unsigned short)raw.z), f3 = bf2f((unsigned short)raw.w);
    float s  = f0 + f1 + f2 + f3;
    float s2 = f0 * f0 + f1 * f1 + f2 * f2 + f3 * f3;
    #pragma unroll
    for (int m = 32; m >= 1; m >>= 1) { s += __shfl_xor(s, m, 64); s2 += __shfl_xor(s2, m, 64); }
    float mu = s * 0.00390625f;
    float var = s2 * 0.00390625f - mu * mu;
    float inv = rsqrtf(var + 1e-5f);

    float b0, b1v, b2, b3;
    if (BASE_F32) {
        float4 braw = *reinterpret_cast<const float4*>(&((const float*)basev)[off]);
        b0 = braw.x; b1v = braw.y; b2 = braw.z; b3 = braw.w;
    } else {
        short4 braw = *reinterpret_cast<const short4*>(&((const unsigned short*)basev)[off]);
        b0 = bf2f((unsigned short)braw.x); b1v = bf2f((unsigned short)braw.y);
        b2 = bf2f((unsigned short)braw.z); b3 = bf2f((unsigned short)braw.w);
    }
    float4 graw = *reinterpret_cast<const float4*>(&gg[lane * 4]);
    float4 brw2 = *reinterpret_cast<const float4*>(&bb[lane * 4]);
    float o0 = b0 + (f0 - mu) * inv * graw.x + brw2.x;
    float o1 = b1v + (f1 - mu) * inv * graw.y + brw2.y;
    float o2 = b2 + (f2 - mu) * inv * graw.z + brw2.z;
    float o3 = b3 + (f3 - mu) * inv * graw.w + brw2.w;
    if (OUT_F32) {
        float4 o; o.x = o0; o.y = o1; o.z = o2; o.w = o3;
        *reinterpret_cast<float4*>(&((float*)outv)[off]) = o;
    } else {
        short4 o;
        o.x = (short)f2bf(o0); o.y = (short)f2bf(o1);
        o.z = (short)f2bf(o2); o.w = (short)f2bf(o3);
        *reinterpret_cast<short4*>(&((unsigned short*)outv)[off]) = o;
    }
}

extern "C" void kernel_launch(void* const* d_in, const int* in_sizes, int n_in,
                              void* d_out, int out_size, void* d_ws, size_t ws_size,
                              hipStream_t stream) {
    const float* x      = (const float*)d_in[0];
    const float* qkv_w  = (const float*)d_in[1];
    const float* q_bias = (const float*)d_in[2];
    const float* v_bias = (const float*)d_in[3];
    const float* lscale = (const float*)d_in[4];
    const float* cpb_w1 = (const float*)d_in[5];
    const float* cpb_b1 = (const float*)d_in[6];
    const float* cpb_w2 = (const float*)d_in[7];
    const float* proj_w = (const float*)d_in[8];
    const float* proj_b = (const float*)d_in[9];
    const float* n1g    = (const float*)d_in[10];
    const float* n1b    = (const float*)d_in[11];
    const float* fc1_w  = (const float*)d_in[12];
    const float* fc1_b  = (const float*)d_in[13];
    const float* fc2_w  = (const float*)d_in[14];
    const float* fc2_b  = (const float*)d_in[15];
    const float* n2g    = (const float*)d_in[16];
    const float* n2b    = (const float*)d_in[17];
    const float* rct    = (const float*)d_in[18];
    const int*   rpi    = (const int*)d_in[19];

    char* ws = (char*)d_ws;
    unsigned short* qkv    = (unsigned short*)(ws);
    unsigned short* hbuf   = (unsigned short*)(ws);
    unsigned short* attn_o = (unsigned short*)(ws + 154140672);
    unsigned short* xb     = (unsigned short*)(ws + 205520896);
    unsigned short* x1     = (unsigned short*)(ws + 205520896);
    unsigned short* projy  = (unsigned short*)(ws + 256901120);
    unsigned short* wqkv   = (unsigned short*)(ws + 308281344);
    unsigned short* wproj  = (unsigned short*)(ws + 308674560);
    unsigned short* wfc1   = (unsigned short*)(ws + 308805632);
    unsigned short* wfc2   = (unsigned short*)(ws + 309329920);
    float*          rpbn   = (float*)(ws + 309854208);
    float*          scales = (float*)(ws + 310378496);
    float*          qkvb   = (float*)(ws + 310378528);

    const int M = 100352;

    conv_kernel<<<2048, 256, 0, stream>>>(x, xb, 25690112 / 4);
    conv_kernel<<<192, 256, 0, stream>>>(qkv_w, wqkv, 196608 / 4);
    conv_kernel<<<64, 256, 0, stream>>>(proj_w, wproj, 65536 / 4);
    conv_kernel<<<256, 256, 0, stream>>>(fc1_w, wfc1, 262144 / 4);
    conv_kernel<<<256, 256, 0, stream>>>(fc2_w, wfc2, 262144 / 4);
    prep_kernel<<<1, 256, 0, stream>>>(lscale, cpb_w1, cpb_b1, cpb_w2, q_bias, v_bias,
                                       rct, rpi, scales, rpbn, qkvb);
    gemm_kernel<0, 0><<<4704, 256, 0, stream>>>(xb, wqkv, qkvb, qkv, M, 768, 256, 6);
    attn_kernel<<<16384, 64, 0, stream>>>(qkv, scales, rpbn, attn_o);
    gemm_kernel<0, 1><<<1568, 256, 0, stream>>>(attn_o, wproj, proj_b, projy, M, 256, 256, 2);
    ln_add_kernel<0, 0><<<25088, 256, 0, stream>>>(xb, projy, n1g, n1b, x1);
    gemm_kernel<1, 0><<<6272, 256, 0, stream>>>(x1, wfc1, fc1_b, hbuf, M, 1024, 256, 8);
    gemm_kernel<0, 0><<<1568, 256, 0, stream>>>(hbuf, wfc2, fc2_b, projy, M, 256, 1024, 2);
    ln_add_kernel<0, 1><<<25088, 256, 0, stream>>>(x1, projy, n2g, n2b, d_out);
}

// Round 8
// 635.767 us; speedup vs baseline: 2.1181x; 1.0141x over previous
//
#include <hip/hip_runtime.h>
#include <hip/hip_bf16.h>

typedef __attribute__((ext_vector_type(8))) short short8_t;
typedef __attribute__((ext_vector_type(4))) float f32x4;

__device__ __forceinline__ float bf2f(unsigned short u) {
    return __uint_as_float(((unsigned)u) << 16);
}
__device__ __forceinline__ unsigned short f2bf(float f) {
    __hip_bfloat16 h = __float2bfloat16(f);
    return *reinterpret_cast<unsigned short*>(&h);
}

// exact-GELU via Abramowitz-Stegun 7.1.26 erf (|err| <= 1.5e-7), branch-free.
__device__ __forceinline__ float fast_gelu(float v) {
    float ax = fabsf(v) * 0.70710678118f;
    float t  = __builtin_amdgcn_rcpf(1.f + 0.3275911f * ax);
    float poly = t * (0.254829592f + t * (-0.284496736f + t * (1.421413741f
               + t * (-1.453152027f + t * 1.061405429f))));
    float e  = __expf(-ax * ax);
    float er = 1.f - poly * e;                 // erf(ax), ax >= 0
    float s  = (v >= 0.f) ? er : -er;
    return 0.5f * v * (1.f + s);
}

// async global->LDS, 16B per lane; LDS dest = wave-uniform base + lane*16
__device__ __forceinline__ void async16(const unsigned short* g, unsigned short* l) {
    __builtin_amdgcn_global_load_lds(
        (const __attribute__((address_space(1))) unsigned int*)g,
        (__attribute__((address_space(3))) unsigned int*)l,
        16, 0, 0);
}

// window-order row r (r = wb*49 + n) -> natural token index
__device__ __forceinline__ int win_row_to_token(int r) {
    int wb = r / 49, n = r - wb * 49;
    int wq = wb & 7, hb = (wb >> 3) & 7, d = (wb >> 6) & 7, b = wb >> 9;
    int hh = n / 7, ww2 = n - hh * 7;
    return ((b * 8 + d) * 56 + hb * 7 + hh) * 56 + wq * 7 + ww2;
}

// ---------------- f32 -> bf16 bulk convert ----------------
__global__ __launch_bounds__(256) void conv_kernel(
    const float* __restrict__ src, unsigned short* __restrict__ dst, int n4)
{
    int stride = gridDim.x * 256;
    for (int i = blockIdx.x * 256 + threadIdx.x; i < n4; i += stride) {
        float4 v = *reinterpret_cast<const float4*>(&src[(size_t)i * 4]);
        short4 o;
        o.x = (short)f2bf(v.x); o.y = (short)f2bf(v.y);
        o.z = (short)f2bf(v.z); o.w = (short)f2bf(v.w);
        *reinterpret_cast<short4*>(&dst[(size_t)i * 4]) = o;
    }
}

// ---------------- prep: scales, qkv bias, CPB-MLP -> rpbn [8][64][64] ----------------
__global__ __launch_bounds__(256) void prep_kernel(
    const float* __restrict__ logit_scale,
    const float* __restrict__ w1, const float* __restrict__ b1,
    const float* __restrict__ w2,
    const float* __restrict__ qb, const float* __restrict__ vb,
    const float* __restrict__ tabin, const int* __restrict__ rpi,
    float* __restrict__ scales, float* __restrict__ rpbn,
    float* __restrict__ qkvb)
{
    int t = threadIdx.x;
    if (t < 8) {
        float v = logit_scale[t];
        scales[t] = expf(fminf(v, 4.6051702f)); // ln(100)
    }
    for (int i = t; i < 768; i += 256) {
        float o;
        if (i < 256) o = qb[i];
        else if (i < 512) o = 0.f;
        else o = vb[i - 512];
        qkvb[i] = o;
    }
    for (int i = t; i < 8 * 4096; i += 256) rpbn[i] = 0.f;
    __shared__ float table[169][8];
    for (int i = t; i < 169; i += 256) {
        float c0 = tabin[i * 3], c1 = tabin[i * 3 + 1], c2 = tabin[i * 3 + 2];
        float acc[8] = {0.f, 0.f, 0.f, 0.f, 0.f, 0.f, 0.f, 0.f};
        for (int j = 0; j < 512; ++j) {
            float hv = c0 * w1[j * 3] + c1 * w1[j * 3 + 1] + c2 * w1[j * 3 + 2] + b1[j];
            hv = fmaxf(hv, 0.f);
            #pragma unroll
            for (int h = 0; h < 8; ++h) acc[h] += hv * w2[h * 512 + j];
        }
        #pragma unroll
        for (int h = 0; h < 8; ++h) table[i][h] = acc[h];
    }
    __syncthreads();
    for (int e = t; e < 2401; e += 256) {
        int i = e / 49, j = e - i * 49;
        int idx = rpi[e];
        #pragma unroll
        for (int h = 0; h < 8; ++h) {
            float xv = table[idx][h];
            rpbn[h * 4096 + i * 64 + j] = 16.f / (1.f + expf(-xv));
        }
    }
}

// ---------------- GEMM: C[M,N] = A[M,K] * W[N,K]^T + bias (bf16 in/out) ----------------
// 128x128 tile, BK=32, 4 waves, double-buffered global_load_lds (2-phase).
// LDS 38.9KB -> 4 blocks/CU. Source-granule swizzle (lane&3)^((row>>1)&3);
// fragment reads use granule g4^((row>>1)&3). LDS-transpose epilogue.
template<int ACT, int SCATTER>
__global__ __launch_bounds__(256) void gemm_kernel(
    const unsigned short* __restrict__ A, const unsigned short* __restrict__ W,
    const float* __restrict__ bias, unsigned short* __restrict__ C,
    int M, int N, int K, int ntn)
{
    // pipeline: As(buf)=buf*4096, Bs(buf)=8192+buf*4096 (ushort idx); 32KB
    // epilogue: per-wave 64x76 tiles at wv*4864; 38,912B total
    __shared__ unsigned short smem[19456];
    const int tid = threadIdx.x;
    const int lane = tid & 63, wv = tid >> 6;
    const int wr = wv >> 1, wc = wv & 1;
    const int nwg = gridDim.x;
    const int virt = (blockIdx.x & 7) * (nwg >> 3) + (blockIdx.x >> 3);
    const int bn = virt % ntn, bm = virt / ntn;
    const size_t arow0 = (size_t)bm * 128;
    const size_t brow0 = (size_t)bn * 128;
    const int r16 = lane & 15, g4 = lane >> 4;
    // staging: per wave-issue 16 rows x 32 cols (1KB); lane covers row lane>>2,
    // granule lane&3; source granule XOR'd so LDS[row][p] = G[row][p ^ ((row>>1)&3)]
    const int srow_l = lane >> 2;                    // 0..15 row within issue
    const int sgran  = (lane & 3) ^ ((srow_l >> 1) & 3);
    f32x4 acc[4][4] = {};

    auto STAGE = [&](int buf, int kt) {
        unsigned short* As = smem + buf * 4096;
        unsigned short* Bs = smem + 8192 + buf * 4096;
        #pragma unroll
        for (int i = 0; i < 2; ++i) {
            int row0 = wv * 32 + i * 16;             // 16-row issue base
            async16(&A[(arow0 + row0 + srow_l) * (size_t)K + kt + sgran * 8], &As[row0 * 32]);
            async16(&W[(brow0 + row0 + srow_l) * (size_t)K + kt + sgran * 8], &Bs[row0 * 32]);
        }
    };
    auto COMPUTE = [&](int buf) {
        unsigned short* As = smem + buf * 4096;
        unsigned short* Bs = smem + 8192 + buf * 4096;
        short8_t af[4], bfr[4];
        const int gsw = g4 ^ ((r16 >> 1) & 3);       // row>>1&3 == r16>>1&3
        #pragma unroll
        for (int m = 0; m < 4; ++m) {
            int row = wr * 64 + m * 16 + r16;
            af[m] = *reinterpret_cast<const short8_t*>(&As[row * 32 + gsw * 8]);
        }
        #pragma unroll
        for (int n = 0; n < 4; ++n) {
            int row = wc * 64 + n * 16 + r16;
            bfr[n] = *reinterpret_cast<const short8_t*>(&Bs[row * 32 + gsw * 8]);
        }
        #pragma unroll
        for (int m = 0; m < 4; ++m)
            #pragma unroll
            for (int n = 0; n < 4; ++n)
                acc[m][n] = __builtin_amdgcn_mfma_f32_16x16x32_bf16(af[m], bfr[n], acc[m][n], 0, 0, 0);
    };

    STAGE(0, 0);
    __syncthreads();
    int cur = 0;
    for (int kt = 32; kt < K; kt += 32) {
        STAGE(cur ^ 1, kt);
        COMPUTE(cur);
        __syncthreads();
        cur ^= 1;
    }
    COMPUTE(cur);
    __syncthreads();

    // ---- epilogue: acc -> per-wave LDS tile (stride 76) -> coalesced stores ----
    unsigned short* Cs = smem + wv * 4864;   // 64 x 76 ushorts
    const int rbase = g4 * 4;
    #pragma unroll
    for (int n = 0; n < 4; ++n) {
        float bv = bias[bn * 128 + wc * 64 + n * 16 + r16];
        #pragma unroll
        for (int m = 0; m < 4; ++m)
            #pragma unroll
            for (int r = 0; r < 4; ++r) {
                float v = acc[m][n][r] + bv;
                if (ACT == 1) v = fast_gelu(v);
                Cs[(m * 16 + rbase + r) * 76 + n * 16 + r16] = f2bf(v);
            }
    }
    __syncthreads();
    const int srow = lane >> 3, scol = (lane & 7) * 8;
    const int gcol0 = bn * 128 + wc * 64;
    #pragma unroll
    for (int rr = 0; rr < 8; ++rr) {
        int lr = rr * 8 + srow;
        int grow = bm * 128 + wr * 64 + lr;
        size_t orow = SCATTER ? (size_t)win_row_to_token(grow) : (size_t)grow;
        short8_t vv = *reinterpret_cast<const short8_t*>(&Cs[lr * 76 + scol]);
        *reinterpret_cast<short8_t*>(&C[orow * (size_t)N + gcol0 + scol]) = vv;
    }
}

// ---------------- attention: one WAVE per (window, head), MFMA ----------------
__global__ __launch_bounds__(64) void attn_kernel(
    const unsigned short* __restrict__ qkv, const float* __restrict__ scales,
    const float* __restrict__ rpbn, unsigned short* __restrict__ out)
{
    constexpr int QO = 0;
    constexpr int KO = 49 * 72;
    constexpr int VO = 98 * 72;
    constexpr int PO = 0;
    __shared__ unsigned short lds[98 * 72 + 32 * 72];

    const int blk = blockIdx.x;
    const int h = blk & 7, wb = blk >> 3;
    const int lane = threadIdx.x;
    const int r16 = lane & 15, g4 = lane >> 4;

    const int wq = wb & 7, hb = (wb >> 3) & 7, dd = (wb >> 6) & 7, bb2 = wb >> 9;
    const int tok_base = ((bb2 * 8 + dd) * 56 + hb * 7) * 56 + wq * 7;
    const float sc = scales[h];

    {
        short8_t z = {};
        int d = lane >> 1, gi = 6 + (lane & 1);
        *reinterpret_cast<short8_t*>(&lds[VO + d * 72 + gi * 8]) = z;
    }
    #pragma unroll
    for (int sel = 0; sel < 2; ++sel) {
        for (int c = lane; c < 196; c += 64) {
            int row = c >> 2, gi = c & 3;
            int tok = tok_base + (row / 7) * 56 + (row % 7);
            const unsigned short* gp = qkv + (size_t)tok * 768 + sel * 256 + h * 32 + gi * 8;
            short8_t raw = *reinterpret_cast<const short8_t*>(gp);
            float f[8]; float ss = 0.f;
            #pragma unroll
            for (int e = 0; e < 8; ++e) { f[e] = bf2f((unsigned short)raw[e]); ss += f[e] * f[e]; }
            ss += __shfl_xor(ss, 1); ss += __shfl_xor(ss, 2);
            float inv = 1.f / fmaxf(sqrtf(ss), 1e-12f);
            if (sel == 0) inv *= sc;
            short8_t o;
            #pragma unroll
            for (int e = 0; e < 8; ++e) o[e] = (short)f2bf(f[e] * inv);
            *reinterpret_cast<short8_t*>(&lds[(sel ? KO : QO) + row * 72 + gi * 8]) = o;
        }
    }
    for (int c = lane; c < 1568; c += 64) {
        int j = c >> 5, d = c & 31;
        int tok = tok_base + (j / 7) * 56 + (j % 7);
        lds[VO + d * 72 + j] = qkv[(size_t)tok * 768 + 512 + h * 32 + d];
    }
    __syncthreads();

    short8_t qf[4], kf[4];
    #pragma unroll
    for (int mi = 0; mi < 4; ++mi)
        qf[mi] = *reinterpret_cast<const short8_t*>(&lds[QO + (mi * 16 + r16) * 72 + g4 * 8]);
    #pragma unroll
    for (int ji = 0; ji < 4; ++ji)
        kf[ji] = *reinterpret_cast<const short8_t*>(&lds[KO + (ji * 16 + r16) * 72 + g4 * 8]);
    f32x4 acc[4][4] = {};
    #pragma unroll
    for (int mi = 0; mi < 4; ++mi)
        #pragma unroll
        for (int ji = 0; ji < 4; ++ji)
            acc[mi][ji] = __builtin_amdgcn_mfma_f32_16x16x32_bf16(qf[mi], kf[ji], acc[mi][ji], 0, 0, 0);
    __syncthreads();

    const float* rb = rpbn + h * 4096;
    #pragma unroll
    for (int mi = 0; mi < 4; ++mi) {
        #pragma unroll
        for (int r = 0; r < 4; ++r) {
            int i = mi * 16 + g4 * 4 + r;
            float s[4]; float m = -1e30f;
            #pragma unroll
            for (int ji = 0; ji < 4; ++ji) {
                int j = ji * 16 + r16;
                float v = acc[mi][ji][r] + rb[i * 64 + j];
                s[ji] = (j < 49) ? v : -1e30f;
                m = fmaxf(m, s[ji]);
            }
            m = fmaxf(m, __shfl_xor(m, 1)); m = fmaxf(m, __shfl_xor(m, 2));
            m = fmaxf(m, __shfl_xor(m, 4)); m = fmaxf(m, __shfl_xor(m, 8));
            float p[4]; float sum = 0.f;
            #pragma unroll
            for (int ji = 0; ji < 4; ++ji) {
                p[ji] = (s[ji] > -1e29f) ? __expf(s[ji] - m) : 0.f;
                sum += p[ji];
            }
            sum += __shfl_xor(sum, 1); sum += __shfl_xor(sum, 2);
            sum += __shfl_xor(sum, 4); sum += __shfl_xor(sum, 8);
            float rinv = 1.f / sum;
            #pragma unroll
            for (int ji = 0; ji < 4; ++ji) {
                int j = ji * 16 + r16;
                lds[PO + i * 72 + j] = f2bf(p[ji] * rinv);
            }
        }
    }
    __syncthreads();

    f32x4 acc2[4][2] = {};
    #pragma unroll
    for (int ks = 0; ks < 2; ++ks) {
        short8_t pf[4], vf[2];
        int ko = ks * 32 + g4 * 8;
        #pragma unroll
        for (int mi = 0; mi < 4; ++mi)
            pf[mi] = *reinterpret_cast<const short8_t*>(&lds[PO + (mi * 16 + r16) * 72 + ko]);
        #pragma unroll
        for (int ni = 0; ni < 2; ++ni)
            vf[ni] = *reinterpret_cast<const short8_t*>(&lds[VO + (ni * 16 + r16) * 72 + ko]);
        #pragma unroll
        for (int mi = 0; mi < 4; ++mi)
            #pragma unroll
            for (int ni = 0; ni < 2; ++ni)
                acc2[mi][ni] = __builtin_amdgcn_mfma_f32_16x16x32_bf16(pf[mi], vf[ni], acc2[mi][ni], 0, 0, 0);
    }

    #pragma unroll
    for (int mi = 0; mi < 4; ++mi)
        #pragma unroll
        for (int r = 0; r < 4; ++r) {
            int i = mi * 16 + g4 * 4 + r;
            if (i < 49) {
                size_t ob = (size_t)(wb * 49 + i) * 256 + h * 32;
                out[ob + r16]      = f2bf(acc2[mi][0][r]);
                out[ob + 16 + r16] = f2bf(acc2[mi][1][r]);
            }
        }
}

// ---------------- fused residual + LayerNorm (one wave per token) ----------------
template<int BASE_F32, int OUT_F32>
__global__ __launch_bounds__(256) void ln_add_kernel(
    const void* __restrict__ basev, const unsigned short* __restrict__ vin,
    const float* __restrict__ gg, const float* __restrict__ bb,
    void* __restrict__ outv)
{
    int token = blockIdx.x * 4 + (threadIdx.x >> 6);
    int lane = threadIdx.x & 63;
    size_t off = (size_t)token * 256 + lane * 4;
    short4 raw = *reinterpret_cast<const short4*>(&vin[off]);
    float f0 = bf2f((unsigned short)raw.x), f1 = bf2f((unsigned short)raw.y);
    float f2 = bf2f((unsigned short)raw.z), f3 = bf2f((unsigned short)raw.w);
    float s  = f0 + f1 + f2 + f3;
    float s2 = f0 * f0 + f1 * f1 + f2 * f2 + f3 * f3;
    #pragma unroll
    for (int m = 32; m >= 1; m >>= 1) { s += __shfl_xor(s, m, 64); s2 += __shfl_xor(s2, m, 64); }
    float mu = s * 0.00390625f;
    float var = s2 * 0.00390625f - mu * mu;
    float inv = rsqrtf(var + 1e-5f);

    float b0, b1v, b2, b3;
    if (BASE_F32) {
        float4 braw = *reinterpret_cast<const float4*>(&((const float*)basev)[off]);
        b0 = braw.x; b1v = braw.y; b2 = braw.z; b3 = braw.w;
    } else {
        short4 braw = *reinterpret_cast<const short4*>(&((const unsigned short*)basev)[off]);
        b0 = bf2f((unsigned short)braw.x); b1v = bf2f((unsigned short)braw.y);
        b2 = bf2f((unsigned short)braw.z); b3 = bf2f((unsigned short)braw.w);
    }
    float4 graw = *reinterpret_cast<const float4*>(&gg[lane * 4]);
    float4 brw2 = *reinterpret_cast<const float4*>(&bb[lane * 4]);
    float o0 = b0 + (f0 - mu) * inv * graw.x + brw2.x;
    float o1 = b1v + (f1 - mu) * inv * graw.y + brw2.y;
    float o2 = b2 + (f2 - mu) * inv * graw.z + brw2.z;
    float o3 = b3 + (f3 - mu) * inv * graw.w + brw2.w;
    if (OUT_F32) {
        float4 o; o.x = o0; o.y = o1; o.z = o2; o.w = o3;
        *reinterpret_cast<float4*>(&((float*)outv)[off]) = o;
    } else {
        short4 o;
        o.x = (short)f2bf(o0); o.y = (short)f2bf(o1);
        o.z = (short)f2bf(o2); o.w = (short)f2bf(o3);
        *reinterpret_cast<short4*>(&((unsigned short*)outv)[off]) = o;
    }
}

extern "C" void kernel_launch(void* const* d_in, const int* in_sizes, int n_in,
                              void* d_out, int out_size, void* d_ws, size_t ws_size,
                              hipStream_t stream) {
    const float* x      = (const float*)d_in[0];
    const float* qkv_w  = (const float*)d_in[1];
    const float* q_bias = (const float*)d_in[2];
    const float* v_bias = (const float*)d_in[3];
    const float* lscale = (const float*)d_in[4];
    const float* cpb_w1 = (const float*)d_in[5];
    const float* cpb_b1 = (const float*)d_in[6];
    const float* cpb_w2 = (const float*)d_in[7];
    const float* proj_w = (const float*)d_in[8];
    const float* proj_b = (const float*)d_in[9];
    const float* n1g    = (const float*)d_in[10];
    const float* n1b    = (const float*)d_in[11];
    const float* fc1_w  = (const float*)d_in[12];
    const float* fc1_b  = (const float*)d_in[13];
    const float* fc2_w  = (const float*)d_in[14];
    const float* fc2_b  = (const float*)d_in[15];
    const float* n2g    = (const float*)d_in[16];
    const float* n2b    = (const float*)d_in[17];
    const float* rct    = (const float*)d_in[18];
    const int*   rpi    = (const int*)d_in[19];

    char* ws = (char*)d_ws;
    unsigned short* qkv    = (unsigned short*)(ws);
    unsigned short* hbuf   = (unsigned short*)(ws);
    unsigned short* attn_o = (unsigned short*)(ws + 154140672);
    unsigned short* xb     = (unsigned short*)(ws + 205520896);
    unsigned short* x1     = (unsigned short*)(ws + 205520896);
    unsigned short* projy  = (unsigned short*)(ws + 256901120);
    unsigned short* wqkv   = (unsigned short*)(ws + 308281344);
    unsigned short* wproj  = (unsigned short*)(ws + 308674560);
    unsigned short* wfc1   = (unsigned short*)(ws + 308805632);
    unsigned short* wfc2   = (unsigned short*)(ws + 309329920);
    float*          rpbn   = (float*)(ws + 309854208);
    float*          scales = (float*)(ws + 310378496);
    float*          qkvb   = (float*)(ws + 310378528);

    const int M = 100352;

    conv_kernel<<<2048, 256, 0, stream>>>(x, xb, 25690112 / 4);
    conv_kernel<<<192, 256, 0, stream>>>(qkv_w, wqkv, 196608 / 4);
    conv_kernel<<<64, 256, 0, stream>>>(proj_w, wproj, 65536 / 4);
    conv_kernel<<<256, 256, 0, stream>>>(fc1_w, wfc1, 262144 / 4);
    conv_kernel<<<256, 256, 0, stream>>>(fc2_w, wfc2, 262144 / 4);
    prep_kernel<<<1, 256, 0, stream>>>(lscale, cpb_w1, cpb_b1, cpb_w2, q_bias, v_bias,
                                       rct, rpi, scales, rpbn, qkvb);
    gemm_kernel<0, 0><<<4704, 256, 0, stream>>>(xb, wqkv, qkvb, qkv, M, 768, 256, 6);
    attn_kernel<<<16384, 64, 0, stream>>>(qkv, scales, rpbn, attn_o);
    gemm_kernel<0, 1><<<1568, 256, 0, stream>>>(attn_o, wproj, proj_b, projy, M, 256, 256, 2);
    ln_add_kernel<0, 0><<<25088, 256, 0, stream>>>(xb, projy, n1g, n1b, x1);
    gemm_kernel<1, 0><<<6272, 256, 0, stream>>>(x1, wfc1, fc1_b, hbuf, M, 1024, 256, 8);
    gemm_kernel<0, 0><<<1568, 256, 0, stream>>>(hbuf, wfc2, fc2_b, projy, M, 256, 1024, 2);
    ln_add_kernel<0, 1><<<25088, 256, 0, stream>>>(x1, projy, n2g, n2b, d_out);
}

// Round 9
// 627.517 us; speedup vs baseline: 2.1459x; 1.0131x over previous
//
#include <hip/hip_runtime.h>
#include <hip/hip_bf16.h>

typedef __attribute__((ext_vector_type(8))) short short8_t;
typedef __attribute__((ext_vector_type(4))) float f32x4;

__device__ __forceinline__ float bf2f(unsigned short u) {
    return __uint_as_float(((unsigned)u) << 16);
}
__device__ __forceinline__ unsigned short f2bf(float f) {
    __hip_bfloat16 h = __float2bfloat16(f);
    return *reinterpret_cast<unsigned short*>(&h);
}

// exact-GELU via Abramowitz-Stegun 7.1.26 erf (|err| <= 1.5e-7), branch-free.
__device__ __forceinline__ float fast_gelu(float v) {
    float ax = fabsf(v) * 0.70710678118f;
    float t  = __builtin_amdgcn_rcpf(1.f + 0.3275911f * ax);
    float poly = t * (0.254829592f + t * (-0.284496736f + t * (1.421413741f
               + t * (-1.453152027f + t * 1.061405429f))));
    float e  = __expf(-ax * ax);
    float er = 1.f - poly * e;                 // erf(ax), ax >= 0
    float s  = (v >= 0.f) ? er : -er;
    return 0.5f * v * (1.f + s);
}

// async global->LDS, 16B per lane; LDS dest = wave-uniform base + lane*16
__device__ __forceinline__ void async16(const unsigned short* g, unsigned short* l) {
    __builtin_amdgcn_global_load_lds(
        (const __attribute__((address_space(1))) unsigned int*)g,
        (__attribute__((address_space(3))) unsigned int*)l,
        16, 0, 0);
}

// window-order row r (r = wb*49 + n) -> natural token index
__device__ __forceinline__ int win_row_to_token(int r) {
    int wb = r / 49, n = r - wb * 49;
    int wq = wb & 7, hb = (wb >> 3) & 7, d = (wb >> 6) & 7, b = wb >> 9;
    int hh = n / 7, ww2 = n - hh * 7;
    return ((b * 8 + d) * 56 + hb * 7 + hh) * 56 + wq * 7 + ww2;
}

// ---------------- f32 -> bf16 bulk convert ----------------
__global__ __launch_bounds__(256) void conv_kernel(
    const float* __restrict__ src, unsigned short* __restrict__ dst, int n4)
{
    int stride = gridDim.x * 256;
    for (int i = blockIdx.x * 256 + threadIdx.x; i < n4; i += stride) {
        float4 v = *reinterpret_cast<const float4*>(&src[(size_t)i * 4]);
        short4 o;
        o.x = (short)f2bf(v.x); o.y = (short)f2bf(v.y);
        o.z = (short)f2bf(v.z); o.w = (short)f2bf(v.w);
        *reinterpret_cast<short4*>(&dst[(size_t)i * 4]) = o;
    }
}

// ---------------- prep: scales, qkv bias, CPB-MLP -> rpbf (C-fragment layout) ----------------
// rpbf[h][mi][ji][r16][g4][r]: value rpb[i][j] with i=mi*16+g4*4+r, j=ji*16+r16;
// pads (i>=49 || j>=49) zeroed. 8*4096 floats.
__global__ __launch_bounds__(256) void prep_kernel(
    const float* __restrict__ logit_scale,
    const float* __restrict__ w1, const float* __restrict__ b1,
    const float* __restrict__ w2,
    const float* __restrict__ qb, const float* __restrict__ vb,
    const float* __restrict__ tabin, const int* __restrict__ rpi,
    float* __restrict__ scales, float* __restrict__ rpbf,
    float* __restrict__ qkvb)
{
    int t = threadIdx.x;
    if (t < 8) {
        float v = logit_scale[t];
        scales[t] = expf(fminf(v, 4.6051702f)); // ln(100)
    }
    for (int i = t; i < 768; i += 256) {
        float o;
        if (i < 256) o = qb[i];
        else if (i < 512) o = 0.f;
        else o = vb[i - 512];
        qkvb[i] = o;
    }
    __shared__ float table[169][8];
    for (int i = t; i < 169; i += 256) {
        float c0 = tabin[i * 3], c1 = tabin[i * 3 + 1], c2 = tabin[i * 3 + 2];
        float acc[8] = {0.f, 0.f, 0.f, 0.f, 0.f, 0.f, 0.f, 0.f};
        for (int j = 0; j < 512; ++j) {
            float hv = c0 * w1[j * 3] + c1 * w1[j * 3 + 1] + c2 * w1[j * 3 + 2] + b1[j];
            hv = fmaxf(hv, 0.f);
            #pragma unroll
            for (int h = 0; h < 8; ++h) acc[h] += hv * w2[h * 512 + j];
        }
        #pragma unroll
        for (int h = 0; h < 8; ++h) table[i][h] = acc[h];
    }
    __syncthreads();
    for (int e = t; e < 32768; e += 256) {
        int h = e >> 12, rem = e & 4095;
        int mi = rem >> 10, ji = (rem >> 8) & 3;
        int r16 = (rem >> 4) & 15, g4 = (rem >> 2) & 3, r = rem & 3;
        int i = mi * 16 + g4 * 4 + r, j = ji * 16 + r16;
        float val = 0.f;
        if (i < 49 && j < 49) {
            float xv = table[rpi[i * 49 + j]][h];
            val = 16.f / (1.f + expf(-xv));
        }
        rpbf[e] = val;
    }
}

// ---------------- GEMM: C[M,N] = A[M,K] * W[N,K]^T + bias (bf16 in/out) ----------------
// 128x128 tile, BK=32, 4 waves, double-buffered global_load_lds (2-phase).
// LDS 32KB (epilogue transposes overlay the dead pipeline buffers, 2 passes)
// -> 5 blocks/CU. Source-granule swizzle matched on read side.
template<int ACT, int SCATTER>
__global__ __launch_bounds__(256) void gemm_kernel(
    const unsigned short* __restrict__ A, const unsigned short* __restrict__ W,
    const float* __restrict__ bias, unsigned short* __restrict__ C,
    int M, int N, int K, int ntn)
{
    // pipeline: As(buf)=buf*4096, Bs(buf)=8192+buf*4096 (ushort idx); 32768 B
    __shared__ unsigned short smem[16384];
    const int tid = threadIdx.x;
    const int lane = tid & 63, wv = tid >> 6;
    const int wr = wv >> 1, wc = wv & 1;
    const int nwg = gridDim.x;
    const int virt = (blockIdx.x & 7) * (nwg >> 3) + (blockIdx.x >> 3);
    const int bn = virt % ntn, bm = virt / ntn;
    const size_t arow0 = (size_t)bm * 128;
    const size_t brow0 = (size_t)bn * 128;
    const int r16 = lane & 15, g4 = lane >> 4;
    const int srow_l = lane >> 2;                    // 0..15 row within issue
    const int sgran  = (lane & 3) ^ ((srow_l >> 1) & 3);
    f32x4 acc[4][4] = {};

    auto STAGE = [&](int buf, int kt) {
        unsigned short* As = smem + buf * 4096;
        unsigned short* Bs = smem + 8192 + buf * 4096;
        #pragma unroll
        for (int i = 0; i < 2; ++i) {
            int row0 = wv * 32 + i * 16;             // 16-row issue base
            async16(&A[(arow0 + row0 + srow_l) * (size_t)K + kt + sgran * 8], &As[row0 * 32]);
            async16(&W[(brow0 + row0 + srow_l) * (size_t)K + kt + sgran * 8], &Bs[row0 * 32]);
        }
    };
    auto COMPUTE = [&](int buf) {
        unsigned short* As = smem + buf * 4096;
        unsigned short* Bs = smem + 8192 + buf * 4096;
        short8_t af[4], bfr[4];
        const int gsw = g4 ^ ((r16 >> 1) & 3);
        #pragma unroll
        for (int m = 0; m < 4; ++m) {
            int row = wr * 64 + m * 16 + r16;
            af[m] = *reinterpret_cast<const short8_t*>(&As[row * 32 + gsw * 8]);
        }
        #pragma unroll
        for (int n = 0; n < 4; ++n) {
            int row = wc * 64 + n * 16 + r16;
            bfr[n] = *reinterpret_cast<const short8_t*>(&Bs[row * 32 + gsw * 8]);
        }
        #pragma unroll
        for (int m = 0; m < 4; ++m)
            #pragma unroll
            for (int n = 0; n < 4; ++n)
                acc[m][n] = __builtin_amdgcn_mfma_f32_16x16x32_bf16(af[m], bfr[n], acc[m][n], 0, 0, 0);
    };

    STAGE(0, 0);
    __syncthreads();
    int cur = 0;
    for (int kt = 32; kt < K; kt += 32) {
        STAGE(cur ^ 1, kt);
        COMPUTE(cur);
        __syncthreads();
        cur ^= 1;
    }
    COMPUTE(cur);
    __syncthreads();   // pipeline LDS dead from here; epilogue overlays it

    // ---- epilogue: 2 passes of per-wave 32x76 transpose -> coalesced stores ----
    unsigned short* Cs = smem + wv * 2432;   // 32 x 76 ushorts per wave
    const int rbase = g4 * 4;
    const int srow = lane >> 3, scol = (lane & 7) * 8;
    const int gcol0 = bn * 128 + wc * 64;
    #pragma unroll
    for (int p = 0; p < 2; ++p) {
        #pragma unroll
        for (int n = 0; n < 4; ++n) {
            float bv = bias[bn * 128 + wc * 64 + n * 16 + r16];
            #pragma unroll
            for (int m2 = 0; m2 < 2; ++m2) {
                int m = p * 2 + m2;
                #pragma unroll
                for (int r = 0; r < 4; ++r) {
                    float v = acc[m][n][r] + bv;
                    if (ACT == 1) v = fast_gelu(v);
                    Cs[(m2 * 16 + rbase + r) * 76 + n * 16 + r16] = f2bf(v);
                }
            }
        }
        #pragma unroll
        for (int rr = 0; rr < 4; ++rr) {
            int lr = rr * 8 + srow;                   // 0..31
            int grow = bm * 128 + wr * 64 + p * 32 + lr;
            size_t orow = SCATTER ? (size_t)win_row_to_token(grow) : (size_t)grow;
            short8_t vv = *reinterpret_cast<const short8_t*>(&Cs[lr * 76 + scol]);
            *reinterpret_cast<short8_t*>(&C[orow * (size_t)N + gcol0 + scol]) = vv;
        }
    }
}

// ---------------- attention: one WAVE per (window, head), MFMA ----------------
// LDS (ushort): Q[64 rows][40] at 0 (rows 49+ garbage, in-bounds), K same at 2560,
// V^T[32][72] at 5120. P[64][72] overlays Q+K after QK. Total 14848 B.
__global__ __launch_bounds__(64) void attn_kernel(
    const unsigned short* __restrict__ qkv, const float* __restrict__ scales,
    const float* __restrict__ rpbf, unsigned short* __restrict__ out)
{
    constexpr int QO = 0;
    constexpr int KO = 2560;
    constexpr int VO = 5120;
    constexpr int PO = 0;
    __shared__ unsigned short lds[7424];

    const int blk = blockIdx.x;
    const int h = blk & 7, wb = blk >> 3;
    const int lane = threadIdx.x;
    const int r16 = lane & 15, g4 = lane >> 4;

    const int wq = wb & 7, hb = (wb >> 3) & 7, dd = (wb >> 6) & 7, bb2 = wb >> 9;
    const int tok_base = ((bb2 * 8 + dd) * 56 + hb * 7) * 56 + wq * 7;
    const float sc = scales[h];

    // zero V^T j-pad (j 48..63; j=48 rewritten by transpose below, same-wave order)
    {
        short8_t z = {};
        int d = lane >> 1, j0 = 48 + (lane & 1) * 8;
        *reinterpret_cast<short8_t*>(&lds[VO + d * 72 + j0]) = z;
    }
    // stage Q (scaled) and K with fused l2norm; 4 granules of 8 per row
    #pragma unroll
    for (int sel = 0; sel < 2; ++sel) {
        for (int c = lane; c < 196; c += 64) {
            int row = c >> 2, gi = c & 3;
            int tok = tok_base + (row / 7) * 56 + (row % 7);
            const unsigned short* gp = qkv + (size_t)tok * 768 + sel * 256 + h * 32 + gi * 8;
            short8_t raw = *reinterpret_cast<const short8_t*>(gp);
            float f[8]; float ss = 0.f;
            #pragma unroll
            for (int e = 0; e < 8; ++e) { f[e] = bf2f((unsigned short)raw[e]); ss += f[e] * f[e]; }
            ss += __shfl_xor(ss, 1); ss += __shfl_xor(ss, 2);
            float inv = 1.f / fmaxf(sqrtf(ss), 1e-12f);
            if (sel == 0) inv *= sc;
            short8_t o;
            #pragma unroll
            for (int e = 0; e < 8; ++e) o[e] = (short)f2bf(f[e] * inv);
            *reinterpret_cast<short8_t*>(&lds[(sel ? KO : QO) + row * 40 + gi * 8]) = o;
        }
    }
    // stage V^T via register transpose: short8 row loads -> 8 scalar LDS writes
    for (int c = lane; c < 196; c += 64) {
        int j = c >> 2, gi = c & 3;
        int tok = tok_base + (j / 7) * 56 + (j % 7);
        short8_t raw = *reinterpret_cast<const short8_t*>(
            qkv + (size_t)tok * 768 + 512 + h * 32 + gi * 8);
        #pragma unroll
        for (int e = 0; e < 8; ++e)
            lds[VO + (gi * 8 + e) * 72 + j] = (unsigned short)raw[e];
    }
    __syncthreads();

    // ---- QK^T: 4x4 tiles of 16x16, single K=32 MFMA each ----
    short8_t qf[4], kf[4];
    #pragma unroll
    for (int mi = 0; mi < 4; ++mi)
        qf[mi] = *reinterpret_cast<const short8_t*>(&lds[QO + (mi * 16 + r16) * 40 + g4 * 8]);
    #pragma unroll
    for (int ji = 0; ji < 4; ++ji)
        kf[ji] = *reinterpret_cast<const short8_t*>(&lds[KO + (ji * 16 + r16) * 40 + g4 * 8]);
    f32x4 acc[4][4] = {};
    #pragma unroll
    for (int mi = 0; mi < 4; ++mi)
        #pragma unroll
        for (int ji = 0; ji < 4; ++ji)
            acc[mi][ji] = __builtin_amdgcn_mfma_f32_16x16x32_bf16(qf[mi], kf[ji], acc[mi][ji], 0, 0, 0);
    __syncthreads();   // Q/K dead; P overlays them

    // ---- prefetch rpb fragments (fragment-layout table, pads = 0) ----
    const float* rbf = rpbf + h * 4096 + r16 * 16 + g4 * 4;
    f32x4 rbv[4][4];
    #pragma unroll
    for (int mi = 0; mi < 4; ++mi)
        #pragma unroll
        for (int ji = 0; ji < 4; ++ji)
            rbv[mi][ji] = *reinterpret_cast<const f32x4*>(&rbf[(mi * 4 + ji) * 256]);

    // ---- softmax over j, P -> LDS bf16 ----
    #pragma unroll
    for (int mi = 0; mi < 4; ++mi) {
        #pragma unroll
        for (int r = 0; r < 4; ++r) {
            int i = mi * 16 + g4 * 4 + r;
            float s[4]; float m = -1e30f;
            #pragma unroll
            for (int ji = 0; ji < 4; ++ji) {
                int j = ji * 16 + r16;
                float v = acc[mi][ji][r] + rbv[mi][ji][r];
                s[ji] = (j < 49) ? v : -1e30f;
                m = fmaxf(m, s[ji]);
            }
            m = fmaxf(m, __shfl_xor(m, 1)); m = fmaxf(m, __shfl_xor(m, 2));
            m = fmaxf(m, __shfl_xor(m, 4)); m = fmaxf(m, __shfl_xor(m, 8));
            float p[4]; float sum = 0.f;
            #pragma unroll
            for (int ji = 0; ji < 4; ++ji) {
                p[ji] = (s[ji] > -1e29f) ? __expf(s[ji] - m) : 0.f;
                sum += p[ji];
            }
            sum += __shfl_xor(sum, 1); sum += __shfl_xor(sum, 2);
            sum += __shfl_xor(sum, 4); sum += __shfl_xor(sum, 8);
            float rinv = 1.f / sum;
            #pragma unroll
            for (int ji = 0; ji < 4; ++ji) {
                int j = ji * 16 + r16;
                lds[PO + i * 72 + j] = f2bf(p[ji] * rinv);
            }
        }
    }
    __syncthreads();

    // ---- PV: out[i,d] = sum_j P[i,j] * Vt[d,j]; 4x2 tiles x 2 k-steps ----
    f32x4 acc2[4][2] = {};
    #pragma unroll
    for (int ks = 0; ks < 2; ++ks) {
        short8_t pf[4], vf[2];
        int ko = ks * 32 + g4 * 8;
        #pragma unroll
        for (int mi = 0; mi < 4; ++mi)
            pf[mi] = *reinterpret_cast<const short8_t*>(&lds[PO + (mi * 16 + r16) * 72 + ko]);
        #pragma unroll
        for (int ni = 0; ni < 2; ++ni)
            vf[ni] = *reinterpret_cast<const short8_t*>(&lds[VO + (ni * 16 + r16) * 72 + ko]);
        #pragma unroll
        for (int mi = 0; mi < 4; ++mi)
            #pragma unroll
            for (int ni = 0; ni < 2; ++ni)
                acc2[mi][ni] = __builtin_amdgcn_mfma_f32_16x16x32_bf16(pf[mi], vf[ni], acc2[mi][ni], 0, 0, 0);
    }

    #pragma unroll
    for (int mi = 0; mi < 4; ++mi)
        #pragma unroll
        for (int r = 0; r < 4; ++r) {
            int i = mi * 16 + g4 * 4 + r;
            if (i < 49) {
                size_t ob = (size_t)(wb * 49 + i) * 256 + h * 32;
                out[ob + r16]      = f2bf(acc2[mi][0][r]);
                out[ob + 16 + r16] = f2bf(acc2[mi][1][r]);
            }
        }
}

// ---------------- fused residual + LayerNorm (one wave per token) ----------------
template<int BASE_F32, int OUT_F32>
__global__ __launch_bounds__(256) void ln_add_kernel(
    const void* __restrict__ basev, const unsigned short* __restrict__ vin,
    const float* __restrict__ gg, const float* __restrict__ bb,
    void* __restrict__ outv)
{
    int token = blockIdx.x * 4 + (threadIdx.x >> 6);
    int lane = threadIdx.x & 63;
    size_t off = (size_t)token * 256 + lane * 4;
    short4 raw = *reinterpret_cast<const short4*>(&vin[off]);
    float f0 = bf2f((unsigned short)raw.x), f1 = bf2f((unsigned short)raw.y);
    float f2 = bf2f((unsigned short)raw.z), f3 = bf2f((unsigned short)raw.w);
    float s  = f0 + f1 + f2 + f3;
    float s2 = f0 * f0 + f1 * f1 + f2 * f2 + f3 * f3;
    #pragma unroll
    for (int m = 32; m >= 1; m >>= 1) { s += __shfl_xor(s, m, 64); s2 += __shfl_xor(s2, m, 64); }
    float mu = s * 0.00390625f;
    float var = s2 * 0.00390625f - mu * mu;
    float inv = rsqrtf(var + 1e-5f);

    float b0, b1v, b2, b3;
    if (BASE_F32) {
        float4 braw = *reinterpret_cast<const float4*>(&((const float*)basev)[off]);
        b0 = braw.x; b1v = braw.y; b2 = braw.z; b3 = braw.w;
    } else {
        short4 braw = *reinterpret_cast<const short4*>(&((const unsigned short*)basev)[off]);
        b0 = bf2f((unsigned short)braw.x); b1v = bf2f((unsigned short)braw.y);
        b2 = bf2f((unsigned short)braw.z); b3 = bf2f((unsigned short)braw.w);
    }
    float4 graw = *reinterpret_cast<const float4*>(&gg[lane * 4]);
    float4 brw2 = *reinterpret_cast<const float4*>(&bb[lane * 4]);
    float o0 = b0 + (f0 - mu) * inv * graw.x + brw2.x;
    float o1 = b1v + (f1 - mu) * inv * graw.y + brw2.y;
    float o2 = b2 + (f2 - mu) * inv * graw.z + brw2.z;
    float o3 = b3 + (f3 - mu) * inv * graw.w + brw2.w;
    if (OUT_F32) {
        float4 o; o.x = o0; o.y = o1; o.z = o2; o.w = o3;
        *reinterpret_cast<float4*>(&((float*)outv)[off]) = o;
    } else {
        short4 o;
        o.x = (short)f2bf(o0); o.y = (short)f2bf(o1);
        o.z = (short)f2bf(o2); o.w = (short)f2bf(o3);
        *reinterpret_cast<short4*>(&((unsigned short*)outv)[off]) = o;
    }
}

extern "C" void kernel_launch(void* const* d_in, const int* in_sizes, int n_in,
                              void* d_out, int out_size, void* d_ws, size_t ws_size,
                              hipStream_t stream) {
    const float* x      = (const float*)d_in[0];
    const float* qkv_w  = (const float*)d_in[1];
    const float* q_bias = (const float*)d_in[2];
    const float* v_bias = (const float*)d_in[3];
    const float* lscale = (const float*)d_in[4];
    const float* cpb_w1 = (const float*)d_in[5];
    const float* cpb_b1 = (const float*)d_in[6];
    const float* cpb_w2 = (const float*)d_in[7];
    const float* proj_w = (const float*)d_in[8];
    const float* proj_b = (const float*)d_in[9];
    const float* n1g    = (const float*)d_in[10];
    const float* n1b    = (const float*)d_in[11];
    const float* fc1_w  = (const float*)d_in[12];
    const float* fc1_b  = (const float*)d_in[13];
    const float* fc2_w  = (const float*)d_in[14];
    const float* fc2_b  = (const float*)d_in[15];
    const float* n2g    = (const float*)d_in[16];
    const float* n2b    = (const float*)d_in[17];
    const float* rct    = (const float*)d_in[18];
    const int*   rpi    = (const int*)d_in[19];

    char* ws = (char*)d_ws;
    unsigned short* qkv    = (unsigned short*)(ws);
    unsigned short* hbuf   = (unsigned short*)(ws);
    unsigned short* attn_o = (unsigned short*)(ws + 154140672);
    unsigned short* xb     = (unsigned short*)(ws + 205520896);
    unsigned short* x1     = (unsigned short*)(ws + 205520896);
    unsigned short* projy  = (unsigned short*)(ws + 256901120);
    unsigned short* wqkv   = (unsigned short*)(ws + 308281344);
    unsigned short* wproj  = (unsigned short*)(ws + 308674560);
    unsigned short* wfc1   = (unsigned short*)(ws + 308805632);
    unsigned short* wfc2   = (unsigned short*)(ws + 309329920);
    float*          rpbf   = (float*)(ws + 309854208);   // 131072 B
    float*          scales = (float*)(ws + 310378496);
    float*          qkvb   = (float*)(ws + 310378528);

    const int M = 100352;

    conv_kernel<<<2048, 256, 0, stream>>>(x, xb, 25690112 / 4);
    conv_kernel<<<192, 256, 0, stream>>>(qkv_w, wqkv, 196608 / 4);
    conv_kernel<<<64, 256, 0, stream>>>(proj_w, wproj, 65536 / 4);
    conv_kernel<<<256, 256, 0, stream>>>(fc1_w, wfc1, 262144 / 4);
    conv_kernel<<<256, 256, 0, stream>>>(fc2_w, wfc2, 262144 / 4);
    prep_kernel<<<1, 256, 0, stream>>>(lscale, cpb_w1, cpb_b1, cpb_w2, q_bias, v_bias,
                                       rct, rpi, scales, rpbf, qkvb);
    gemm_kernel<0, 0><<<4704, 256, 0, stream>>>(xb, wqkv, qkvb, qkv, M, 768, 256, 6);
    attn_kernel<<<16384, 64, 0, stream>>>(qkv, scales, rpbf, attn_o);
    gemm_kernel<0, 1><<<1568, 256, 0, stream>>>(attn_o, wproj, proj_b, projy, M, 256, 256, 2);
    ln_add_kernel<0, 0><<<25088, 256, 0, stream>>>(xb, projy, n1g, n1b, x1);
    gemm_kernel<1, 0><<<6272, 256, 0, stream>>>(x1, wfc1, fc1_b, hbuf, M, 1024, 256, 8);
    gemm_kernel<0, 0><<<1568, 256, 0, stream>>>(hbuf, wfc2, fc2_b, projy, M, 256, 1024, 2);
    ln_add_kernel<0, 1><<<25088, 256, 0, stream>>>(x1, projy, n2g, n2b, d_out);
}

// Round 11
// 601.499 us; speedup vs baseline: 2.2387x; 1.0433x over previous
//
#include <hip/hip_runtime.h>
#include <hip/hip_bf16.h>

typedef __attribute__((ext_vector_type(8))) short short8_t;
typedef __attribute__((ext_vector_type(4))) float f32x4;

__device__ __forceinline__ float bf2f(unsigned short u) {
    return __uint_as_float(((unsigned)u) << 16);
}
__device__ __forceinline__ unsigned short f2bf(float f) {
    __hip_bfloat16 h = __float2bfloat16(f);
    return *reinterpret_cast<unsigned short*>(&h);
}

// exact-GELU via Abramowitz-Stegun 7.1.26 erf (|err| <= 1.5e-7), branch-free.
__device__ __forceinline__ float fast_gelu(float v) {
    float ax = fabsf(v) * 0.70710678118f;
    float t  = __builtin_amdgcn_rcpf(1.f + 0.3275911f * ax);
    float poly = t * (0.254829592f + t * (-0.284496736f + t * (1.421413741f
               + t * (-1.453152027f + t * 1.061405429f))));
    float e  = __expf(-ax * ax);
    float er = 1.f - poly * e;                 // erf(ax), ax >= 0
    float s  = (v >= 0.f) ? er : -er;
    return 0.5f * v * (1.f + s);
}

// async global->LDS, 16B per lane; LDS dest = wave-uniform base + lane*16
__device__ __forceinline__ void async16(const unsigned short* g, unsigned short* l) {
    __builtin_amdgcn_global_load_lds(
        (const __attribute__((address_space(1))) unsigned int*)g,
        (__attribute__((address_space(3))) unsigned int*)l,
        16, 0, 0);
}

// window-order row r (r = wb*49 + n) -> natural token index
__device__ __forceinline__ int win_row_to_token(int r) {
    int wb = r / 49, n = r - wb * 49;
    int wq = wb & 7, hb = (wb >> 3) & 7, d = (wb >> 6) & 7, b = wb >> 9;
    int hh = n / 7, ww2 = n - hh * 7;
    return ((b * 8 + d) * 56 + hb * 7 + hh) * 56 + wq * 7 + ww2;
}

// ---------------- f32 -> bf16 bulk convert ----------------
__global__ __launch_bounds__(256) void conv_kernel(
    const float* __restrict__ src, unsigned short* __restrict__ dst, int n4)
{
    int stride = gridDim.x * 256;
    for (int i = blockIdx.x * 256 + threadIdx.x; i < n4; i += stride) {
        float4 v = *reinterpret_cast<const float4*>(&src[(size_t)i * 4]);
        short4 o;
        o.x = (short)f2bf(v.x); o.y = (short)f2bf(v.y);
        o.z = (short)f2bf(v.z); o.w = (short)f2bf(v.w);
        *reinterpret_cast<short4*>(&dst[(size_t)i * 4]) = o;
    }
}

// 4 weight tensors in one dispatch (vec4 counts)
__global__ __launch_bounds__(256) void conv4_kernel(
    const float* __restrict__ s0, unsigned short* __restrict__ d0, int n0,
    const float* __restrict__ s1, unsigned short* __restrict__ d1, int n1,
    const float* __restrict__ s2, unsigned short* __restrict__ d2, int n2,
    const float* __restrict__ s3, unsigned short* __restrict__ d3, int n3)
{
    int stride = gridDim.x * 256;
    int total = n0 + n1 + n2 + n3;
    for (int i = blockIdx.x * 256 + threadIdx.x; i < total; i += stride) {
        const float* s; unsigned short* d; int j = i;
        if (j < n0) { s = s0; d = d0; }
        else if ((j -= n0) < n1) { s = s1; d = d1; }
        else if ((j -= n1) < n2) { s = s2; d = d2; }
        else { j -= n2; s = s3; d = d3; }
        float4 v = *reinterpret_cast<const float4*>(&s[(size_t)j * 4]);
        short4 o;
        o.x = (short)f2bf(v.x); o.y = (short)f2bf(v.y);
        o.z = (short)f2bf(v.z); o.w = (short)f2bf(v.w);
        *reinterpret_cast<short4*>(&d[(size_t)j * 4]) = o;
    }
}

// ---------------- prep: scales, qkv bias, CPB-MLP -> rpbf (C-fragment layout) ----------------
__global__ __launch_bounds__(256) void prep_kernel(
    const float* __restrict__ logit_scale,
    const float* __restrict__ w1, const float* __restrict__ b1,
    const float* __restrict__ w2,
    const float* __restrict__ qb, const float* __restrict__ vb,
    const float* __restrict__ tabin, const int* __restrict__ rpi,
    float* __restrict__ scales, float* __restrict__ rpbf,
    float* __restrict__ qkvb)
{
    int t = threadIdx.x;
    if (t < 8) {
        float v = logit_scale[t];
        scales[t] = expf(fminf(v, 4.6051702f)); // ln(100)
    }
    for (int i = t; i < 768; i += 256) {
        float o;
        if (i < 256) o = qb[i];
        else if (i < 512) o = 0.f;
        else o = vb[i - 512];
        qkvb[i] = o;
    }
    __shared__ float table[169][8];
    for (int i = t; i < 169; i += 256) {
        float c0 = tabin[i * 3], c1 = tabin[i * 3 + 1], c2 = tabin[i * 3 + 2];
        float acc[8] = {0.f, 0.f, 0.f, 0.f, 0.f, 0.f, 0.f, 0.f};
        for (int j = 0; j < 512; ++j) {
            float hv = c0 * w1[j * 3] + c1 * w1[j * 3 + 1] + c2 * w1[j * 3 + 2] + b1[j];
            hv = fmaxf(hv, 0.f);
            #pragma unroll
            for (int h = 0; h < 8; ++h) acc[h] += hv * w2[h * 512 + j];
        }
        #pragma unroll
        for (int h = 0; h < 8; ++h) table[i][h] = acc[h];
    }
    __syncthreads();
    for (int e = t; e < 32768; e += 256) {
        int h = e >> 12, rem = e & 4095;
        int mi = rem >> 10, ji = (rem >> 8) & 3;
        int r16 = (rem >> 4) & 15, g4 = (rem >> 2) & 3, r = rem & 3;
        int i = mi * 16 + g4 * 4 + r, j = ji * 16 + r16;
        float val = 0.f;
        if (i < 49 && j < 49) {
            float xv = table[rpi[i * 49 + j]][h];
            val = 16.f / (1.f + expf(-xv));
        }
        rpbf[e] = val;
    }
}

// ---------------- GEMM: C[M,N] = A[M,K] * W[N,K]^T + bias (bf16 in/out) ----------------
// 128x128 tile, BK=32, 4 waves, double-buffered global_load_lds with COUNTED
// vmcnt waits. Barriers are asm s_barrier WITH "memory" clobber (IR fence) and
// sched_barrier(0) pins — rule #18: raw builtin barriers let hipcc reorder LDS
// ops across them (round-10 race).
template<int ACT, int SCATTER>
__global__ __launch_bounds__(256) void gemm_kernel(
    const unsigned short* __restrict__ A, const unsigned short* __restrict__ W,
    const float* __restrict__ bias, unsigned short* __restrict__ C,
    int M, int N, int K, int ntn)
{
    __shared__ unsigned short smem[16384];
    const int tid = threadIdx.x;
    const int lane = tid & 63, wv = tid >> 6;
    const int wr = wv >> 1, wc = wv & 1;
    const int nwg = gridDim.x;
    const int virt = (blockIdx.x & 7) * (nwg >> 3) + (blockIdx.x >> 3);
    const int bn = virt % ntn, bm = virt / ntn;
    const size_t arow0 = (size_t)bm * 128;
    const size_t brow0 = (size_t)bn * 128;
    const int r16 = lane & 15, g4 = lane >> 4;
    const int srow_l = lane >> 2;                    // 0..15 row within issue
    const int sgran  = (lane & 3) ^ ((srow_l >> 1) & 3);
    f32x4 acc[4][4] = {};

    auto STAGE = [&](int buf, int kt) {             // 4 loads/thread
        unsigned short* As = smem + buf * 4096;
        unsigned short* Bs = smem + 8192 + buf * 4096;
        #pragma unroll
        for (int i = 0; i < 2; ++i) {
            int row0 = wv * 32 + i * 16;
            async16(&A[(arow0 + row0 + srow_l) * (size_t)K + kt + sgran * 8], &As[row0 * 32]);
            async16(&W[(brow0 + row0 + srow_l) * (size_t)K + kt + sgran * 8], &Bs[row0 * 32]);
        }
    };
    auto COMPUTE = [&](int buf) {
        unsigned short* As = smem + buf * 4096;
        unsigned short* Bs = smem + 8192 + buf * 4096;
        short8_t af[4], bfr[4];
        const int gsw = g4 ^ ((r16 >> 1) & 3);
        #pragma unroll
        for (int m = 0; m < 4; ++m) {
            int row = wr * 64 + m * 16 + r16;
            af[m] = *reinterpret_cast<const short8_t*>(&As[row * 32 + gsw * 8]);
        }
        #pragma unroll
        for (int n = 0; n < 4; ++n) {
            int row = wc * 64 + n * 16 + r16;
            bfr[n] = *reinterpret_cast<const short8_t*>(&Bs[row * 32 + gsw * 8]);
        }
        #pragma unroll
        for (int m = 0; m < 4; ++m)
            #pragma unroll
            for (int n = 0; n < 4; ++n)
                acc[m][n] = __builtin_amdgcn_mfma_f32_16x16x32_bf16(af[m], bfr[n], acc[m][n], 0, 0, 0);
    };

    const int nk = K >> 5;
    STAGE(0, 0);
    STAGE(1, 32);
    int cur = 0;
    for (int ks = 0; ks < nk - 1; ++ks) {
        // wait only for oldest stage's 4 loads; newer stage stays in flight
        asm volatile("s_waitcnt vmcnt(4)" ::: "memory");
        __builtin_amdgcn_sched_barrier(0);
        asm volatile("s_barrier" ::: "memory");      // buf cur fully populated
        COMPUTE(cur);
        __builtin_amdgcn_sched_barrier(0);
        asm volatile("s_barrier" ::: "memory");      // all reads of buf cur done
        if (ks + 2 < nk) STAGE(cur, (ks + 2) << 5);  // restage 2 ahead
        cur ^= 1;
    }
    asm volatile("s_waitcnt vmcnt(0)" ::: "memory"); // final tile: full drain
    __builtin_amdgcn_sched_barrier(0);
    asm volatile("s_barrier" ::: "memory");
    COMPUTE(cur);
    __builtin_amdgcn_sched_barrier(0);
    asm volatile("s_barrier" ::: "memory");          // LDS dead; epilogue overlays

    // ---- epilogue: 2 passes of per-wave 32x76 transpose -> coalesced stores ----
    unsigned short* Cs = smem + wv * 2432;   // 32 x 76 ushorts per wave
    const int rbase = g4 * 4;
    const int srow = lane >> 3, scol = (lane & 7) * 8;
    const int gcol0 = bn * 128 + wc * 64;
    #pragma unroll
    for (int p = 0; p < 2; ++p) {
        #pragma unroll
        for (int n = 0; n < 4; ++n) {
            float bv = bias[bn * 128 + wc * 64 + n * 16 + r16];
            #pragma unroll
            for (int m2 = 0; m2 < 2; ++m2) {
                int m = p * 2 + m2;
                #pragma unroll
                for (int r = 0; r < 4; ++r) {
                    float v = acc[m][n][r] + bv;
                    if (ACT == 1) v = fast_gelu(v);
                    Cs[(m2 * 16 + rbase + r) * 76 + n * 16 + r16] = f2bf(v);
                }
            }
        }
        #pragma unroll
        for (int rr = 0; rr < 4; ++rr) {
            int lr = rr * 8 + srow;                   // 0..31
            int grow = bm * 128 + wr * 64 + p * 32 + lr;
            size_t orow = SCATTER ? (size_t)win_row_to_token(grow) : (size_t)grow;
            short8_t vv = *reinterpret_cast<const short8_t*>(&Cs[lr * 76 + scol]);
            *reinterpret_cast<short8_t*>(&C[orow * (size_t)N + gcol0 + scol]) = vv;
        }
    }
}

// ---------------- attention: one WAVE per (window, head), MFMA ----------------
// LDS (ushort): Q[64 rows][40] at 0, K at 2560, V^T[32][72] at 5120;
// P[64][72] overlays Q+K after QK. Total 14848 B.
__global__ __launch_bounds__(64) void attn_kernel(
    const unsigned short* __restrict__ qkv, const float* __restrict__ scales,
    const float* __restrict__ rpbf, unsigned short* __restrict__ out)
{
    constexpr int QO = 0;
    constexpr int KO = 2560;
    constexpr int VO = 5120;
    constexpr int PO = 0;
    __shared__ unsigned short lds[7424];

    const int blk = blockIdx.x;
    const int h = blk & 7, wb = blk >> 3;
    const int lane = threadIdx.x;
    const int r16 = lane & 15, g4 = lane >> 4;

    const int wq = wb & 7, hb = (wb >> 3) & 7, dd = (wb >> 6) & 7, bb2 = wb >> 9;
    const int tok_base = ((bb2 * 8 + dd) * 56 + hb * 7) * 56 + wq * 7;
    const float sc = scales[h];

    {
        short8_t z = {};
        int d = lane >> 1, j0 = 48 + (lane & 1) * 8;
        *reinterpret_cast<short8_t*>(&lds[VO + d * 72 + j0]) = z;
    }
    #pragma unroll
    for (int sel = 0; sel < 2; ++sel) {
        for (int c = lane; c < 196; c += 64) {
            int row = c >> 2, gi = c & 3;
            int tok = tok_base + (row / 7) * 56 + (row % 7);
            const unsigned short* gp = qkv + (size_t)tok * 768 + sel * 256 + h * 32 + gi * 8;
            short8_t raw = *reinterpret_cast<const short8_t*>(gp);
            float f[8]; float ss = 0.f;
            #pragma unroll
            for (int e = 0; e < 8; ++e) { f[e] = bf2f((unsigned short)raw[e]); ss += f[e] * f[e]; }
            ss += __shfl_xor(ss, 1); ss += __shfl_xor(ss, 2);
            float inv = 1.f / fmaxf(sqrtf(ss), 1e-12f);
            if (sel == 0) inv *= sc;
            short8_t o;
            #pragma unroll
            for (int e = 0; e < 8; ++e) o[e] = (short)f2bf(f[e] * inv);
            *reinterpret_cast<short8_t*>(&lds[(sel ? KO : QO) + row * 40 + gi * 8]) = o;
        }
    }
    for (int c = lane; c < 196; c += 64) {
        int j = c >> 2, gi = c & 3;
        int tok = tok_base + (j / 7) * 56 + (j % 7);
        short8_t raw = *reinterpret_cast<const short8_t*>(
            qkv + (size_t)tok * 768 + 512 + h * 32 + gi * 8);
        #pragma unroll
        for (int e = 0; e < 8; ++e)
            lds[VO + (gi * 8 + e) * 72 + j] = (unsigned short)raw[e];
    }
    __syncthreads();

    short8_t qf[4], kf[4];
    #pragma unroll
    for (int mi = 0; mi < 4; ++mi)
        qf[mi] = *reinterpret_cast<const short8_t*>(&lds[QO + (mi * 16 + r16) * 40 + g4 * 8]);
    #pragma unroll
    for (int ji = 0; ji < 4; ++ji)
        kf[ji] = *reinterpret_cast<const short8_t*>(&lds[KO + (ji * 16 + r16) * 40 + g4 * 8]);
    f32x4 acc[4][4] = {};
    #pragma unroll
    for (int mi = 0; mi < 4; ++mi)
        #pragma unroll
        for (int ji = 0; ji < 4; ++ji)
            acc[mi][ji] = __builtin_amdgcn_mfma_f32_16x16x32_bf16(qf[mi], kf[ji], acc[mi][ji], 0, 0, 0);
    __syncthreads();   // Q/K dead; P overlays them

    const float* rbf = rpbf + h * 4096 + r16 * 16 + g4 * 4;
    f32x4 rbv[4][4];
    #pragma unroll
    for (int mi = 0; mi < 4; ++mi)
        #pragma unroll
        for (int ji = 0; ji < 4; ++ji)
            rbv[mi][ji] = *reinterpret_cast<const f32x4*>(&rbf[(mi * 4 + ji) * 256]);

    #pragma unroll
    for (int mi = 0; mi < 4; ++mi) {
        #pragma unroll
        for (int r = 0; r < 4; ++r) {
            int i = mi * 16 + g4 * 4 + r;
            float s[4]; float m = -1e30f;
            #pragma unroll
            for (int ji = 0; ji < 4; ++ji) {
                int j = ji * 16 + r16;
                float v = acc[mi][ji][r] + rbv[mi][ji][r];
                s[ji] = (j < 49) ? v : -1e30f;
                m = fmaxf(m, s[ji]);
            }
            m = fmaxf(m, __shfl_xor(m, 1)); m = fmaxf(m, __shfl_xor(m, 2));
            m = fmaxf(m, __shfl_xor(m, 4)); m = fmaxf(m, __shfl_xor(m, 8));
            float p[4]; float sum = 0.f;
            #pragma unroll
            for (int ji = 0; ji < 4; ++ji) {
                p[ji] = (s[ji] > -1e29f) ? __expf(s[ji] - m) : 0.f;
                sum += p[ji];
            }
            sum += __shfl_xor(sum, 1); sum += __shfl_xor(sum, 2);
            sum += __shfl_xor(sum, 4); sum += __shfl_xor(sum, 8);
            float rinv = 1.f / sum;
            #pragma unroll
            for (int ji = 0; ji < 4; ++ji) {
                int j = ji * 16 + r16;
                lds[PO + i * 72 + j] = f2bf(p[ji] * rinv);
            }
        }
    }
    __syncthreads();

    f32x4 acc2[4][2] = {};
    #pragma unroll
    for (int ks = 0; ks < 2; ++ks) {
        short8_t pf[4], vf[2];
        int ko = ks * 32 + g4 * 8;
        #pragma unroll
        for (int mi = 0; mi < 4; ++mi)
            pf[mi] = *reinterpret_cast<const short8_t*>(&lds[PO + (mi * 16 + r16) * 72 + ko]);
        #pragma unroll
        for (int ni = 0; ni < 2; ++ni)
            vf[ni] = *reinterpret_cast<const short8_t*>(&lds[VO + (ni * 16 + r16) * 72 + ko]);
        #pragma unroll
        for (int mi = 0; mi < 4; ++mi)
            #pragma unroll
            for (int ni = 0; ni < 2; ++ni)
                acc2[mi][ni] = __builtin_amdgcn_mfma_f32_16x16x32_bf16(pf[mi], vf[ni], acc2[mi][ni], 0, 0, 0);
    }

    #pragma unroll
    for (int mi = 0; mi < 4; ++mi)
        #pragma unroll
        for (int r = 0; r < 4; ++r) {
            int i = mi * 16 + g4 * 4 + r;
            if (i < 49) {
                size_t ob = (size_t)(wb * 49 + i) * 256 + h * 32;
                out[ob + r16]      = f2bf(acc2[mi][0][r]);
                out[ob + 16 + r16] = f2bf(acc2[mi][1][r]);
            }
        }
}

// ---------------- fused residual + LayerNorm (one wave per token) ----------------
template<int BASE_F32, int OUT_F32>
__global__ __launch_bounds__(256) void ln_add_kernel(
    const void* __restrict__ basev, const unsigned short* __restrict__ vin,
    const float* __restrict__ gg, const float* __restrict__ bb,
    void* __restrict__ outv)
{
    int token = blockIdx.x * 4 + (threadIdx.x >> 6);
    int lane = threadIdx.x & 63;
    size_t off = (size_t)token * 256 + lane * 4;
    short4 raw = *reinterpret_cast<const short4*>(&vin[off]);
    float f0 = bf2f((unsigned short)raw.x), f1 = bf2f((unsigned short)raw.y);
    float f2 = bf2f((unsigned short)raw.z), f3 = bf2f((unsigned short)raw.w);
    float s  = f0 + f1 + f2 + f3;
    float s2 = f0 * f0 + f1 * f1 + f2 * f2 + f3 * f3;
    #pragma unroll
    for (int m = 32; m >= 1; m >>= 1) { s += __shfl_xor(s, m, 64); s2 += __shfl_xor(s2, m, 64); }
    float mu = s * 0.00390625f;
    float var = s2 * 0.00390625f - mu * mu;
    float inv = rsqrtf(var + 1e-5f);

    float b0, b1v, b2, b3;
    if (BASE_F32) {
        float4 braw = *reinterpret_cast<const float4*>(&((const float*)basev)[off]);
        b0 = braw.x; b1v = braw.y; b2 = braw.z; b3 = braw.w;
    } else {
        short4 braw = *reinterpret_cast<const short4*>(&((const unsigned short*)basev)[off]);
        b0 = bf2f((unsigned short)braw.x); b1v = bf2f((unsigned short)braw.y);
        b2 = bf2f((unsigned short)braw.z); b3 = bf2f((unsigned short)braw.w);
    }
    float4 graw = *reinterpret_cast<const float4*>(&gg[lane * 4]);
    float4 brw2 = *reinterpret_cast<const float4*>(&bb[lane * 4]);
    float o0 = b0 + (f0 - mu) * inv * graw.x + brw2.x;
    float o1 = b1v + (f1 - mu) * inv * graw.y + brw2.y;
    float o2 = b2 + (f2 - mu) * inv * graw.z + brw2.z;
    float o3 = b3 + (f3 - mu) * inv * graw.w + brw2.w;
    if (OUT_F32) {
        float4 o; o.x = o0; o.y = o1; o.z = o2; o.w = o3;
        *reinterpret_cast<float4*>(&((float*)outv)[off]) = o;
    } else {
        short4 o;
        o.x = (short)f2bf(o0); o.y = (short)f2bf(o1);
        o.z = (short)f2bf(o2); o.w = (short)f2bf(o3);
        *reinterpret_cast<short4*>(&((unsigned short*)outv)[off]) = o;
    }
}

extern "C" void kernel_launch(void* const* d_in, const int* in_sizes, int n_in,
                              void* d_out, int out_size, void* d_ws, size_t ws_size,
                              hipStream_t stream) {
    const float* x      = (const float*)d_in[0];
    const float* qkv_w  = (const float*)d_in[1];
    const float* q_bias = (const float*)d_in[2];
    const float* v_bias = (const float*)d_in[3];
    const float* lscale = (const float*)d_in[4];
    const float* cpb_w1 = (const float*)d_in[5];
    const float* cpb_b1 = (const float*)d_in[6];
    const float* cpb_w2 = (const float*)d_in[7];
    const float* proj_w = (const float*)d_in[8];
    const float* proj_b = (const float*)d_in[9];
    const float* n1g    = (const float*)d_in[10];
    const float* n1b    = (const float*)d_in[11];
    const float* fc1_w  = (const float*)d_in[12];
    const float* fc1_b  = (const float*)d_in[13];
    const float* fc2_w  = (const float*)d_in[14];
    const float* fc2_b  = (const float*)d_in[15];
    const float* n2g    = (const float*)d_in[16];
    const float* n2b    = (const float*)d_in[17];
    const float* rct    = (const float*)d_in[18];
    const int*   rpi    = (const int*)d_in[19];

    char* ws = (char*)d_ws;
    unsigned short* qkv    = (unsigned short*)(ws);
    unsigned short* hbuf   = (unsigned short*)(ws);
    unsigned short* attn_o = (unsigned short*)(ws + 154140672);
    unsigned short* xb     = (unsigned short*)(ws + 205520896);
    unsigned short* x1     = (unsigned short*)(ws + 205520896);
    unsigned short* projy  = (unsigned short*)(ws + 256901120);
    unsigned short* wqkv   = (unsigned short*)(ws + 308281344);
    unsigned short* wproj  = (unsigned short*)(ws + 308674560);
    unsigned short* wfc1   = (unsigned short*)(ws + 308805632);
    unsigned short* wfc2   = (unsigned short*)(ws + 309329920);
    float*          rpbf   = (float*)(ws + 309854208);
    float*          scales = (float*)(ws + 310378496);
    float*          qkvb   = (float*)(ws + 310378528);

    const int M = 100352;

    conv_kernel<<<2048, 256, 0, stream>>>(x, xb, 25690112 / 4);
    conv4_kernel<<<768, 256, 0, stream>>>(qkv_w, wqkv, 49152,
                                          proj_w, wproj, 16384,
                                          fc1_w, wfc1, 65536,
                                          fc2_w, wfc2, 65536);
    prep_kernel<<<1, 256, 0, stream>>>(lscale, cpb_w1, cpb_b1, cpb_w2, q_bias, v_bias,
                                       rct, rpi, scales, rpbf, qkvb);
    gemm_kernel<0, 0><<<4704, 256, 0, stream>>>(xb, wqkv, qkvb, qkv, M, 768, 256, 6);
    attn_kernel<<<16384, 64, 0, stream>>>(qkv, scales, rpbf, attn_o);
    gemm_kernel<0, 1><<<1568, 256, 0, stream>>>(attn_o, wproj, proj_b, projy, M, 256, 256, 2);
    ln_add_kernel<0, 0><<<25088, 256, 0, stream>>>(xb, projy, n1g, n1b, x1);
    gemm_kernel<1, 0><<<6272, 256, 0, stream>>>(x1, wfc1, fc1_b, hbuf, M, 1024, 256, 8);
    gemm_kernel<0, 0><<<1568, 256, 0, stream>>>(hbuf, wfc2, fc2_b, projy, M, 256, 1024, 2);
    ln_add_kernel<0, 1><<<25088, 256, 0, stream>>>(x1, projy, n2g, n2b, d_out);
}

// Round 12
// 487.215 us; speedup vs baseline: 2.7639x; 1.2346x over previous
//
#include <hip/hip_runtime.h>
#include <hip/hip_bf16.h>

typedef __attribute__((ext_vector_type(8))) short short8_t;
typedef __attribute__((ext_vector_type(4))) float f32x4;

__device__ __forceinline__ float bf2f(unsigned short u) {
    return __uint_as_float(((unsigned)u) << 16);
}
__device__ __forceinline__ unsigned short f2bf(float f) {
    __hip_bfloat16 h = __float2bfloat16(f);
    return *reinterpret_cast<unsigned short*>(&h);
}

// exact-GELU via Abramowitz-Stegun 7.1.26 erf (|err| <= 1.5e-7), branch-free.
__device__ __forceinline__ float fast_gelu(float v) {
    float ax = fabsf(v) * 0.70710678118f;
    float t  = __builtin_amdgcn_rcpf(1.f + 0.3275911f * ax);
    float poly = t * (0.254829592f + t * (-0.284496736f + t * (1.421413741f
               + t * (-1.453152027f + t * 1.061405429f))));
    float e  = __expf(-ax * ax);
    float er = 1.f - poly * e;                 // erf(ax), ax >= 0
    float s  = (v >= 0.f) ? er : -er;
    return 0.5f * v * (1.f + s);
}

// async global->LDS, 16B per lane; LDS dest = wave-uniform base + lane*16
__device__ __forceinline__ void async16(const unsigned short* g, unsigned short* l) {
    __builtin_amdgcn_global_load_lds(
        (const __attribute__((address_space(1))) unsigned int*)g,
        (__attribute__((address_space(3))) unsigned int*)l,
        16, 0, 0);
}

// window-order row r (r = wb*49 + n) -> natural token index
__device__ __forceinline__ int win_row_to_token(int r) {
    int wb = r / 49, n = r - wb * 49;
    int wq = wb & 7, hb = (wb >> 3) & 7, d = (wb >> 6) & 7, b = wb >> 9;
    int hh = n / 7, ww2 = n - hh * 7;
    return ((b * 8 + d) * 56 + hb * 7 + hh) * 56 + wq * 7 + ww2;
}

// ---------------- f32 -> bf16 bulk convert ----------------
__global__ __launch_bounds__(256) void conv_kernel(
    const float* __restrict__ src, unsigned short* __restrict__ dst, int n4)
{
    int stride = gridDim.x * 256;
    for (int i = blockIdx.x * 256 + threadIdx.x; i < n4; i += stride) {
        float4 v = *reinterpret_cast<const float4*>(&src[(size_t)i * 4]);
        short4 o;
        o.x = (short)f2bf(v.x); o.y = (short)f2bf(v.y);
        o.z = (short)f2bf(v.z); o.w = (short)f2bf(v.w);
        *reinterpret_cast<short4*>(&dst[(size_t)i * 4]) = o;
    }
}

// 4 weight tensors in one dispatch (vec4 counts)
__global__ __launch_bounds__(256) void conv4_kernel(
    const float* __restrict__ s0, unsigned short* __restrict__ d0, int n0,
    const float* __restrict__ s1, unsigned short* __restrict__ d1, int n1,
    const float* __restrict__ s2, unsigned short* __restrict__ d2, int n2,
    const float* __restrict__ s3, unsigned short* __restrict__ d3, int n3)
{
    int stride = gridDim.x * 256;
    int total = n0 + n1 + n2 + n3;
    for (int i = blockIdx.x * 256 + threadIdx.x; i < total; i += stride) {
        const float* s; unsigned short* d; int j = i;
        if (j < n0) { s = s0; d = d0; }
        else if ((j -= n0) < n1) { s = s1; d = d1; }
        else if ((j -= n1) < n2) { s = s2; d = d2; }
        else { j -= n2; s = s3; d = d3; }
        float4 v = *reinterpret_cast<const float4*>(&s[(size_t)j * 4]);
        short4 o;
        o.x = (short)f2bf(v.x); o.y = (short)f2bf(v.y);
        o.z = (short)f2bf(v.z); o.w = (short)f2bf(v.w);
        *reinterpret_cast<short4*>(&d[(size_t)j * 4]) = o;
    }
}

// ---------------- prep stage 1: CPB-MLP table, one block per table row ----------------
// tableg[i][h] = sum_j relu(coords_i . w1_j + b1_j) * w2[h][j]; j-parallel, coalesced.
__global__ __launch_bounds__(256) void prep_table_kernel(
    const float* __restrict__ w1, const float* __restrict__ b1,
    const float* __restrict__ w2, const float* __restrict__ tabin,
    float* __restrict__ tableg)
{
    const int i = blockIdx.x;          // 0..168
    const int t = threadIdx.x;
    const float c0 = tabin[i * 3], c1 = tabin[i * 3 + 1], c2 = tabin[i * 3 + 2];
    float part[8] = {0.f, 0.f, 0.f, 0.f, 0.f, 0.f, 0.f, 0.f};
    for (int j = t; j < 512; j += 256) {
        float hv = fmaxf(c0 * w1[j * 3] + c1 * w1[j * 3 + 1] + c2 * w1[j * 3 + 2] + b1[j], 0.f);
        #pragma unroll
        for (int h = 0; h < 8; ++h) part[h] += hv * w2[h * 512 + j];
    }
    #pragma unroll
    for (int h = 0; h < 8; ++h) {
        float v = part[h];
        v += __shfl_xor(v, 1);  v += __shfl_xor(v, 2);  v += __shfl_xor(v, 4);
        v += __shfl_xor(v, 8);  v += __shfl_xor(v, 16); v += __shfl_xor(v, 32);
        part[h] = v;
    }
    __shared__ float red[4][8];
    const int wv = t >> 6, lane = t & 63;
    if (lane == 0) {
        #pragma unroll
        for (int h = 0; h < 8; ++h) red[wv][h] = part[h];
    }
    __syncthreads();
    if (t < 8) tableg[i * 8 + t] = red[0][t] + red[1][t] + red[2][t] + red[3][t];
}

// ---------------- prep stage 2: scales, qkv bias, rpbf expansion ----------------
__global__ __launch_bounds__(256) void prep_expand_kernel(
    const float* __restrict__ logit_scale,
    const float* __restrict__ qb, const float* __restrict__ vb,
    const int* __restrict__ rpi, const float* __restrict__ tableg,
    float* __restrict__ scales, float* __restrict__ rpbf,
    float* __restrict__ qkvb)
{
    const int stride = gridDim.x * 256;
    const int gt = blockIdx.x * 256 + threadIdx.x;
    if (gt < 8) scales[gt] = expf(fminf(logit_scale[gt], 4.6051702f)); // ln(100)
    for (int i = gt; i < 768; i += stride) {
        float o;
        if (i < 256) o = qb[i];
        else if (i < 512) o = 0.f;
        else o = vb[i - 512];
        qkvb[i] = o;
    }
    // rpbf[h][mi][ji][r16][g4][r] = sigmoid-scaled bias at (i,j); pads zeroed
    for (int e = gt; e < 32768; e += stride) {
        int h = e >> 12, rem = e & 4095;
        int mi = rem >> 10, ji = (rem >> 8) & 3;
        int r16 = (rem >> 4) & 15, g4 = (rem >> 2) & 3, r = rem & 3;
        int i = mi * 16 + g4 * 4 + r, j = ji * 16 + r16;
        float val = 0.f;
        if (i < 49 && j < 49) {
            float xv = tableg[rpi[i * 49 + j] * 8 + h];
            val = 16.f / (1.f + expf(-xv));
        }
        rpbf[e] = val;
    }
}

// ---------------- GEMM: C[M,N] = A[M,K] * W[N,K]^T + bias (bf16 in/out) ----------------
// 128x128 tile, BK=32, 4 waves, double-buffered global_load_lds with COUNTED
// vmcnt waits; asm s_barrier with "memory" clobber + sched_barrier(0) (rule #18).
template<int ACT, int SCATTER>
__global__ __launch_bounds__(256) void gemm_kernel(
    const unsigned short* __restrict__ A, const unsigned short* __restrict__ W,
    const float* __restrict__ bias, unsigned short* __restrict__ C,
    int M, int N, int K, int ntn)
{
    __shared__ unsigned short smem[16384];
    const int tid = threadIdx.x;
    const int lane = tid & 63, wv = tid >> 6;
    const int wr = wv >> 1, wc = wv & 1;
    const int nwg = gridDim.x;
    const int virt = (blockIdx.x & 7) * (nwg >> 3) + (blockIdx.x >> 3);
    const int bn = virt % ntn, bm = virt / ntn;
    const size_t arow0 = (size_t)bm * 128;
    const size_t brow0 = (size_t)bn * 128;
    const int r16 = lane & 15, g4 = lane >> 4;
    const int srow_l = lane >> 2;                    // 0..15 row within issue
    const int sgran  = (lane & 3) ^ ((srow_l >> 1) & 3);
    f32x4 acc[4][4] = {};

    auto STAGE = [&](int buf, int kt) {             // 4 loads/thread
        unsigned short* As = smem + buf * 4096;
        unsigned short* Bs = smem + 8192 + buf * 4096;
        #pragma unroll
        for (int i = 0; i < 2; ++i) {
            int row0 = wv * 32 + i * 16;
            async16(&A[(arow0 + row0 + srow_l) * (size_t)K + kt + sgran * 8], &As[row0 * 32]);
            async16(&W[(brow0 + row0 + srow_l) * (size_t)K + kt + sgran * 8], &Bs[row0 * 32]);
        }
    };
    auto COMPUTE = [&](int buf) {
        unsigned short* As = smem + buf * 4096;
        unsigned short* Bs = smem + 8192 + buf * 4096;
        short8_t af[4], bfr[4];
        const int gsw = g4 ^ ((r16 >> 1) & 3);
        #pragma unroll
        for (int m = 0; m < 4; ++m) {
            int row = wr * 64 + m * 16 + r16;
            af[m] = *reinterpret_cast<const short8_t*>(&As[row * 32 + gsw * 8]);
        }
        #pragma unroll
        for (int n = 0; n < 4; ++n) {
            int row = wc * 64 + n * 16 + r16;
            bfr[n] = *reinterpret_cast<const short8_t*>(&Bs[row * 32 + gsw * 8]);
        }
        #pragma unroll
        for (int m = 0; m < 4; ++m)
            #pragma unroll
            for (int n = 0; n < 4; ++n)
                acc[m][n] = __builtin_amdgcn_mfma_f32_16x16x32_bf16(af[m], bfr[n], acc[m][n], 0, 0, 0);
    };

    const int nk = K >> 5;
    STAGE(0, 0);
    STAGE(1, 32);
    int cur = 0;
    for (int ks = 0; ks < nk - 1; ++ks) {
        asm volatile("s_waitcnt vmcnt(4)" ::: "memory");
        __builtin_amdgcn_sched_barrier(0);
        asm volatile("s_barrier" ::: "memory");      // buf cur fully populated
        COMPUTE(cur);
        __builtin_amdgcn_sched_barrier(0);
        asm volatile("s_barrier" ::: "memory");      // all reads of buf cur done
        if (ks + 2 < nk) STAGE(cur, (ks + 2) << 5);  // restage 2 ahead
        cur ^= 1;
    }
    asm volatile("s_waitcnt vmcnt(0)" ::: "memory"); // final tile: full drain
    __builtin_amdgcn_sched_barrier(0);
    asm volatile("s_barrier" ::: "memory");
    COMPUTE(cur);
    __builtin_amdgcn_sched_barrier(0);
    asm volatile("s_barrier" ::: "memory");          // LDS dead; epilogue overlays

    // ---- epilogue: 2 passes of per-wave 32x76 transpose -> coalesced stores ----
    unsigned short* Cs = smem + wv * 2432;   // 32 x 76 ushorts per wave
    const int rbase = g4 * 4;
    const int srow = lane >> 3, scol = (lane & 7) * 8;
    const int gcol0 = bn * 128 + wc * 64;
    #pragma unroll
    for (int p = 0; p < 2; ++p) {
        #pragma unroll
        for (int n = 0; n < 4; ++n) {
            float bv = bias[bn * 128 + wc * 64 + n * 16 + r16];
            #pragma unroll
            for (int m2 = 0; m2 < 2; ++m2) {
                int m = p * 2 + m2;
                #pragma unroll
                for (int r = 0; r < 4; ++r) {
                    float v = acc[m][n][r] + bv;
                    if (ACT == 1) v = fast_gelu(v);
                    Cs[(m2 * 16 + rbase + r) * 76 + n * 16 + r16] = f2bf(v);
                }
            }
        }
        #pragma unroll
        for (int rr = 0; rr < 4; ++rr) {
            int lr = rr * 8 + srow;                   // 0..31
            int grow = bm * 128 + wr * 64 + p * 32 + lr;
            size_t orow = SCATTER ? (size_t)win_row_to_token(grow) : (size_t)grow;
            short8_t vv = *reinterpret_cast<const short8_t*>(&Cs[lr * 76 + scol]);
            *reinterpret_cast<short8_t*>(&C[orow * (size_t)N + gcol0 + scol]) = vv;
        }
    }
}

// ---------------- attention: one WAVE per (window, head), MFMA ----------------
// LDS (ushort): Q[64 rows][40] at 0, K at 2560, V^T[32][72] at 5120;
// P[64][72] overlays Q+K after QK. Total 14848 B.
__global__ __launch_bounds__(64) void attn_kernel(
    const unsigned short* __restrict__ qkv, const float* __restrict__ scales,
    const float* __restrict__ rpbf, unsigned short* __restrict__ out)
{
    constexpr int QO = 0;
    constexpr int KO = 2560;
    constexpr int VO = 5120;
    constexpr int PO = 0;
    __shared__ unsigned short lds[7424];

    const int blk = blockIdx.x;
    const int h = blk & 7, wb = blk >> 3;
    const int lane = threadIdx.x;
    const int r16 = lane & 15, g4 = lane >> 4;

    const int wq = wb & 7, hb = (wb >> 3) & 7, dd = (wb >> 6) & 7, bb2 = wb >> 9;
    const int tok_base = ((bb2 * 8 + dd) * 56 + hb * 7) * 56 + wq * 7;
    const float sc = scales[h];

    {
        short8_t z = {};
        int d = lane >> 1, j0 = 48 + (lane & 1) * 8;
        *reinterpret_cast<short8_t*>(&lds[VO + d * 72 + j0]) = z;
    }
    #pragma unroll
    for (int sel = 0; sel < 2; ++sel) {
        for (int c = lane; c < 196; c += 64) {
            int row = c >> 2, gi = c & 3;
            int tok = tok_base + (row / 7) * 56 + (row % 7);
            const unsigned short* gp = qkv + (size_t)tok * 768 + sel * 256 + h * 32 + gi * 8;
            short8_t raw = *reinterpret_cast<const short8_t*>(gp);
            float f[8]; float ss = 0.f;
            #pragma unroll
            for (int e = 0; e < 8; ++e) { f[e] = bf2f((unsigned short)raw[e]); ss += f[e] * f[e]; }
            ss += __shfl_xor(ss, 1); ss += __shfl_xor(ss, 2);
            float inv = 1.f / fmaxf(sqrtf(ss), 1e-12f);
            if (sel == 0) inv *= sc;
            short8_t o;
            #pragma unroll
            for (int e = 0; e < 8; ++e) o[e] = (short)f2bf(f[e] * inv);
            *reinterpret_cast<short8_t*>(&lds[(sel ? KO : QO) + row * 40 + gi * 8]) = o;
        }
    }
    for (int c = lane; c < 196; c += 64) {
        int j = c >> 2, gi = c & 3;
        int tok = tok_base + (j / 7) * 56 + (j % 7);
        short8_t raw = *reinterpret_cast<const short8_t*>(
            qkv + (size_t)tok * 768 + 512 + h * 32 + gi * 8);
        #pragma unroll
        for (int e = 0; e < 8; ++e)
            lds[VO + (gi * 8 + e) * 72 + j] = (unsigned short)raw[e];
    }
    __syncthreads();

    short8_t qf[4], kf[4];
    #pragma unroll
    for (int mi = 0; mi < 4; ++mi)
        qf[mi] = *reinterpret_cast<const short8_t*>(&lds[QO + (mi * 16 + r16) * 40 + g4 * 8]);
    #pragma unroll
    for (int ji = 0; ji < 4; ++ji)
        kf[ji] = *reinterpret_cast<const short8_t*>(&lds[KO + (ji * 16 + r16) * 40 + g4 * 8]);
    f32x4 acc[4][4] = {};
    #pragma unroll
    for (int mi = 0; mi < 4; ++mi)
        #pragma unroll
        for (int ji = 0; ji < 4; ++ji)
            acc[mi][ji] = __builtin_amdgcn_mfma_f32_16x16x32_bf16(qf[mi], kf[ji], acc[mi][ji], 0, 0, 0);
    __syncthreads();   // Q/K dead; P overlays them

    const float* rbf = rpbf + h * 4096 + r16 * 16 + g4 * 4;
    f32x4 rbv[4][4];
    #pragma unroll
    for (int mi = 0; mi < 4; ++mi)
        #pragma unroll
        for (int ji = 0; ji < 4; ++ji)
            rbv[mi][ji] = *reinterpret_cast<const f32x4*>(&rbf[(mi * 4 + ji) * 256]);

    #pragma unroll
    for (int mi = 0; mi < 4; ++mi) {
        #pragma unroll
        for (int r = 0; r < 4; ++r) {
            int i = mi * 16 + g4 * 4 + r;
            float s[4]; float m = -1e30f;
            #pragma unroll
            for (int ji = 0; ji < 4; ++ji) {
                int j = ji * 16 + r16;
                float v = acc[mi][ji][r] + rbv[mi][ji][r];
                s[ji] = (j < 49) ? v : -1e30f;
                m = fmaxf(m, s[ji]);
            }
            m = fmaxf(m, __shfl_xor(m, 1)); m = fmaxf(m, __shfl_xor(m, 2));
            m = fmaxf(m, __shfl_xor(m, 4)); m = fmaxf(m, __shfl_xor(m, 8));
            float p[4]; float sum = 0.f;
            #pragma unroll
            for (int ji = 0; ji < 4; ++ji) {
                p[ji] = (s[ji] > -1e29f) ? __expf(s[ji] - m) : 0.f;
                sum += p[ji];
            }
            sum += __shfl_xor(sum, 1); sum += __shfl_xor(sum, 2);
            sum += __shfl_xor(sum, 4); sum += __shfl_xor(sum, 8);
            float rinv = 1.f / sum;
            #pragma unroll
            for (int ji = 0; ji < 4; ++ji) {
                int j = ji * 16 + r16;
                lds[PO + i * 72 + j] = f2bf(p[ji] * rinv);
            }
        }
    }
    __syncthreads();

    f32x4 acc2[4][2] = {};
    #pragma unroll
    for (int ks = 0; ks < 2; ++ks) {
        short8_t pf[4], vf[2];
        int ko = ks * 32 + g4 * 8;
        #pragma unroll
        for (int mi = 0; mi < 4; ++mi)
            pf[mi] = *reinterpret_cast<const short8_t*>(&lds[PO + (mi * 16 + r16) * 72 + ko]);
        #pragma unroll
        for (int ni = 0; ni < 2; ++ni)
            vf[ni] = *reinterpret_cast<const short8_t*>(&lds[VO + (ni * 16 + r16) * 72 + ko]);
        #pragma unroll
        for (int mi = 0; mi < 4; ++mi)
            #pragma unroll
            for (int ni = 0; ni < 2; ++ni)
                acc2[mi][ni] = __builtin_amdgcn_mfma_f32_16x16x32_bf16(pf[mi], vf[ni], acc2[mi][ni], 0, 0, 0);
    }

    #pragma unroll
    for (int mi = 0; mi < 4; ++mi)
        #pragma unroll
        for (int r = 0; r < 4; ++r) {
            int i = mi * 16 + g4 * 4 + r;
            if (i < 49) {
                size_t ob = (size_t)(wb * 49 + i) * 256 + h * 32;
                out[ob + r16]      = f2bf(acc2[mi][0][r]);
                out[ob + 16 + r16] = f2bf(acc2[mi][1][r]);
            }
        }
}

// ---------------- fused residual + LayerNorm (one wave per token) ----------------
template<int BASE_F32, int OUT_F32>
__global__ __launch_bounds__(256) void ln_add_kernel(
    const void* __restrict__ basev, const unsigned short* __restrict__ vin,
    const float* __restrict__ gg, const float* __restrict__ bb,
    void* __restrict__ outv)
{
    int token = blockIdx.x * 4 + (threadIdx.x >> 6);
    int lane = threadIdx.x & 63;
    size_t off = (size_t)token * 256 + lane * 4;
    short4 raw = *reinterpret_cast<const short4*>(&vin[off]);
    float f0 = bf2f((unsigned short)raw.x), f1 = bf2f((unsigned short)raw.y);
    float f2 = bf2f((unsigned short)raw.z), f3 = bf2f((unsigned short)raw.w);
    float s  = f0 + f1 + f2 + f3;
    float s2 = f0 * f0 + f1 * f1 + f2 * f2 + f3 * f3;
    #pragma unroll
    for (int m = 32; m >= 1; m >>= 1) { s += __shfl_xor(s, m, 64); s2 += __shfl_xor(s2, m, 64); }
    float mu = s * 0.00390625f;
    float var = s2 * 0.00390625f - mu * mu;
    float inv = rsqrtf(var + 1e-5f);

    float b0, b1v, b2, b3;
    if (BASE_F32) {
        float4 braw = *reinterpret_cast<const float4*>(&((const float*)basev)[off]);
        b0 = braw.x; b1v = braw.y; b2 = braw.z; b3 = braw.w;
    } else {
        short4 braw = *reinterpret_cast<const short4*>(&((const unsigned short*)basev)[off]);
        b0 = bf2f((unsigned short)braw.x); b1v = bf2f((unsigned short)braw.y);
        b2 = bf2f((unsigned short)braw.z); b3 = bf2f((unsigned short)braw.w);
    }
    float4 graw = *reinterpret_cast<const float4*>(&gg[lane * 4]);
    float4 brw2 = *reinterpret_cast<const float4*>(&bb[lane * 4]);
    float o0 = b0 + (f0 - mu) * inv * graw.x + brw2.x;
    float o1 = b1v + (f1 - mu) * inv * graw.y + brw2.y;
    float o2 = b2 + (f2 - mu) * inv * graw.z + brw2.z;
    float o3 = b3 + (f3 - mu) * inv * graw.w + brw2.w;
    if (OUT_F32) {
        float4 o; o.x = o0; o.y = o1; o.z = o2; o.w = o3;
        *reinterpret_cast<float4*>(&((float*)outv)[off]) = o;
    } else {
        short4 o;
        o.x = (short)f2bf(o0); o.y = (short)f2bf(o1);
        o.z = (short)f2bf(o2); o.w = (short)f2bf(o3);
        *reinterpret_cast<short4*>(&((unsigned short*)outv)[off]) = o;
    }
}

extern "C" void kernel_launch(void* const* d_in, const int* in_sizes, int n_in,
                              void* d_out, int out_size, void* d_ws, size_t ws_size,
                              hipStream_t stream) {
    const float* x      = (const float*)d_in[0];
    const float* qkv_w  = (const float*)d_in[1];
    const float* q_bias = (const float*)d_in[2];
    const float* v_bias = (const float*)d_in[3];
    const float* lscale = (const float*)d_in[4];
    const float* cpb_w1 = (const float*)d_in[5];
    const float* cpb_b1 = (const float*)d_in[6];
    const float* cpb_w2 = (const float*)d_in[7];
    const float* proj_w = (const float*)d_in[8];
    const float* proj_b = (const float*)d_in[9];
    const float* n1g    = (const float*)d_in[10];
    const float* n1b    = (const float*)d_in[11];
    const float* fc1_w  = (const float*)d_in[12];
    const float* fc1_b  = (const float*)d_in[13];
    const float* fc2_w  = (const float*)d_in[14];
    const float* fc2_b  = (const float*)d_in[15];
    const float* n2g    = (const float*)d_in[16];
    const float* n2b    = (const float*)d_in[17];
    const float* rct    = (const float*)d_in[18];
    const int*   rpi    = (const int*)d_in[19];

    char* ws = (char*)d_ws;
    unsigned short* qkv    = (unsigned short*)(ws);
    unsigned short* hbuf   = (unsigned short*)(ws);
    unsigned short* attn_o = (unsigned short*)(ws + 154140672);
    unsigned short* xb     = (unsigned short*)(ws + 205520896);
    unsigned short* x1     = (unsigned short*)(ws + 205520896);
    unsigned short* projy  = (unsigned short*)(ws + 256901120);
    unsigned short* wqkv   = (unsigned short*)(ws + 308281344);
    unsigned short* wproj  = (unsigned short*)(ws + 308674560);
    unsigned short* wfc1   = (unsigned short*)(ws + 308805632);
    unsigned short* wfc2   = (unsigned short*)(ws + 309329920);
    float*          rpbf   = (float*)(ws + 309854208);   // 131072 B
    float*          scales = (float*)(ws + 310378496);   // 32 B
    float*          qkvb   = (float*)(ws + 310378528);   // 3072 B
    float*          tableg = (float*)(ws + 310381600);   // 5408 B

    const int M = 100352;

    conv_kernel<<<2048, 256, 0, stream>>>(x, xb, 25690112 / 4);
    conv4_kernel<<<768, 256, 0, stream>>>(qkv_w, wqkv, 49152,
                                          proj_w, wproj, 16384,
                                          fc1_w, wfc1, 65536,
                                          fc2_w, wfc2, 65536);
    prep_table_kernel<<<169, 256, 0, stream>>>(cpb_w1, cpb_b1, cpb_w2, rct, tableg);
    prep_expand_kernel<<<128, 256, 0, stream>>>(lscale, q_bias, v_bias, rpi, tableg,
                                                scales, rpbf, qkvb);
    gemm_kernel<0, 0><<<4704, 256, 0, stream>>>(xb, wqkv, qkvb, qkv, M, 768, 256, 6);
    attn_kernel<<<16384, 64, 0, stream>>>(qkv, scales, rpbf, attn_o);
    gemm_kernel<0, 1><<<1568, 256, 0, stream>>>(attn_o, wproj, proj_b, projy, M, 256, 256, 2);
    ln_add_kernel<0, 0><<<25088, 256, 0, stream>>>(xb, projy, n1g, n1b, x1);
    gemm_kernel<1, 0><<<6272, 256, 0, stream>>>(x1, wfc1, fc1_b, hbuf, M, 1024, 256, 8);
    gemm_kernel<0, 0><<<1568, 256, 0, stream>>>(hbuf, wfc2, fc2_b, projy, M, 256, 1024, 2);
    ln_add_kernel<0, 1><<<25088, 256, 0, stream>>>(x1, projy, n2g, n2b, d_out);
}

// Round 13
// 465.883 us; speedup vs baseline: 2.8904x; 1.0458x over previous
//
#include <hip/hip_runtime.h>
#include <hip/hip_bf16.h>

typedef __attribute__((ext_vector_type(8))) short short8_t;
typedef __attribute__((ext_vector_type(4))) float f32x4;

__device__ __forceinline__ float bf2f(unsigned short u) {
    return __uint_as_float(((unsigned)u) << 16);
}
__device__ __forceinline__ unsigned short f2bf(float f) {
    __hip_bfloat16 h = __float2bfloat16(f);
    return *reinterpret_cast<unsigned short*>(&h);
}

// exact-GELU via Abramowitz-Stegun 7.1.26 erf (|err| <= 1.5e-7), branch-free.
__device__ __forceinline__ float fast_gelu(float v) {
    float ax = fabsf(v) * 0.70710678118f;
    float t  = __builtin_amdgcn_rcpf(1.f + 0.3275911f * ax);
    float poly = t * (0.254829592f + t * (-0.284496736f + t * (1.421413741f
               + t * (-1.453152027f + t * 1.061405429f))));
    float e  = __expf(-ax * ax);
    float er = 1.f - poly * e;                 // erf(ax), ax >= 0
    float s  = (v >= 0.f) ? er : -er;
    return 0.5f * v * (1.f + s);
}

// async global->LDS, 16B per lane; LDS dest = wave-uniform base + lane*16
__device__ __forceinline__ void async16(const unsigned short* g, unsigned short* l) {
    __builtin_amdgcn_global_load_lds(
        (const __attribute__((address_space(1))) unsigned int*)g,
        (__attribute__((address_space(3))) unsigned int*)l,
        16, 0, 0);
}

// window-order row r (r = wb*49 + n) -> natural token index
__device__ __forceinline__ int win_row_to_token(int r) {
    int wb = r / 49, n = r - wb * 49;
    int wq = wb & 7, hb = (wb >> 3) & 7, d = (wb >> 6) & 7, b = wb >> 9;
    int hh = n / 7, ww2 = n - hh * 7;
    return ((b * 8 + d) * 56 + hb * 7 + hh) * 56 + wq * 7 + ww2;
}

// ---------------- f32 -> bf16 bulk convert ----------------
__global__ __launch_bounds__(256) void conv_kernel(
    const float* __restrict__ src, unsigned short* __restrict__ dst, int n4)
{
    int stride = gridDim.x * 256;
    for (int i = blockIdx.x * 256 + threadIdx.x; i < n4; i += stride) {
        float4 v = *reinterpret_cast<const float4*>(&src[(size_t)i * 4]);
        short4 o;
        o.x = (short)f2bf(v.x); o.y = (short)f2bf(v.y);
        o.z = (short)f2bf(v.z); o.w = (short)f2bf(v.w);
        *reinterpret_cast<short4*>(&dst[(size_t)i * 4]) = o;
    }
}

// 4 weight tensors in one dispatch (vec4 counts)
__global__ __launch_bounds__(256) void conv4_kernel(
    const float* __restrict__ s0, unsigned short* __restrict__ d0, int n0,
    const float* __restrict__ s1, unsigned short* __restrict__ d1, int n1,
    const float* __restrict__ s2, unsigned short* __restrict__ d2, int n2,
    const float* __restrict__ s3, unsigned short* __restrict__ d3, int n3)
{
    int stride = gridDim.x * 256;
    int total = n0 + n1 + n2 + n3;
    for (int i = blockIdx.x * 256 + threadIdx.x; i < total; i += stride) {
        const float* s; unsigned short* d; int j = i;
        if (j < n0) { s = s0; d = d0; }
        else if ((j -= n0) < n1) { s = s1; d = d1; }
        else if ((j -= n1) < n2) { s = s2; d = d2; }
        else { j -= n2; s = s3; d = d3; }
        float4 v = *reinterpret_cast<const float4*>(&s[(size_t)j * 4]);
        short4 o;
        o.x = (short)f2bf(v.x); o.y = (short)f2bf(v.y);
        o.z = (short)f2bf(v.z); o.w = (short)f2bf(v.w);
        *reinterpret_cast<short4*>(&d[(size_t)j * 4]) = o;
    }
}

// ---------------- prep stage 1: CPB-MLP table, one block per table row ----------------
__global__ __launch_bounds__(256) void prep_table_kernel(
    const float* __restrict__ w1, const float* __restrict__ b1,
    const float* __restrict__ w2, const float* __restrict__ tabin,
    float* __restrict__ tableg)
{
    const int i = blockIdx.x;          // 0..168
    const int t = threadIdx.x;
    const float c0 = tabin[i * 3], c1 = tabin[i * 3 + 1], c2 = tabin[i * 3 + 2];
    float part[8] = {0.f, 0.f, 0.f, 0.f, 0.f, 0.f, 0.f, 0.f};
    for (int j = t; j < 512; j += 256) {
        float hv = fmaxf(c0 * w1[j * 3] + c1 * w1[j * 3 + 1] + c2 * w1[j * 3 + 2] + b1[j], 0.f);
        #pragma unroll
        for (int h = 0; h < 8; ++h) part[h] += hv * w2[h * 512 + j];
    }
    #pragma unroll
    for (int h = 0; h < 8; ++h) {
        float v = part[h];
        v += __shfl_xor(v, 1);  v += __shfl_xor(v, 2);  v += __shfl_xor(v, 4);
        v += __shfl_xor(v, 8);  v += __shfl_xor(v, 16); v += __shfl_xor(v, 32);
        part[h] = v;
    }
    __shared__ float red[4][8];
    const int wv = t >> 6, lane = t & 63;
    if (lane == 0) {
        #pragma unroll
        for (int h = 0; h < 8; ++h) red[wv][h] = part[h];
    }
    __syncthreads();
    if (t < 8) tableg[i * 8 + t] = red[0][t] + red[1][t] + red[2][t] + red[3][t];
}

// ---------------- prep stage 2: scales, qkv bias, rpbf expansion ----------------
__global__ __launch_bounds__(256) void prep_expand_kernel(
    const float* __restrict__ logit_scale,
    const float* __restrict__ qb, const float* __restrict__ vb,
    const int* __restrict__ rpi, const float* __restrict__ tableg,
    float* __restrict__ scales, float* __restrict__ rpbf,
    float* __restrict__ qkvb)
{
    const int stride = gridDim.x * 256;
    const int gt = blockIdx.x * 256 + threadIdx.x;
    if (gt < 8) scales[gt] = expf(fminf(logit_scale[gt], 4.6051702f)); // ln(100)
    for (int i = gt; i < 768; i += stride) {
        float o;
        if (i < 256) o = qb[i];
        else if (i < 512) o = 0.f;
        else o = vb[i - 512];
        qkvb[i] = o;
    }
    for (int e = gt; e < 32768; e += stride) {
        int h = e >> 12, rem = e & 4095;
        int mi = rem >> 10, ji = (rem >> 8) & 3;
        int r16 = (rem >> 4) & 15, g4 = (rem >> 2) & 3, r = rem & 3;
        int i = mi * 16 + g4 * 4 + r, j = ji * 16 + r16;
        float val = 0.f;
        if (i < 49 && j < 49) {
            float xv = tableg[rpi[i * 49 + j] * 8 + h];
            val = 16.f / (1.f + expf(-xv));
        }
        rpbf[e] = val;
    }
}

// ---------------- GEMM: C[M,N] = A[M,K] * W[N,K]^T + bias (bf16 in/out) ----------------
// 128x128 tile, BK=32, 4 waves, counted-vmcnt double buffer (r11 structure).
template<int ACT, int SCATTER>
__global__ __launch_bounds__(256) void gemm_kernel(
    const unsigned short* __restrict__ A, const unsigned short* __restrict__ W,
    const float* __restrict__ bias, unsigned short* __restrict__ C,
    int M, int N, int K, int ntn)
{
    __shared__ unsigned short smem[16384];
    const int tid = threadIdx.x;
    const int lane = tid & 63, wv = tid >> 6;
    const int wr = wv >> 1, wc = wv & 1;
    const int nwg = gridDim.x;
    const int virt = (blockIdx.x & 7) * (nwg >> 3) + (blockIdx.x >> 3);
    const int bn = virt % ntn, bm = virt / ntn;
    const size_t arow0 = (size_t)bm * 128;
    const size_t brow0 = (size_t)bn * 128;
    const int r16 = lane & 15, g4 = lane >> 4;
    const int srow_l = lane >> 2;
    const int sgran  = (lane & 3) ^ ((srow_l >> 1) & 3);
    f32x4 acc[4][4] = {};

    auto STAGE = [&](int buf, int kt) {
        unsigned short* As = smem + buf * 4096;
        unsigned short* Bs = smem + 8192 + buf * 4096;
        #pragma unroll
        for (int i = 0; i < 2; ++i) {
            int row0 = wv * 32 + i * 16;
            async16(&A[(arow0 + row0 + srow_l) * (size_t)K + kt + sgran * 8], &As[row0 * 32]);
            async16(&W[(brow0 + row0 + srow_l) * (size_t)K + kt + sgran * 8], &Bs[row0 * 32]);
        }
    };
    auto COMPUTE = [&](int buf) {
        unsigned short* As = smem + buf * 4096;
        unsigned short* Bs = smem + 8192 + buf * 4096;
        short8_t af[4], bfr[4];
        const int gsw = g4 ^ ((r16 >> 1) & 3);
        #pragma unroll
        for (int m = 0; m < 4; ++m) {
            int row = wr * 64 + m * 16 + r16;
            af[m] = *reinterpret_cast<const short8_t*>(&As[row * 32 + gsw * 8]);
        }
        #pragma unroll
        for (int n = 0; n < 4; ++n) {
            int row = wc * 64 + n * 16 + r16;
            bfr[n] = *reinterpret_cast<const short8_t*>(&Bs[row * 32 + gsw * 8]);
        }
        #pragma unroll
        for (int m = 0; m < 4; ++m)
            #pragma unroll
            for (int n = 0; n < 4; ++n)
                acc[m][n] = __builtin_amdgcn_mfma_f32_16x16x32_bf16(af[m], bfr[n], acc[m][n], 0, 0, 0);
    };

    const int nk = K >> 5;
    STAGE(0, 0);
    STAGE(1, 32);
    int cur = 0;
    for (int ks = 0; ks < nk - 1; ++ks) {
        asm volatile("s_waitcnt vmcnt(4)" ::: "memory");
        __builtin_amdgcn_sched_barrier(0);
        asm volatile("s_barrier" ::: "memory");
        COMPUTE(cur);
        __builtin_amdgcn_sched_barrier(0);
        asm volatile("s_barrier" ::: "memory");
        if (ks + 2 < nk) STAGE(cur, (ks + 2) << 5);
        cur ^= 1;
    }
    asm volatile("s_waitcnt vmcnt(0)" ::: "memory");
    __builtin_amdgcn_sched_barrier(0);
    asm volatile("s_barrier" ::: "memory");
    COMPUTE(cur);
    __builtin_amdgcn_sched_barrier(0);
    asm volatile("s_barrier" ::: "memory");

    // ---- epilogue: 2 passes of per-wave 32x76 transpose -> coalesced stores ----
    unsigned short* Cs = smem + wv * 2432;
    const int rbase = g4 * 4;
    const int srow = lane >> 3, scol = (lane & 7) * 8;
    const int gcol0 = bn * 128 + wc * 64;
    #pragma unroll
    for (int p = 0; p < 2; ++p) {
        #pragma unroll
        for (int n = 0; n < 4; ++n) {
            float bv = bias[bn * 128 + wc * 64 + n * 16 + r16];
            #pragma unroll
            for (int m2 = 0; m2 < 2; ++m2) {
                int m = p * 2 + m2;
                #pragma unroll
                for (int r = 0; r < 4; ++r) {
                    float v = acc[m][n][r] + bv;
                    if (ACT == 1) v = fast_gelu(v);
                    Cs[(m2 * 16 + rbase + r) * 76 + n * 16 + r16] = f2bf(v);
                }
            }
        }
        #pragma unroll
        for (int rr = 0; rr < 4; ++rr) {
            int lr = rr * 8 + srow;
            int grow = bm * 128 + wr * 64 + p * 32 + lr;
            size_t orow = SCATTER ? (size_t)win_row_to_token(grow) : (size_t)grow;
            short8_t vv = *reinterpret_cast<const short8_t*>(&Cs[lr * 76 + scol]);
            *reinterpret_cast<short8_t*>(&C[orow * (size_t)N + gcol0 + scol]) = vv;
        }
    }
}

// ---------------- fused GEMM + residual + LayerNorm (N=256 fixed) ----------------
// 128x256 tile, 512 threads (8 waves of 64x64), counted-vmcnt double buffer.
// out = resid + LN(A@W^T + bias) with per-row stats computed in f32.
// SCATTER: row -> win_row_to_token. OUT_F32: f32 output (else bf16).
template<int SCATTER, int OUT_F32>
__global__ __launch_bounds__(512) void gemm_ln_kernel(
    const unsigned short* __restrict__ A, const unsigned short* __restrict__ W,
    const float* __restrict__ bias, const unsigned short* __restrict__ resid,
    const float* __restrict__ gamma, const float* __restrict__ beta,
    void* __restrict__ Cv, int M, int K)
{
    __shared__ unsigned short smem[24576];  // 48KB: As[2] 16KB, Bs[2] 32KB
    const int tid = threadIdx.x;
    const int lane = tid & 63, wv = tid >> 6;      // 8 waves
    const int wr = wv >> 2, wc = wv & 3;           // 2 x 4 wave grid
    const int nwg = gridDim.x;                     // 784 (divisible by 8)
    const int bm = (blockIdx.x & 7) * (nwg >> 3) + (blockIdx.x >> 3);
    const size_t arow0 = (size_t)bm * 128;
    const int r16 = lane & 15, g4 = lane >> 4;
    const int srow_l = lane >> 2;
    const int sgran = (lane & 3) ^ ((srow_l >> 1) & 3);
    f32x4 acc[4][4] = {};

    auto STAGE = [&](int buf, int kt) {            // 3 loads per thread
        unsigned short* As = smem + buf * 4096;            // 128x32
        unsigned short* Bs = smem + 8192 + buf * 8192;     // 256x32
        async16(&A[(arow0 + wv * 16 + srow_l) * (size_t)K + kt + sgran * 8],
                &As[(wv * 16) * 32]);
        #pragma unroll
        for (int i = 0; i < 2; ++i) {
            int row0 = wv * 32 + i * 16;
            async16(&W[(size_t)(row0 + srow_l) * K + kt + sgran * 8], &Bs[row0 * 32]);
        }
    };
    auto COMPUTE = [&](int buf) {
        unsigned short* As = smem + buf * 4096;
        unsigned short* Bs = smem + 8192 + buf * 8192;
        short8_t af[4], bfr[4];
        const int gsw = g4 ^ ((r16 >> 1) & 3);
        #pragma unroll
        for (int m = 0; m < 4; ++m) {
            int row = wr * 64 + m * 16 + r16;
            af[m] = *reinterpret_cast<const short8_t*>(&As[row * 32 + gsw * 8]);
        }
        #pragma unroll
        for (int n = 0; n < 4; ++n) {
            int row = wc * 64 + n * 16 + r16;
            bfr[n] = *reinterpret_cast<const short8_t*>(&Bs[row * 32 + gsw * 8]);
        }
        #pragma unroll
        for (int m = 0; m < 4; ++m)
            #pragma unroll
            for (int n = 0; n < 4; ++n)
                acc[m][n] = __builtin_amdgcn_mfma_f32_16x16x32_bf16(af[m], bfr[n], acc[m][n], 0, 0, 0);
    };

    const int nk = K >> 5;
    STAGE(0, 0);
    STAGE(1, 32);
    int cur = 0;
    for (int ks = 0; ks < nk - 1; ++ks) {
        asm volatile("s_waitcnt vmcnt(3)" ::: "memory");   // oldest stage's 3 loads
        __builtin_amdgcn_sched_barrier(0);
        asm volatile("s_barrier" ::: "memory");
        COMPUTE(cur);
        __builtin_amdgcn_sched_barrier(0);
        asm volatile("s_barrier" ::: "memory");
        if (ks + 2 < nk) STAGE(cur, (ks + 2) << 5);
        cur ^= 1;
    }
    asm volatile("s_waitcnt vmcnt(0)" ::: "memory");
    __builtin_amdgcn_sched_barrier(0);
    asm volatile("s_barrier" ::: "memory");
    COMPUTE(cur);
    __builtin_amdgcn_sched_barrier(0);
    asm volatile("s_barrier" ::: "memory");            // pipeline LDS dead

    // ---- row stats: bias-included partial sums per wave -> LDS reduce ----
    float bv[4];
    #pragma unroll
    for (int n = 0; n < 4; ++n) bv[n] = bias[wc * 64 + n * 16 + r16];
    float* psum  = reinterpret_cast<float*>(smem + 19456);   // byte 38912: [128][4]
    float* psq   = psum + 512;                               // [128][4]
    float* stats = psq + 512;                                // [128][2] (mu, inv)
    #pragma unroll
    for (int m = 0; m < 4; ++m) {
        #pragma unroll
        for (int r = 0; r < 4; ++r) {
            float s = 0.f, s2 = 0.f;
            #pragma unroll
            for (int n = 0; n < 4; ++n) {
                float v = acc[m][n][r] + bv[n];
                s += v; s2 += v * v;
            }
            s  += __shfl_xor(s, 1);  s  += __shfl_xor(s, 2);
            s  += __shfl_xor(s, 4);  s  += __shfl_xor(s, 8);
            s2 += __shfl_xor(s2, 1); s2 += __shfl_xor(s2, 2);
            s2 += __shfl_xor(s2, 4); s2 += __shfl_xor(s2, 8);
            if (r16 == 0) {
                int row = wr * 64 + m * 16 + g4 * 4 + r;
                psum[row * 4 + wc] = s;
                psq[row * 4 + wc]  = s2;
            }
        }
    }
    __syncthreads();
    if (tid < 128) {
        f32x4 a = *reinterpret_cast<const f32x4*>(&psum[tid * 4]);
        f32x4 b = *reinterpret_cast<const f32x4*>(&psq[tid * 4]);
        float mu  = (a[0] + a[1] + a[2] + a[3]) * 0.00390625f;
        float ex2 = (b[0] + b[1] + b[2] + b[3]) * 0.00390625f;
        stats[tid * 2]     = mu;
        stats[tid * 2 + 1] = rsqrtf(ex2 - mu * mu + 1e-5f);
    }
    __syncthreads();

    // ---- transpose + LN-apply stores (Cs per-wave; no cross-wave LDS) ----
    unsigned short* Cs = smem + wv * 2432;   // 32 x 76 ushorts per wave
    const int rbase = g4 * 4;
    const int srow = lane >> 3, scol = (lane & 7) * 8;
    const int gcol0 = wc * 64;
    f32x4 gm0 = *reinterpret_cast<const f32x4*>(&gamma[gcol0 + scol]);
    f32x4 gm1 = *reinterpret_cast<const f32x4*>(&gamma[gcol0 + scol + 4]);
    f32x4 bt0 = *reinterpret_cast<const f32x4*>(&beta[gcol0 + scol]);
    f32x4 bt1 = *reinterpret_cast<const f32x4*>(&beta[gcol0 + scol + 4]);
    #pragma unroll
    for (int p = 0; p < 2; ++p) {
        #pragma unroll
        for (int n = 0; n < 4; ++n)
            #pragma unroll
            for (int m2 = 0; m2 < 2; ++m2)
                #pragma unroll
                for (int r = 0; r < 4; ++r)
                    Cs[(m2 * 16 + rbase + r) * 76 + n * 16 + r16] =
                        f2bf(acc[p * 2 + m2][n][r] + bv[n]);
        #pragma unroll
        for (int rr = 0; rr < 4; ++rr) {
            int lr = rr * 8 + srow;                    // 0..31
            int lrow = wr * 64 + p * 32 + lr;          // 0..127
            int grow = bm * 128 + lrow;
            size_t orow = SCATTER ? (size_t)win_row_to_token(grow) : (size_t)grow;
            float mu  = stats[lrow * 2];
            float inv = stats[lrow * 2 + 1];
            short8_t cv = *reinterpret_cast<const short8_t*>(&Cs[lr * 76 + scol]);
            short8_t rv = *reinterpret_cast<const short8_t*>(&resid[orow * 256 + gcol0 + scol]);
            float o[8];
            #pragma unroll
            for (int e = 0; e < 8; ++e) {
                float g = (e < 4) ? gm0[e] : gm1[e - 4];
                float bb = (e < 4) ? bt0[e] : bt1[e - 4];
                o[e] = bf2f((unsigned short)rv[e])
                     + (bf2f((unsigned short)cv[e]) - mu) * inv * g + bb;
            }
            if (OUT_F32) {
                float* outp = (float*)Cv + orow * 256 + gcol0 + scol;
                f32x4 o0, o1;
                #pragma unroll
                for (int e = 0; e < 4; ++e) { o0[e] = o[e]; o1[e] = o[e + 4]; }
                *reinterpret_cast<f32x4*>(outp)     = o0;
                *reinterpret_cast<f32x4*>(outp + 4) = o1;
            } else {
                unsigned short* outp = (unsigned short*)Cv + orow * 256 + gcol0 + scol;
                short8_t ov;
                #pragma unroll
                for (int e = 0; e < 8; ++e) ov[e] = (short)f2bf(o[e]);
                *reinterpret_cast<short8_t*>(outp) = ov;
            }
        }
    }
}

// ---------------- attention: one WAVE per (window, head), MFMA ----------------
__global__ __launch_bounds__(64) void attn_kernel(
    const unsigned short* __restrict__ qkv, const float* __restrict__ scales,
    const float* __restrict__ rpbf, unsigned short* __restrict__ out)
{
    constexpr int QO = 0;
    constexpr int KO = 2560;
    constexpr int VO = 5120;
    constexpr int PO = 0;
    __shared__ unsigned short lds[7424];

    const int blk = blockIdx.x;
    const int h = blk & 7, wb = blk >> 3;
    const int lane = threadIdx.x;
    const int r16 = lane & 15, g4 = lane >> 4;

    const int wq = wb & 7, hb = (wb >> 3) & 7, dd = (wb >> 6) & 7, bb2 = wb >> 9;
    const int tok_base = ((bb2 * 8 + dd) * 56 + hb * 7) * 56 + wq * 7;
    const float sc = scales[h];

    {
        short8_t z = {};
        int d = lane >> 1, j0 = 48 + (lane & 1) * 8;
        *reinterpret_cast<short8_t*>(&lds[VO + d * 72 + j0]) = z;
    }
    #pragma unroll
    for (int sel = 0; sel < 2; ++sel) {
        for (int c = lane; c < 196; c += 64) {
            int row = c >> 2, gi = c & 3;
            int tok = tok_base + (row / 7) * 56 + (row % 7);
            const unsigned short* gp = qkv + (size_t)tok * 768 + sel * 256 + h * 32 + gi * 8;
            short8_t raw = *reinterpret_cast<const short8_t*>(gp);
            float f[8]; float ss = 0.f;
            #pragma unroll
            for (int e = 0; e < 8; ++e) { f[e] = bf2f((unsigned short)raw[e]); ss += f[e] * f[e]; }
            ss += __shfl_xor(ss, 1); ss += __shfl_xor(ss, 2);
            float inv = 1.f / fmaxf(sqrtf(ss), 1e-12f);
            if (sel == 0) inv *= sc;
            short8_t o;
            #pragma unroll
            for (int e = 0; e < 8; ++e) o[e] = (short)f2bf(f[e] * inv);
            *reinterpret_cast<short8_t*>(&lds[(sel ? KO : QO) + row * 40 + gi * 8]) = o;
        }
    }
    for (int c = lane; c < 196; c += 64) {
        int j = c >> 2, gi = c & 3;
        int tok = tok_base + (j / 7) * 56 + (j % 7);
        short8_t raw = *reinterpret_cast<const short8_t*>(
            qkv + (size_t)tok * 768 + 512 + h * 32 + gi * 8);
        #pragma unroll
        for (int e = 0; e < 8; ++e)
            lds[VO + (gi * 8 + e) * 72 + j] = (unsigned short)raw[e];
    }
    __syncthreads();

    short8_t qf[4], kf[4];
    #pragma unroll
    for (int mi = 0; mi < 4; ++mi)
        qf[mi] = *reinterpret_cast<const short8_t*>(&lds[QO + (mi * 16 + r16) * 40 + g4 * 8]);
    #pragma unroll
    for (int ji = 0; ji < 4; ++ji)
        kf[ji] = *reinterpret_cast<const short8_t*>(&lds[KO + (ji * 16 + r16) * 40 + g4 * 8]);
    f32x4 acc[4][4] = {};
    #pragma unroll
    for (int mi = 0; mi < 4; ++mi)
        #pragma unroll
        for (int ji = 0; ji < 4; ++ji)
            acc[mi][ji] = __builtin_amdgcn_mfma_f32_16x16x32_bf16(qf[mi], kf[ji], acc[mi][ji], 0, 0, 0);
    __syncthreads();   // Q/K dead; P overlays them

    const float* rbf = rpbf + h * 4096 + r16 * 16 + g4 * 4;
    f32x4 rbv[4][4];
    #pragma unroll
    for (int mi = 0; mi < 4; ++mi)
        #pragma unroll
        for (int ji = 0; ji < 4; ++ji)
            rbv[mi][ji] = *reinterpret_cast<const f32x4*>(&rbf[(mi * 4 + ji) * 256]);

    #pragma unroll
    for (int mi = 0; mi < 4; ++mi) {
        #pragma unroll
        for (int r = 0; r < 4; ++r) {
            int i = mi * 16 + g4 * 4 + r;
            float s[4]; float m = -1e30f;
            #pragma unroll
            for (int ji = 0; ji < 4; ++ji) {
                int j = ji * 16 + r16;
                float v = acc[mi][ji][r] + rbv[mi][ji][r];
                s[ji] = (j < 49) ? v : -1e30f;
                m = fmaxf(m, s[ji]);
            }
            m = fmaxf(m, __shfl_xor(m, 1)); m = fmaxf(m, __shfl_xor(m, 2));
            m = fmaxf(m, __shfl_xor(m, 4)); m = fmaxf(m, __shfl_xor(m, 8));
            float p[4]; float sum = 0.f;
            #pragma unroll
            for (int ji = 0; ji < 4; ++ji) {
                p[ji] = (s[ji] > -1e29f) ? __expf(s[ji] - m) : 0.f;
                sum += p[ji];
            }
            sum += __shfl_xor(sum, 1); sum += __shfl_xor(sum, 2);
            sum += __shfl_xor(sum, 4); sum += __shfl_xor(sum, 8);
            float rinv = 1.f / sum;
            #pragma unroll
            for (int ji = 0; ji < 4; ++ji) {
                int j = ji * 16 + r16;
                lds[PO + i * 72 + j] = f2bf(p[ji] * rinv);
            }
        }
    }
    __syncthreads();

    f32x4 acc2[4][2] = {};
    #pragma unroll
    for (int ks = 0; ks < 2; ++ks) {
        short8_t pf[4], vf[2];
        int ko = ks * 32 + g4 * 8;
        #pragma unroll
        for (int mi = 0; mi < 4; ++mi)
            pf[mi] = *reinterpret_cast<const short8_t*>(&lds[PO + (mi * 16 + r16) * 72 + ko]);
        #pragma unroll
        for (int ni = 0; ni < 2; ++ni)
            vf[ni] = *reinterpret_cast<const short8_t*>(&lds[VO + (ni * 16 + r16) * 72 + ko]);
        #pragma unroll
        for (int mi = 0; mi < 4; ++mi)
            #pragma unroll
            for (int ni = 0; ni < 2; ++ni)
                acc2[mi][ni] = __builtin_amdgcn_mfma_f32_16x16x32_bf16(pf[mi], vf[ni], acc2[mi][ni], 0, 0, 0);
    }

    #pragma unroll
    for (int mi = 0; mi < 4; ++mi)
        #pragma unroll
        for (int r = 0; r < 4; ++r) {
            int i = mi * 16 + g4 * 4 + r;
            if (i < 49) {
                size_t ob = (size_t)(wb * 49 + i) * 256 + h * 32;
                out[ob + r16]      = f2bf(acc2[mi][0][r]);
                out[ob + 16 + r16] = f2bf(acc2[mi][1][r]);
            }
        }
}

extern "C" void kernel_launch(void* const* d_in, const int* in_sizes, int n_in,
                              void* d_out, int out_size, void* d_ws, size_t ws_size,
                              hipStream_t stream) {
    const float* x      = (const float*)d_in[0];
    const float* qkv_w  = (const float*)d_in[1];
    const float* q_bias = (const float*)d_in[2];
    const float* v_bias = (const float*)d_in[3];
    const float* lscale = (const float*)d_in[4];
    const float* cpb_w1 = (const float*)d_in[5];
    const float* cpb_b1 = (const float*)d_in[6];
    const float* cpb_w2 = (const float*)d_in[7];
    const float* proj_w = (const float*)d_in[8];
    const float* proj_b = (const float*)d_in[9];
    const float* n1g    = (const float*)d_in[10];
    const float* n1b    = (const float*)d_in[11];
    const float* fc1_w  = (const float*)d_in[12];
    const float* fc1_b  = (const float*)d_in[13];
    const float* fc2_w  = (const float*)d_in[14];
    const float* fc2_b  = (const float*)d_in[15];
    const float* n2g    = (const float*)d_in[16];
    const float* n2b    = (const float*)d_in[17];
    const float* rct    = (const float*)d_in[18];
    const int*   rpi    = (const int*)d_in[19];

    char* ws = (char*)d_ws;
    unsigned short* qkv    = (unsigned short*)(ws);
    unsigned short* hbuf   = (unsigned short*)(ws);
    unsigned short* attn_o = (unsigned short*)(ws + 154140672);
    unsigned short* xb     = (unsigned short*)(ws + 205520896);
    unsigned short* x1     = (unsigned short*)(ws + 205520896);  // in-place over xb
    unsigned short* wqkv   = (unsigned short*)(ws + 308281344);
    unsigned short* wproj  = (unsigned short*)(ws + 308674560);
    unsigned short* wfc1   = (unsigned short*)(ws + 308805632);
    unsigned short* wfc2   = (unsigned short*)(ws + 309329920);
    float*          rpbf   = (float*)(ws + 309854208);
    float*          scales = (float*)(ws + 310378496);
    float*          qkvb   = (float*)(ws + 310378528);
    float*          tableg = (float*)(ws + 310381600);

    const int M = 100352;

    conv_kernel<<<2048, 256, 0, stream>>>(x, xb, 25690112 / 4);
    conv4_kernel<<<768, 256, 0, stream>>>(qkv_w, wqkv, 49152,
                                          proj_w, wproj, 16384,
                                          fc1_w, wfc1, 65536,
                                          fc2_w, wfc2, 65536);
    prep_table_kernel<<<169, 256, 0, stream>>>(cpb_w1, cpb_b1, cpb_w2, rct, tableg);
    prep_expand_kernel<<<128, 256, 0, stream>>>(lscale, q_bias, v_bias, rpi, tableg,
                                                scales, rpbf, qkvb);
    // qkv = xb @ wqkv^T + qkv_bias
    gemm_kernel<0, 0><<<4704, 256, 0, stream>>>(xb, wqkv, qkvb, qkv, M, 768, 256, 6);
    // attention -> window-ordered (Bw*49, 256)
    attn_kernel<<<16384, 64, 0, stream>>>(qkv, scales, rpbf, attn_o);
    // x1 = xb + LN(attn_o @ wproj^T + proj_b)  [fused, scatter to natural order]
    gemm_ln_kernel<1, 0><<<784, 512, 0, stream>>>(attn_o, wproj, proj_b, xb, n1g, n1b,
                                                  x1, M, 256);
    // h = gelu(x1 @ wfc1^T + fc1_b)
    gemm_kernel<1, 0><<<6272, 256, 0, stream>>>(x1, wfc1, fc1_b, hbuf, M, 1024, 256, 8);
    // out = x1 + LN(h @ wfc2^T + fc2_b)  [fused, f32 output]
    gemm_ln_kernel<0, 1><<<784, 512, 0, stream>>>(hbuf, wfc2, fc2_b, x1, n2g, n2b,
                                                  d_out, M, 1024);
}